// Round 13
// baseline (5320.356 us; speedup 1.0000x reference)
//
#include <hip/hip_runtime.h>
#include <hip/hip_bf16.h>

// ---------------- problem constants ----------------
constexpr int cL   = 256;
constexpr int cB   = 256;
constexpr int cN   = 64;
constexpr int cF   = 1024;   // L*D_OB
constexpr int cDM  = 256;    // N*D_OB
constexpr int cDTR = 272;    // D_MODEL + D_PE
constexpr int cHD  = 68;     // D_TR / H
constexpr int cNH  = 1024;   // NHID
constexpr int cDST = 9;
constexpr int cDFIN= 336;    // D_TR + N
constexpr int cE   = 4096;   // N*N
constexpr int cLB  = cL * cB;   // 65536
constexpr int cBN  = cB * cN;   // 16384
constexpr int BC   = 64;        // batch chunk
constexpr int NCHUNK = cB / BC; // 4
constexpr int RC_OBS = BC * cN;   // 4096 rows per obs chunk
constexpr int RC_TR  = BC * cL;   // 16384 rows per transformer chunk

using u16 = unsigned short;
using u32 = unsigned int;
typedef short bf16x8 __attribute__((ext_vector_type(8)));
typedef float f32x4  __attribute__((ext_vector_type(4)));
typedef u16   u16x4  __attribute__((ext_vector_type(4)));

__device__ inline u16 f2bf(float x) {            // RNE f32->bf16
    unsigned int u = __float_as_uint(x);
    unsigned int r = (u + 0x7FFFu + ((u >> 16) & 1u)) >> 16;
    return (u16)r;
}
__device__ inline float bf2f(u16 x) {
    return __uint_as_float(((u32)x) << 16);
}

// ---------------- workspace layout (float words), ~183MB ----------------
constexpr size_t O_PE    = 0;                               // LB*16 (b,l,16)
constexpr size_t O_PEM   = O_PE    + (size_t)cLB*16;
constexpr size_t O_EMB   = O_PEM   + (size_t)cB*16;
constexpr size_t O_BIAS1 = O_EMB   + (size_t)cB*64;
constexpr size_t O_BIAS2 = O_BIAS1 + (size_t)cB*cF;
constexpr size_t O_SA    = O_BIAS2 + (size_t)cB*cF;
constexpr size_t O_SR    = O_SA    + (size_t)cBN;
constexpr size_t O_AL1   = O_SR    + (size_t)cBN;           // B*E
constexpr size_t O_AL2   = O_AL1   + (size_t)cB*cE;         // B*E
constexpr size_t O_GRAM  = O_AL2   + (size_t)cB*cE;         // B*B
constexpr size_t O_DPART = O_GRAM  + (size_t)cB*cB;         // B
constexpr size_t O_AGG   = O_DPART + (size_t)cB;            // B*336
constexpr size_t O_HMLP  = O_AGG   + (size_t)cB*cDFIN;      // B*336
constexpr size_t O_LEN   = O_HMLP  + (size_t)cB*cDFIN;      // B ints
// bf16 buffers (word counts = elems/2)
constexpr size_t O_W1o   = O_LEN   + (size_t)cB;            // 1024x1024
constexpr size_t O_W2o   = O_W1o   + 524288;                // 1024x1024
constexpr size_t O_WQKV  = O_W2o   + 524288;                // 2 x 288x896
constexpr size_t O_WO    = O_WQKV  + 258048;                // 2 x 288x384
constexpr size_t O_W1t   = O_WO    + 110592;                // 2 x 288x1024
constexpr size_t O_W2t   = O_W1t   + 294912;                // 2 x 1024x384
constexpr size_t O_XBBF  = O_W2t   + 393216;                // 4096x1024 bf16
constexpr size_t O_O1BF  = O_XBBF  + 2097152;               // 4096x1024 bf16
constexpr size_t O_TRXBF = O_O1BF  + 2097152;               // 16384x288 bf16
constexpr size_t O_ATTBF = O_TRXBF + 2359296;               // 16384x288 bf16
constexpr size_t O_HIDBF = O_ATTBF + 2359296;               // 16384x1024 bf16
constexpr size_t O_TRXC  = O_HIDBF + 8388608;               // 16384x272 f32
constexpr size_t O_CH0   = O_TRXC  + (size_t)RC_TR*cDTR;    // 16384x816 f32 (qkv / obs z)
constexpr size_t O_CH1   = O_CH0   + (size_t)RC_TR*816;     // max(4096x1024, 16384x272) f32
constexpr size_t WS_END  = O_CH1   + (size_t)RC_TR*cDTR;    // ~45.7M words

// ---------------- lengths canonicalization ----------------
__global__ void fix_lengths(const int* __restrict__ raw, int* __restrict__ canon) {
    __shared__ int odd_nonzero;
    if (threadIdx.x == 0) odd_nonzero = 0;
    __syncthreads();
    int t = threadIdx.x;
    int w = raw[t];
    if ((t & 1) && w != 0) odd_nonzero = 1;
    __syncthreads();
    if (odd_nonzero) canon[t] = raw[t];
    else             canon[t] = raw[2 * t];
}

// ---------------- setup kernels ----------------

__global__ __launch_bounds__(256) void pe_kernel(const float* __restrict__ times,
                                                 float* __restrict__ pe) {
    int t = blockIdx.x * 256 + threadIdx.x;   // t = b*256 + l
    int b = t >> 8, l = t & 255;
    float tv = times[l * cB + b];
    #pragma unroll
    for (int i = 0; i < 8; i++) {
        float ts = exp2f((8.0f * i) / 7.0f);  // 256^(i/7)
        float sc = tv / ts;
        pe[(size_t)t * 16 + i]     = sinf(sc);
        pe[(size_t)t * 16 + 8 + i] = cosf(sc);
    }
}

__global__ __launch_bounds__(256) void pemean_naive(const float* __restrict__ pe,
                                                    float* __restrict__ pm) {
    int gid = blockIdx.x * 256 + threadIdx.x;
    if (gid >= cB * 16) return;
    int b = gid >> 4, i = gid & 15;
    float s = 0.f;
    for (int l = 0; l < cL; l++) s += pe[((size_t)b * cL + l) * 16 + i];
    pm[gid] = s * (1.0f / 256.0f);
}

__global__ __launch_bounds__(64) void emb_kernel(const float* __restrict__ st,
                                                 const float* __restrict__ w,
                                                 const float* __restrict__ bb,
                                                 float* __restrict__ emb) {
    int b = blockIdx.x, n = threadIdx.x;
    float s = bb[n];
    #pragma unroll
    for (int k = 0; k < cDST; k++) s += st[b * cDST + k] * w[k * cN + n];
    emb[b * cN + n] = s;
}

__global__ __launch_bounds__(256) void bias_kernel(const float* __restrict__ pm,
                                                   const float* __restrict__ wp,
                                                   float* __restrict__ bias) {
    int t = blockIdx.x * 256 + threadIdx.x;   // b*1024 + f
    int b = t >> 10, f = t & 1023;
    float s = 0.f;
    #pragma unroll
    for (int i = 0; i < 16; i++) s += pm[b * 16 + i] * wp[i * cF + f];
    bias[t] = s;
}

// f32 [K][N] -> bf16 [KP][NP], zero padded (weights only)
__global__ __launch_bounds__(256) void cvt_pad(const float* __restrict__ in,
                                               u16* __restrict__ out,
                                               int K, int N, int NP, int total) {
    int gid = blockIdx.x * 256 + threadIdx.x;
    if (gid >= total) return;
    int r = gid / NP, c = gid - r * NP;
    float v = (r < K && c < N) ? in[(size_t)r * N + c] : 0.f;
    out[gid] = f2bf(v);
}

// xb_bf[r,1024] bf16 for local rows r = b_local*64 + n of chunk b0
__global__ __launch_bounds__(256) void build_xb_bf(const float* __restrict__ src,
                                                   const float* __restrict__ R_u,
                                                   int b0,
                                                   u16* __restrict__ xb) {
    int r = blockIdx.x;
    int l = threadIdx.x;
    int b = b0 + (r >> 6), n = r & 63;
    float s = src[((size_t)l * cB + b) * 128 + n];
    float4 rr = *(const float4*)(R_u + n * 4);
    u16x4 o;
    o[0] = f2bf(fmaxf(s * rr.x, 0.f));
    o[1] = f2bf(fmaxf(s * rr.y, 0.f));
    o[2] = f2bf(fmaxf(s * rr.z, 0.f));
    o[3] = f2bf(fmaxf(s * rr.w, 0.f));
    *(u16x4*)(xb + (size_t)r * cF + l * 4) = o;
}

// ---------------- bf16 MFMA GEMM: C(MxNcol) = A(M x KP) * B(KP x NP) ----------------
template<int BIASMODE, int ACT, int OBF>
__global__ __launch_bounds__(256) void gemm_bf(const u16* __restrict__ A,
                                               const u16* __restrict__ B,
                                               const float* __restrict__ bias,
                                               void* __restrict__ Cv,
                                               int M, int Ncol, int KP, int NP) {
    constexpr int LPA = 40;                 // u16 stride for A rows (80B)
    constexpr int LPB = 20;                 // u32 stride for B n-rows (80B)
    __shared__ u16 As[128 * LPA];           // 10 KB
    __shared__ u32 Bs[128 * LPB];           // 10 KB
    int tid = threadIdx.x;
    int m0 = blockIdx.y * 128;
    int n0 = blockIdx.x * 128;
    int w = tid >> 6, lane = tid & 63;
    int wr = w >> 1, wc = w & 1;
    int fr = lane & 15, kg = lane >> 4;

    f32x4 acc[4][4];
    #pragma unroll
    for (int mi = 0; mi < 4; mi++)
        #pragma unroll
        for (int ni = 0; ni < 4; ni++)
            acc[mi][ni] = (f32x4){0.f, 0.f, 0.f, 0.f};

    int arow = tid >> 1, ah = (tid & 1) * 16;
    int bkp = tid >> 4;              // k-pair slot 0..15
    int bnb = (tid & 15) * 8;        // n offset 0..120

    for (int k0 = 0; k0 < KP; k0 += 32) {
        const uint4* ga = (const uint4*)(A + (size_t)(m0 + arow) * KP + k0 + ah);
        *(uint4*)&As[arow * LPA + ah]     = ga[0];
        *(uint4*)&As[arow * LPA + ah + 8] = ga[1];
        const u16* bp0 = B + (size_t)(k0 + 2 * bkp) * NP + n0 + bnb;
        uint4 r0 = *(const uint4*)bp0;
        uint4 r1 = *(const uint4*)(bp0 + NP);
        const u16* e0 = (const u16*)&r0;
        const u16* e1 = (const u16*)&r1;
        #pragma unroll
        for (int j = 0; j < 8; j++) {
            int n = bnb + j;
            int slot = bkp ^ (((n >> 3) & 3) << 2);
            Bs[n * LPB + slot] = (u32)e0[j] | ((u32)e1[j] << 16);
        }
        __syncthreads();

        bf16x8 a[4], bfr[4];
        #pragma unroll
        for (int mi = 0; mi < 4; mi++)
            a[mi] = *(const bf16x8*)&As[(wr * 64 + mi * 16 + fr) * LPA + kg * 8];
        #pragma unroll
        for (int ni = 0; ni < 4; ni++) {
            int n = wc * 64 + ni * 16 + fr;
            int slot4 = 4 * (kg ^ ((n >> 3) & 3));
            bfr[ni] = *(const bf16x8*)&Bs[n * LPB + slot4];
        }
        #pragma unroll
        for (int mi = 0; mi < 4; mi++)
            #pragma unroll
            for (int ni = 0; ni < 4; ni++)
                acc[mi][ni] = __builtin_amdgcn_mfma_f32_16x16x32_bf16(
                    a[mi], bfr[ni], acc[mi][ni], 0, 0, 0);
        __syncthreads();
    }

    float* Cf = (float*)Cv;
    u16*   Cb = (u16*)Cv;
    #pragma unroll
    for (int mi = 0; mi < 4; mi++) {
        #pragma unroll
        for (int ni = 0; ni < 4; ni++) {
            int col = n0 + wc * 64 + ni * 16 + fr;
            if (col >= Ncol) continue;
            #pragma unroll
            for (int r = 0; r < 4; r++) {
                int row = m0 + wr * 64 + mi * 16 + kg * 4 + r;
                float x = acc[mi][ni][r];
                if (BIASMODE == 1) x += bias[col];
                else if (BIASMODE == 2) x += bias[(size_t)(row >> 6) * cF + col];
                if (ACT) x = fmaxf(x, 0.f);
                if (OBF) Cb[(size_t)row * Ncol + col] = f2bf(x);
                else     Cf[(size_t)row * Ncol + col] = x;
            }
        }
    }
}

// ---------------- f32 tiled GEMM (head + gram only) ----------------
template<int BIASMODE, int ACT>
__global__ __launch_bounds__(256) void gemm_f32(const float* __restrict__ A,
                                                const float* __restrict__ Bm,
                                                const float* __restrict__ bias,
                                                float* __restrict__ C,
                                                int M, int Ncol, int K) {
    __shared__ float As[16][65];
    __shared__ float Bs[16][65];
    int bx = blockIdx.x, by = blockIdx.y;
    int tid = threadIdx.x;
    int tx = tid & 15, ty = tid >> 4;
    int row0 = by * 64, col0 = bx * 64;
    float acc[4][4] = {};
    for (int k0 = 0; k0 < K; k0 += 16) {
        {
            int r  = tid >> 2;
            int kk = (tid & 3) * 4;
            int gr = row0 + r;
            #pragma unroll
            for (int i = 0; i < 4; i++) {
                int gk = k0 + kk + i;
                As[kk + i][r] = (gr < M && gk < K) ? A[(size_t)gr * K + gk] : 0.f;
            }
        }
        {
            int kr = tid >> 4;
            int c  = (tid & 15) * 4;
            int gk = k0 + kr;
            #pragma unroll
            for (int i = 0; i < 4; i++) {
                int gc = col0 + c + i;
                Bs[kr][c + i] = (gk < K && gc < Ncol) ? Bm[(size_t)gk * Ncol + gc] : 0.f;
            }
        }
        __syncthreads();
        #pragma unroll
        for (int kk = 0; kk < 16; kk++) {
            float a[4], bv[4];
            #pragma unroll
            for (int i = 0; i < 4; i++) a[i]  = As[kk][ty * 4 + i];
            #pragma unroll
            for (int j = 0; j < 4; j++) bv[j] = Bs[kk][tx * 4 + j];
            #pragma unroll
            for (int i = 0; i < 4; i++)
                #pragma unroll
                for (int j = 0; j < 4; j++)
                    acc[i][j] += a[i] * bv[j];
        }
        __syncthreads();
    }
    #pragma unroll
    for (int i = 0; i < 4; i++) {
        int r = row0 + ty * 4 + i;
        if (r >= M) continue;
        #pragma unroll
        for (int j = 0; j < 4; j++) {
            int c = col0 + tx * 4 + j;
            if (c >= Ncol) continue;
            float v = acc[i][j];
            if (BIASMODE == 1) v += bias[c];
            if (ACT == 1) v = fmaxf(v, 0.f);
            C[(size_t)r * Ncol + c] = v;
        }
    }
}

// ---------------- obs_prop (wave-parallel, pre-validated) ----------------

__global__ __launch_bounds__(256) void sasr_kernel(const float* __restrict__ z,
                                                   const float* __restrict__ al,
                                                   const float* __restrict__ ar,
                                                   float* __restrict__ sa,
                                                   float* __restrict__ sr) {
    int row  = blockIdx.x * 4 + (threadIdx.x >> 6);
    int lane = threadIdx.x & 63;
    const float* zr = z + (size_t)row * cF;
    float a = 0.f, r = 0.f;
    for (int k = lane; k < cF; k += 64) {
        float v = zr[k];
        a += v * al[k];
        r += v * ar[k];
    }
    for (int off = 32; off; off >>= 1) {
        a += __shfl_xor(a, off);
        r += __shfl_xor(r, off);
    }
    if (lane == 0) { sa[row] = a; sr[row] = r; }
}

template<int WITH_EW>
__global__ __launch_bounds__(256) void alpha_kernel(const float* __restrict__ sa,
                                                    const float* __restrict__ sr,
                                                    const float* __restrict__ ew,
                                                    float* __restrict__ alpha) {
    int idx = blockIdx.x * 4 + (threadIdx.x >> 6);   // local b*64 + d
    int b = idx >> 6, d = idx & 63;
    int s = threadIdx.x & 63;
    float sc = sa[b * 64 + s] + sr[b * 64 + d];
    sc = sc >= 0.f ? sc : 0.2f * sc;
    size_t eidx = (size_t)b * cE + s * 64 + d;
    if (WITH_EW) sc *= ew[eidx];
    float m = sc;
    for (int off = 32; off; off >>= 1) m = fmaxf(m, __shfl_xor(m, off));
    float e = expf(sc - m);
    float zz = e;
    for (int off = 32; off; off >>= 1) zz += __shfl_xor(zz, off);
    alpha[eidx] = e / zz;
}

// dst[b,d,:] = sum_s alpha[b, s*64+d] * z[b,s,:]  (dst separate; OBF: bf16 out)
template<int OBF>
__global__ __launch_bounds__(256) void obs_out_k(const float* __restrict__ alpha,
                                                 const float* __restrict__ z,
                                                 void* __restrict__ dstv) {
    __shared__ float As[64][65];
    int b  = blockIdx.x, fc = blockIdx.y;
    int tid = threadIdx.x;
    for (int i = tid; i < cE; i += 256) As[i >> 6][i & 63] = alpha[(size_t)b * cE + i];
    __syncthreads();
    int f = fc * 256 + tid;
    float acc[64];
    #pragma unroll
    for (int d = 0; d < 64; d++) acc[d] = 0.f;
    for (int s = 0; s < 64; s++) {
        float zv = z[((size_t)b * 64 + s) * cF + f];
        #pragma unroll
        for (int d = 0; d < 64; d++) acc[d] += As[s][d] * zv;
    }
    float* df = (float*)dstv;
    u16*   db = (u16*)dstv;
    #pragma unroll
    for (int d = 0; d < 64; d++) {
        size_t o = ((size_t)b * 64 + d) * cF + f;
        if (OBF) db[o] = f2bf(acc[d]);
        else     df[o] = acc[d];
    }
}

// scatter out2 chunk + pe chunk -> trx chunk f32 AND bf16 (padded 288)
__global__ __launch_bounds__(256) void scatter_trx(const float* __restrict__ out2,
                                                   const float* __restrict__ pe_c,
                                                   float* __restrict__ trx_c,
                                                   u16* __restrict__ trxbf) {
    int r = blockIdx.x;                 // local row = b_local*256 + l
    int bl = r >> 8, l = r & 255;
    size_t obase = (size_t)r * cDTR;
    size_t bbase = (size_t)r * 288;
    for (int c = threadIdx.x; c < cDTR; c += 256) {
        float v;
        if (c < cDM) v = out2[((size_t)bl * 64 + (c >> 2)) * cF + l * 4 + (c & 3)];
        else         v = pe_c[(size_t)r * 16 + (c - cDM)];
        trx_c[obase + c] = v;
        trxbf[bbase + c] = f2bf(v);
    }
}

// ---------------- attention v3: K^T/V^T bf16 in LDS, Ps in LDS (round-9 structure) ----------------
// block = 256 threads (4 waves); grid = BC*4h*4seg; each wave does 16 q-rows.
constexpr int KT_S = 264;   // k-stride (u16): 528B rows, 16B-aligned, conflict-free
__global__ __launch_bounds__(256) void attn_kernel(const float* __restrict__ qkv,
                                                   const int* __restrict__ lengths,
                                                   u16* __restrict__ att) {
    __shared__ __align__(16) u16 Ks[cHD * KT_S];   // 35,904 B  K^T [d][k]
    __shared__ __align__(16) u16 Vs[cHD * KT_S];   // 35,904 B  V^T [d][k]
    __shared__ float Ps[4][cL];                    //  4,096 B
    int blk = blockIdx.x;
    int seg = blk & 3;
    int h   = (blk >> 2) & 3;
    int bl  = blk >> 4;
    int tid = threadIdx.x;
    int len = lengths[bl];

    // stage K^T and V^T (each thread: one k-row of K and V, scalar u16 transposed writes)
    {
        int k = tid;
        const float* krow = qkv + ((size_t)bl * cL + k) * 816 + cDTR + h * cHD;
        const float* vrow = krow + cDTR;
        for (int d = 0; d < cHD; d += 4) {
            float4 kv = *(const float4*)(krow + d);
            float4 vv = *(const float4*)(vrow + d);
            Ks[(d + 0) * KT_S + k] = f2bf(kv.x);
            Ks[(d + 1) * KT_S + k] = f2bf(kv.y);
            Ks[(d + 2) * KT_S + k] = f2bf(kv.z);
            Ks[(d + 3) * KT_S + k] = f2bf(kv.w);
            Vs[(d + 0) * KT_S + k] = f2bf(vv.x);
            Vs[(d + 1) * KT_S + k] = f2bf(vv.y);
            Vs[(d + 2) * KT_S + k] = f2bf(vv.z);
            Vs[(d + 3) * KT_S + k] = f2bf(vv.w);
        }
    }
    __syncthreads();

    int wave = tid >> 6, lane = tid & 63;
    const float scale = 0.12126781f;   // 1/sqrt(68)
    int d1 = 64 + (lane & 3);
    const u16* v0row = &Vs[lane * KT_S];
    const u16* v1row = &Vs[d1 * KT_S];

    for (int lq = seg * 64 + wave; lq < seg * 64 + 64; lq += 4) {
        size_t qbase = ((size_t)bl * cL + lq) * 816 + h * cHD;
        // QK^T: scores for k = lane + 64*i (scalar-broadcast q, conflict-free K^T reads)
        float acc[4] = {0.f, 0.f, 0.f, 0.f};
        for (int d = 0; d < cHD; d++) {
            float qd = qkv[qbase + d];           // wave-uniform scalar load
            const u16* kr = &Ks[d * KT_S + lane];
            acc[0] += qd * bf2f(kr[0]);
            acc[1] += qd * bf2f(kr[64]);
            acc[2] += qd * bf2f(kr[128]);
            acc[3] += qd * bf2f(kr[192]);
        }
        float sc[4];
        #pragma unroll
        for (int i = 0; i < 4; i++) {
            int lk = lane + i * 64;
            sc[i] = (lk >= len) ? -1e9f : acc[i] * scale;
        }
        float m = fmaxf(fmaxf(sc[0], sc[1]), fmaxf(sc[2], sc[3]));
        for (int off = 32; off; off >>= 1) m = fmaxf(m, __shfl_xor(m, off));
        float e[4], sum = 0.f;
        #pragma unroll
        for (int i = 0; i < 4; i++) { e[i] = expf(sc[i] - m); sum += e[i]; }
        for (int off = 32; off; off >>= 1) sum += __shfl_xor(sum, off);
        float inv = 1.0f / sum;
        #pragma unroll
        for (int i = 0; i < 4; i++) Ps[wave][lane + i * 64] = e[i] * inv;
        __syncthreads();

        // PV: lane owns d=lane (and d1 for lanes 0-3); vector bf16x8 V reads + uniform f32x4 P reads
        float o0 = 0.f, o1 = 0.f;
        #pragma unroll 2
        for (int t8 = 0; t8 < 32; t8++) {
            int t = t8 * 8;
            f32x4 p0 = *(const f32x4*)&Ps[wave][t];
            f32x4 p1 = *(const f32x4*)&Ps[wave][t + 4];
            bf16x8 v0 = *(const bf16x8*)(v0row + t);
            bf16x8 v1 = *(const bf16x8*)(v1row + t);
            o0 += p0[0] * bf2f((u16)v0[0]) + p0[1] * bf2f((u16)v0[1])
                + p0[2] * bf2f((u16)v0[2]) + p0[3] * bf2f((u16)v0[3])
                + p1[0] * bf2f((u16)v0[4]) + p1[1] * bf2f((u16)v0[5])
                + p1[2] * bf2f((u16)v0[6]) + p1[3] * bf2f((u16)v0[7]);
            o1 += p0[0] * bf2f((u16)v1[0]) + p0[1] * bf2f((u16)v1[1])
                + p0[2] * bf2f((u16)v1[2]) + p0[3] * bf2f((u16)v1[3])
                + p1[0] * bf2f((u16)v1[4]) + p1[1] * bf2f((u16)v1[5])
                + p1[2] * bf2f((u16)v1[6]) + p1[3] * bf2f((u16)v1[7]);
        }
        size_t obase = ((size_t)bl * cL + lq) * 288 + h * cHD;
        att[obase + lane] = f2bf(o0);
        if (lane < 4) att[obase + 64 + lane] = f2bf(o1);
        __syncthreads();
    }
}

// ---------------- residual + layernorm (wave per row), fused bf16 out ----------------
__global__ __launch_bounds__(256) void resid_ln_kernel(float* __restrict__ x,
                                                       const float* __restrict__ res,
                                                       const float* __restrict__ g,
                                                       const float* __restrict__ bt,
                                                       u16* __restrict__ xbf) {
    int row  = blockIdx.x * 4 + (threadIdx.x >> 6);
    int lane = threadIdx.x & 63;
    size_t base = (size_t)row * cDTR;
    size_t bbase = (size_t)row * 288;
    float v[5];
    float sum = 0.f, sumsq = 0.f;
    #pragma unroll
    for (int k = 0; k < 5; k++) {
        int c = lane + k * 64;
        float t = 0.f;
        if (c < cDTR) t = x[base + c] + res[base + c];
        v[k] = t;
        sum += t;
        sumsq += t * t;
    }
    for (int off = 32; off; off >>= 1) {
        sum   += __shfl_xor(sum, off);
        sumsq += __shfl_xor(sumsq, off);
    }
    float mean = sum * (1.0f / cDTR);
    float var  = fmaxf(sumsq * (1.0f / cDTR) - mean * mean, 0.f);
    float rstd = 1.0f / sqrtf(var + 1e-5f);
    #pragma unroll
    for (int k = 0; k < 5; k++) {
        int c = lane + k * 64;
        if (c < cDTR) {
            float o = (v[k] - mean) * rstd * g[c] + bt[c];
            x[base + c] = o;
            xbf[bbase + c] = f2bf(o);
        }
    }
}

// ---------------- head ----------------

__global__ __launch_bounds__(256) void agg_kernel(const float* __restrict__ trxc,
                                                  const int* __restrict__ lengths,
                                                  const float* __restrict__ emb,
                                                  float* __restrict__ agg) {
    int b = blockIdx.x;   // local
    int len = lengths[b];
    float inv = 1.0f / ((float)len + 1.0f);
    for (int c = threadIdx.x; c < cDTR; c += 256) {
        float s = 0.f;
        for (int l = 0; l < len; l++) s += trxc[((size_t)b * cL + l) * cDTR + c];
        agg[(size_t)b * cDFIN + c] = s * inv;
    }
    for (int c = threadIdx.x; c < cN; c += 256)
        agg[(size_t)b * cDFIN + cDTR + c] = emb[b * cN + c];
}

__global__ __launch_bounds__(256) void mlp2_naive(const float* __restrict__ hm,
                                                  const float* __restrict__ w2,
                                                  const float* __restrict__ b2,
                                                  float* __restrict__ out) {
    int gid = blockIdx.x * 256 + threadIdx.x;
    if (gid >= cB * 2) return;
    int b = gid >> 1, c = gid & 1;
    float a = b2[c];
    for (int j = 0; j < cDFIN; j++) a += hm[(size_t)b * cDFIN + j] * w2[j * 2 + c];
    out[gid] = a;
}

// ---------------- distance ----------------

__global__ __launch_bounds__(256) void transpose_kernel(const float* __restrict__ a,
                                                        float* __restrict__ at) {
    int t = blockIdx.x * 256 + threadIdx.x;   // b*4096 + e
    int b = t >> 12, e = t & 4095;
    at[(size_t)e * cB + b] = a[t];
}

__global__ __launch_bounds__(256) void dist_rows(const float* __restrict__ G,
                                                 float* __restrict__ part) {
    __shared__ float red[256];
    int i = blockIdx.x, j = threadIdx.x;
    float d2 = fmaxf(G[i * cB + i] + G[j * cB + j] - 2.0f * G[i * cB + j], 0.0f);
    red[j] = sqrtf(d2);
    __syncthreads();
    for (int s = 128; s; s >>= 1) {
        if (j < s) red[j] += red[j + s];
        __syncthreads();
    }
    if (j == 0) part[i] = red[0];
}

__global__ void dist_final_naive(const float* __restrict__ part,
                                 float* __restrict__ out) {
    if (threadIdx.x == 0 && blockIdx.x == 0) {
        float s = 0.f;
        for (int i = 0; i < cB; i++) s += part[i];
        out[512] = s * (1.0f / 65536.0f);
    }
}

// ---------------- launch ----------------

extern "C" void kernel_launch(void* const* d_in, const int* in_sizes, int n_in,
                              void* d_out, int out_size, void* d_ws, size_t ws_size,
                              hipStream_t stream) {
    const float* src     = (const float*)d_in[0];
    const float* statin  = (const float*)d_in[1];
    const float* times   = (const float*)d_in[2];
    const int*   lengths = (const int*)  d_in[3];
    const float* R_u     = (const float*)d_in[4];
    const float* emb_w   = (const float*)d_in[5];
    const float* emb_b   = (const float*)d_in[6];
    const float* op1_W   = (const float*)d_in[7];
    const float* op1_al  = (const float*)d_in[8];
    const float* op1_ar  = (const float*)d_in[9];
    const float* op1_wp  = (const float*)d_in[10];
    const float* op2_W   = (const float*)d_in[11];
    const float* op2_al  = (const float*)d_in[12];
    const float* op2_ar  = (const float*)d_in[13];
    const float* op2_wp  = (const float*)d_in[14];
    const float* tr_wqkv = (const float*)d_in[15];
    const float* tr_bqkv = (const float*)d_in[16];
    const float* tr_wo   = (const float*)d_in[17];
    const float* tr_bo   = (const float*)d_in[18];
    const float* tr_ln1g = (const float*)d_in[19];
    const float* tr_ln1b = (const float*)d_in[20];
    const float* tr_w1   = (const float*)d_in[21];
    const float* tr_b1   = (const float*)d_in[22];
    const float* tr_w2   = (const float*)d_in[23];
    const float* tr_b2   = (const float*)d_in[24];
    const float* tr_ln2g = (const float*)d_in[25];
    const float* tr_ln2b = (const float*)d_in[26];
    const float* mlp_w1  = (const float*)d_in[27];
    const float* mlp_b1  = (const float*)d_in[28];
    const float* mlp_w2  = (const float*)d_in[29];
    const float* mlp_b2  = (const float*)d_in[30];

    float* ws = (float*)d_ws;
    float* out = (float*)d_out;

    float* PE    = ws + O_PE;
    float* TRXC  = ws + O_TRXC;
    float* CH0   = ws + O_CH0;
    float* CH1   = ws + O_CH1;
    int*   LEN   = (int*)(ws + O_LEN);
    u16*   W1o   = (u16*)(ws + O_W1o);
    u16*   W2o   = (u16*)(ws + O_W2o);
    u16*   WQKV  = (u16*)(ws + O_WQKV);
    u16*   WO    = (u16*)(ws + O_WO);
    u16*   W1t   = (u16*)(ws + O_W1t);
    u16*   W2t   = (u16*)(ws + O_W2t);
    u16*   XBBF  = (u16*)(ws + O_XBBF);
    u16*   O1BF  = (u16*)(ws + O_O1BF);
    u16*   TRXBF = (u16*)(ws + O_TRXBF);
    u16*   ATTBF = (u16*)(ws + O_ATTBF);
    u16*   HIDBF = (u16*)(ws + O_HIDBF);

    // ---- setup ----
    fix_lengths<<<1, 256, 0, stream>>>(lengths, LEN);
    pe_kernel<<<cLB / 256, 256, 0, stream>>>(times, PE);
    pemean_naive<<<(cB * 16 + 255) / 256, 256, 0, stream>>>(PE, ws + O_PEM);
    emb_kernel<<<cB, 64, 0, stream>>>(statin, emb_w, emb_b, ws + O_EMB);
    bias_kernel<<<cB * cF / 256, 256, 0, stream>>>(ws + O_PEM, op1_wp, ws + O_BIAS1);
    bias_kernel<<<cB * cF / 256, 256, 0, stream>>>(ws + O_PEM, op2_wp, ws + O_BIAS2);

    // ---- weight conversions (bf16, padded) ----
    cvt_pad<<<(1024 * 1024 + 255) / 256, 256, 0, stream>>>(op1_W, W1o, 1024, 1024, 1024, 1024 * 1024);
    cvt_pad<<<(1024 * 1024 + 255) / 256, 256, 0, stream>>>(op2_W, W2o, 1024, 1024, 1024, 1024 * 1024);
    for (int l = 0; l < 2; l++) {
        cvt_pad<<<(288 * 896 + 255) / 256, 256, 0, stream>>>(
            tr_wqkv + (size_t)l * 272 * 816, WQKV + (size_t)l * 288 * 896, 272, 816, 896, 288 * 896);
        cvt_pad<<<(288 * 384 + 255) / 256, 256, 0, stream>>>(
            tr_wo + (size_t)l * 272 * 272, WO + (size_t)l * 288 * 384, 272, 272, 384, 288 * 384);
        cvt_pad<<<(288 * 1024 + 255) / 256, 256, 0, stream>>>(
            tr_w1 + (size_t)l * 272 * 1024, W1t + (size_t)l * 288 * 1024, 272, 1024, 1024, 288 * 1024);
        cvt_pad<<<(1024 * 384 + 255) / 256, 256, 0, stream>>>(
            tr_w2 + (size_t)l * 1024 * 272, W2t + (size_t)l * 1024 * 384, 1024, 272, 384, 1024 * 384);
    }

    // ---- per-chunk pipeline ----
    for (int c = 0; c < NCHUNK; c++) {
        int b0 = c * BC;

        // obs_prop layer 1 (z in CH0, Ncol=1024)
        build_xb_bf<<<RC_OBS, 256, 0, stream>>>(src, R_u, b0, XBBF);
        gemm_bf<2, 0, 0><<<dim3(8, RC_OBS / 128), 256, 0, stream>>>(
            XBBF, W1o, ws + O_BIAS1 + (size_t)b0 * cF, CH0, RC_OBS, 1024, 1024, 1024);
        sasr_kernel<<<RC_OBS / 4, 256, 0, stream>>>(CH0, op1_al, op1_ar,
            ws + O_SA + b0 * 64, ws + O_SR + b0 * 64);
        alpha_kernel<0><<<RC_OBS / 4, 256, 0, stream>>>(
            ws + O_SA + b0 * 64, ws + O_SR + b0 * 64, nullptr,
            ws + O_AL1 + (size_t)b0 * cE);
        obs_out_k<1><<<dim3(BC, 4), 256, 0, stream>>>(
            ws + O_AL1 + (size_t)b0 * cE, CH0, O1BF);

        // obs_prop layer 2 (out2 f32 -> CH1)
        gemm_bf<2, 0, 0><<<dim3(8, RC_OBS / 128), 256, 0, stream>>>(
            O1BF, W2o, ws + O_BIAS2 + (size_t)b0 * cF, CH0, RC_OBS, 1024, 1024, 1024);
        sasr_kernel<<<RC_OBS / 4, 256, 0, stream>>>(CH0, op2_al, op2_ar,
            ws + O_SA + b0 * 64, ws + O_SR + b0 * 64);
        alpha_kernel<1><<<RC_OBS / 4, 256, 0, stream>>>(
            ws + O_SA + b0 * 64, ws + O_SR + b0 * 64,
            ws + O_AL1 + (size_t)b0 * cE, ws + O_AL2 + (size_t)b0 * cE);
        obs_out_k<0><<<dim3(BC, 4), 256, 0, stream>>>(
            ws + O_AL2 + (size_t)b0 * cE, CH0, CH1);

        // transformer input (f32 + bf16 fused)
        scatter_trx<<<RC_TR, 256, 0, stream>>>(
            CH1, PE + (size_t)b0 * cL * 16, TRXC, TRXBF);

        for (int l = 0; l < 2; l++) {
            const float* bqkv = tr_bqkv + (size_t)l * 816;
            const float* bo   = tr_bo   + (size_t)l * 272;
            const float* bb1  = tr_b1   + (size_t)l * cNH;
            const float* bb2  = tr_b2   + (size_t)l * 272;

            gemm_bf<1, 0, 0><<<dim3(7, RC_TR / 128), 256, 0, stream>>>(
                TRXBF, WQKV + (size_t)l * 288 * 896, bqkv, CH0, RC_TR, 816, 288, 896);
            attn_kernel<<<BC * 16, 256, 0, stream>>>(CH0, LEN + b0, ATTBF);
            gemm_bf<1, 0, 0><<<dim3(3, RC_TR / 128), 256, 0, stream>>>(
                ATTBF, WO + (size_t)l * 288 * 384, bo, CH1, RC_TR, 272, 288, 384);
            resid_ln_kernel<<<RC_TR / 4, 256, 0, stream>>>(
                TRXC, CH1, tr_ln1g + (size_t)l * cDTR, tr_ln1b + (size_t)l * cDTR, TRXBF);
            gemm_bf<1, 1, 1><<<dim3(8, RC_TR / 128), 256, 0, stream>>>(
                TRXBF, W1t + (size_t)l * 288 * 1024, bb1, HIDBF, RC_TR, 1024, 288, 1024);
            gemm_bf<1, 0, 0><<<dim3(3, RC_TR / 128), 256, 0, stream>>>(
                HIDBF, W2t + (size_t)l * 1024 * 384, bb2, CH1, RC_TR, 272, 1024, 384);
            resid_ln_kernel<<<RC_TR / 4, 256, 0, stream>>>(
                TRXC, CH1, tr_ln2g + (size_t)l * cDTR, tr_ln2b + (size_t)l * cDTR, TRXBF);
        }

        agg_kernel<<<BC, 256, 0, stream>>>(
            TRXC, LEN + b0, ws + O_EMB + (size_t)b0 * cN,
            ws + O_AGG + (size_t)b0 * cDFIN);
    }

    // ---- head ----
    gemm_f32<1, 1><<<dim3(6, 4), 256, 0, stream>>>(
        ws + O_AGG, mlp_w1, mlp_b1, ws + O_HMLP, cB, cDFIN, cDFIN);
    mlp2_naive<<<(cB * 2 + 255) / 256, 256, 0, stream>>>(
        ws + O_HMLP, mlp_w2, mlp_b2, out);

    // ---- distance from alpha2 (AL1 dead -> reuse as transpose buf) ----
    transpose_kernel<<<cB * cE / 256, 256, 0, stream>>>(ws + O_AL2, ws + O_AL1);
    gemm_f32<0, 0><<<dim3(4, 4), 256, 0, stream>>>(
        ws + O_AL2, ws + O_AL1, nullptr, ws + O_GRAM, cB, cB, cE);
    dist_rows<<<cB, 256, 0, stream>>>(ws + O_GRAM, ws + O_DPART);
    dist_final_naive<<<1, 64, 0, stream>>>(ws + O_DPART, out);

    (void)in_sizes; (void)n_in; (void)out_size; (void)ws_size;
}

// Round 14
// 4889.291 us; speedup vs baseline: 1.0882x; 1.0882x over previous
//
#include <hip/hip_runtime.h>
#include <hip/hip_bf16.h>

// ---------------- problem constants ----------------
constexpr int cL   = 256;
constexpr int cB   = 256;
constexpr int cN   = 64;
constexpr int cF   = 1024;   // L*D_OB
constexpr int cDM  = 256;    // N*D_OB
constexpr int cDTR = 272;    // D_MODEL + D_PE
constexpr int cHD  = 68;     // D_TR / H
constexpr int cNH  = 1024;   // NHID
constexpr int cDST = 9;
constexpr int cDFIN= 336;    // D_TR + N
constexpr int cE   = 4096;   // N*N
constexpr int cLB  = cL * cB;   // 65536
constexpr int cBN  = cB * cN;   // 16384
constexpr int BC   = 64;        // batch chunk
constexpr int NCHUNK = cB / BC; // 4
constexpr int RC_OBS = BC * cN;   // 4096 rows per obs chunk
constexpr int RC_TR  = BC * cL;   // 16384 rows per transformer chunk

using u16 = unsigned short;
using u32 = unsigned int;
typedef short bf16x8 __attribute__((ext_vector_type(8)));
typedef float f32x4  __attribute__((ext_vector_type(4)));
typedef u16   u16x4  __attribute__((ext_vector_type(4)));

__device__ inline u16 f2bf(float x) {            // RNE f32->bf16
    unsigned int u = __float_as_uint(x);
    unsigned int r = (u + 0x7FFFu + ((u >> 16) & 1u)) >> 16;
    return (u16)r;
}
__device__ inline float bf2f(u16 x) {
    return __uint_as_float(((u32)x) << 16);
}

// ---------------- workspace layout (float words), ~183MB ----------------
constexpr size_t O_PE    = 0;                               // LB*16 (b,l,16)
constexpr size_t O_PEM   = O_PE    + (size_t)cLB*16;
constexpr size_t O_EMB   = O_PEM   + (size_t)cB*16;
constexpr size_t O_BIAS1 = O_EMB   + (size_t)cB*64;
constexpr size_t O_BIAS2 = O_BIAS1 + (size_t)cB*cF;
constexpr size_t O_SA    = O_BIAS2 + (size_t)cB*cF;
constexpr size_t O_SR    = O_SA    + (size_t)cBN;
constexpr size_t O_AL1   = O_SR    + (size_t)cBN;           // B*E
constexpr size_t O_AL2   = O_AL1   + (size_t)cB*cE;         // B*E
constexpr size_t O_GRAM  = O_AL2   + (size_t)cB*cE;         // B*B
constexpr size_t O_DPART = O_GRAM  + (size_t)cB*cB;         // B
constexpr size_t O_AGG   = O_DPART + (size_t)cB;            // B*336
constexpr size_t O_HMLP  = O_AGG   + (size_t)cB*cDFIN;      // B*336
constexpr size_t O_LEN   = O_HMLP  + (size_t)cB*cDFIN;      // B ints
// bf16 buffers (word counts = elems/2)
constexpr size_t O_W1o   = O_LEN   + (size_t)cB;            // 1024x1024
constexpr size_t O_W2o   = O_W1o   + 524288;                // 1024x1024
constexpr size_t O_WQKV  = O_W2o   + 524288;                // 2 x 288x896
constexpr size_t O_WO    = O_WQKV  + 258048;                // 2 x 288x384
constexpr size_t O_W1t   = O_WO    + 110592;                // 2 x 288x1024
constexpr size_t O_W2t   = O_W1t   + 294912;                // 2 x 1024x384
constexpr size_t O_XBBF  = O_W2t   + 393216;                // 4096x1024 bf16
constexpr size_t O_O1BF  = O_XBBF  + 2097152;               // 4096x1024 bf16
constexpr size_t O_TRXBF = O_O1BF  + 2097152;               // 16384x288 bf16
constexpr size_t O_ATTBF = O_TRXBF + 2359296;               // 16384x288 bf16
constexpr size_t O_HIDBF = O_ATTBF + 2359296;               // 16384x1024 bf16
constexpr size_t O_TRXC  = O_HIDBF + 8388608;               // 16384x272 f32
constexpr size_t O_CH0   = O_TRXC  + (size_t)RC_TR*cDTR;    // 16384x816 f32 (qkv / obs z / gram partials)
constexpr size_t O_CH1   = O_CH0   + (size_t)RC_TR*816;     // max(4096x1024, 16384x272) f32
constexpr size_t WS_END  = O_CH1   + (size_t)RC_TR*cDTR;    // ~45.7M words

// ---------------- lengths canonicalization ----------------
__global__ void fix_lengths(const int* __restrict__ raw, int* __restrict__ canon) {
    __shared__ int odd_nonzero;
    if (threadIdx.x == 0) odd_nonzero = 0;
    __syncthreads();
    int t = threadIdx.x;
    int w = raw[t];
    if ((t & 1) && w != 0) odd_nonzero = 1;
    __syncthreads();
    if (odd_nonzero) canon[t] = raw[t];
    else             canon[t] = raw[2 * t];
}

// ---------------- setup kernels ----------------

__global__ __launch_bounds__(256) void pe_kernel(const float* __restrict__ times,
                                                 float* __restrict__ pe) {
    int t = blockIdx.x * 256 + threadIdx.x;   // t = b*256 + l
    int b = t >> 8, l = t & 255;
    float tv = times[l * cB + b];
    #pragma unroll
    for (int i = 0; i < 8; i++) {
        float ts = exp2f((8.0f * i) / 7.0f);  // 256^(i/7)
        float sc = tv / ts;
        pe[(size_t)t * 16 + i]     = sinf(sc);
        pe[(size_t)t * 16 + 8 + i] = cosf(sc);
    }
}

__global__ __launch_bounds__(256) void pemean_naive(const float* __restrict__ pe,
                                                    float* __restrict__ pm) {
    int gid = blockIdx.x * 256 + threadIdx.x;
    if (gid >= cB * 16) return;
    int b = gid >> 4, i = gid & 15;
    float s = 0.f;
    for (int l = 0; l < cL; l++) s += pe[((size_t)b * cL + l) * 16 + i];
    pm[gid] = s * (1.0f / 256.0f);
}

__global__ __launch_bounds__(64) void emb_kernel(const float* __restrict__ st,
                                                 const float* __restrict__ w,
                                                 const float* __restrict__ bb,
                                                 float* __restrict__ emb) {
    int b = blockIdx.x, n = threadIdx.x;
    float s = bb[n];
    #pragma unroll
    for (int k = 0; k < cDST; k++) s += st[b * cDST + k] * w[k * cN + n];
    emb[b * cN + n] = s;
}

__global__ __launch_bounds__(256) void bias_kernel(const float* __restrict__ pm,
                                                   const float* __restrict__ wp,
                                                   float* __restrict__ bias) {
    int t = blockIdx.x * 256 + threadIdx.x;   // b*1024 + f
    int b = t >> 10, f = t & 1023;
    float s = 0.f;
    #pragma unroll
    for (int i = 0; i < 16; i++) s += pm[b * 16 + i] * wp[i * cF + f];
    bias[t] = s;
}

// f32 [K][N] -> bf16 [KP][NP], zero padded (weights only)
__global__ __launch_bounds__(256) void cvt_pad(const float* __restrict__ in,
                                               u16* __restrict__ out,
                                               int K, int N, int NP, int total) {
    int gid = blockIdx.x * 256 + threadIdx.x;
    if (gid >= total) return;
    int r = gid / NP, c = gid - r * NP;
    float v = (r < K && c < N) ? in[(size_t)r * N + c] : 0.f;
    out[gid] = f2bf(v);
}

// xb_bf[r,1024] bf16 for local rows r = b_local*64 + n of chunk b0
__global__ __launch_bounds__(256) void build_xb_bf(const float* __restrict__ src,
                                                   const float* __restrict__ R_u,
                                                   int b0,
                                                   u16* __restrict__ xb) {
    int r = blockIdx.x;
    int l = threadIdx.x;
    int b = b0 + (r >> 6), n = r & 63;
    float s = src[((size_t)l * cB + b) * 128 + n];
    float4 rr = *(const float4*)(R_u + n * 4);
    u16x4 o;
    o[0] = f2bf(fmaxf(s * rr.x, 0.f));
    o[1] = f2bf(fmaxf(s * rr.y, 0.f));
    o[2] = f2bf(fmaxf(s * rr.z, 0.f));
    o[3] = f2bf(fmaxf(s * rr.w, 0.f));
    *(u16x4*)(xb + (size_t)r * cF + l * 4) = o;
}

// ---------------- bf16 MFMA GEMM: C(MxNcol) = A(M x KP) * B(KP x NP) ----------------
template<int BIASMODE, int ACT, int OBF>
__global__ __launch_bounds__(256) void gemm_bf(const u16* __restrict__ A,
                                               const u16* __restrict__ B,
                                               const float* __restrict__ bias,
                                               void* __restrict__ Cv,
                                               int M, int Ncol, int KP, int NP) {
    constexpr int LPA = 40;                 // u16 stride for A rows (80B)
    constexpr int LPB = 20;                 // u32 stride for B n-rows (80B)
    __shared__ u16 As[128 * LPA];           // 10 KB
    __shared__ u32 Bs[128 * LPB];           // 10 KB
    int tid = threadIdx.x;
    int m0 = blockIdx.y * 128;
    int n0 = blockIdx.x * 128;
    int w = tid >> 6, lane = tid & 63;
    int wr = w >> 1, wc = w & 1;
    int fr = lane & 15, kg = lane >> 4;

    f32x4 acc[4][4];
    #pragma unroll
    for (int mi = 0; mi < 4; mi++)
        #pragma unroll
        for (int ni = 0; ni < 4; ni++)
            acc[mi][ni] = (f32x4){0.f, 0.f, 0.f, 0.f};

    int arow = tid >> 1, ah = (tid & 1) * 16;
    int bkp = tid >> 4;              // k-pair slot 0..15
    int bnb = (tid & 15) * 8;        // n offset 0..120

    for (int k0 = 0; k0 < KP; k0 += 32) {
        const uint4* ga = (const uint4*)(A + (size_t)(m0 + arow) * KP + k0 + ah);
        *(uint4*)&As[arow * LPA + ah]     = ga[0];
        *(uint4*)&As[arow * LPA + ah + 8] = ga[1];
        const u16* bp0 = B + (size_t)(k0 + 2 * bkp) * NP + n0 + bnb;
        uint4 r0 = *(const uint4*)bp0;
        uint4 r1 = *(const uint4*)(bp0 + NP);
        const u16* e0 = (const u16*)&r0;
        const u16* e1 = (const u16*)&r1;
        #pragma unroll
        for (int j = 0; j < 8; j++) {
            int n = bnb + j;
            int slot = bkp ^ (((n >> 3) & 3) << 2);
            Bs[n * LPB + slot] = (u32)e0[j] | ((u32)e1[j] << 16);
        }
        __syncthreads();

        bf16x8 a[4], bfr[4];
        #pragma unroll
        for (int mi = 0; mi < 4; mi++)
            a[mi] = *(const bf16x8*)&As[(wr * 64 + mi * 16 + fr) * LPA + kg * 8];
        #pragma unroll
        for (int ni = 0; ni < 4; ni++) {
            int n = wc * 64 + ni * 16 + fr;
            int slot4 = 4 * (kg ^ ((n >> 3) & 3));
            bfr[ni] = *(const bf16x8*)&Bs[n * LPB + slot4];
        }
        #pragma unroll
        for (int mi = 0; mi < 4; mi++)
            #pragma unroll
            for (int ni = 0; ni < 4; ni++)
                acc[mi][ni] = __builtin_amdgcn_mfma_f32_16x16x32_bf16(
                    a[mi], bfr[ni], acc[mi][ni], 0, 0, 0);
        __syncthreads();
    }

    float* Cf = (float*)Cv;
    u16*   Cb = (u16*)Cv;
    #pragma unroll
    for (int mi = 0; mi < 4; mi++) {
        #pragma unroll
        for (int ni = 0; ni < 4; ni++) {
            int col = n0 + wc * 64 + ni * 16 + fr;
            if (col >= Ncol) continue;
            #pragma unroll
            for (int r = 0; r < 4; r++) {
                int row = m0 + wr * 64 + mi * 16 + kg * 4 + r;
                float x = acc[mi][ni][r];
                if (BIASMODE == 1) x += bias[col];
                else if (BIASMODE == 2) x += bias[(size_t)(row >> 6) * cF + col];
                if (ACT) x = fmaxf(x, 0.f);
                if (OBF) Cb[(size_t)row * Ncol + col] = f2bf(x);
                else     Cf[(size_t)row * Ncol + col] = x;
            }
        }
    }
}

// ---------------- f32 tiled GEMM (head) ----------------
template<int BIASMODE, int ACT>
__global__ __launch_bounds__(256) void gemm_f32(const float* __restrict__ A,
                                                const float* __restrict__ Bm,
                                                const float* __restrict__ bias,
                                                float* __restrict__ C,
                                                int M, int Ncol, int K) {
    __shared__ float As[16][65];
    __shared__ float Bs[16][65];
    int bx = blockIdx.x, by = blockIdx.y;
    int tid = threadIdx.x;
    int tx = tid & 15, ty = tid >> 4;
    int row0 = by * 64, col0 = bx * 64;
    float acc[4][4] = {};
    for (int k0 = 0; k0 < K; k0 += 16) {
        {
            int r  = tid >> 2;
            int kk = (tid & 3) * 4;
            int gr = row0 + r;
            #pragma unroll
            for (int i = 0; i < 4; i++) {
                int gk = k0 + kk + i;
                As[kk + i][r] = (gr < M && gk < K) ? A[(size_t)gr * K + gk] : 0.f;
            }
        }
        {
            int kr = tid >> 4;
            int c  = (tid & 15) * 4;
            int gk = k0 + kr;
            #pragma unroll
            for (int i = 0; i < 4; i++) {
                int gc = col0 + c + i;
                Bs[kr][c + i] = (gk < K && gc < Ncol) ? Bm[(size_t)gk * Ncol + gc] : 0.f;
            }
        }
        __syncthreads();
        #pragma unroll
        for (int kk = 0; kk < 16; kk++) {
            float a[4], bv[4];
            #pragma unroll
            for (int i = 0; i < 4; i++) a[i]  = As[kk][ty * 4 + i];
            #pragma unroll
            for (int j = 0; j < 4; j++) bv[j] = Bs[kk][tx * 4 + j];
            #pragma unroll
            for (int i = 0; i < 4; i++)
                #pragma unroll
                for (int j = 0; j < 4; j++)
                    acc[i][j] += a[i] * bv[j];
        }
        __syncthreads();
    }
    #pragma unroll
    for (int i = 0; i < 4; i++) {
        int r = row0 + ty * 4 + i;
        if (r >= M) continue;
        #pragma unroll
        for (int j = 0; j < 4; j++) {
            int c = col0 + tx * 4 + j;
            if (c >= Ncol) continue;
            float v = acc[i][j];
            if (BIASMODE == 1) v += bias[c];
            if (ACT == 1) v = fmaxf(v, 0.f);
            C[(size_t)r * Ncol + c] = v;
        }
    }
}

// ---------------- split-K f32 GEMM for the Gram matrix ----------------
// P[z][M][Ncol] partial over K-slice z of size KS. Grid (Ncol/64, M/64, K/KS).
__global__ __launch_bounds__(256) void gemm_f32_splitk(const float* __restrict__ A,
                                                       const float* __restrict__ Bm,
                                                       float* __restrict__ P,
                                                       int M, int Ncol, int K, int KS) {
    __shared__ float As[16][65];
    __shared__ float Bs[16][65];
    int bx = blockIdx.x, by = blockIdx.y, bz = blockIdx.z;
    int tid = threadIdx.x;
    int tx = tid & 15, ty = tid >> 4;
    int row0 = by * 64, col0 = bx * 64;
    int kbeg = bz * KS;
    float acc[4][4] = {};
    for (int k0 = kbeg; k0 < kbeg + KS; k0 += 16) {
        {
            int r  = tid >> 2;
            int kk = (tid & 3) * 4;
            int gr = row0 + r;
            #pragma unroll
            for (int i = 0; i < 4; i++) {
                int gk = k0 + kk + i;
                As[kk + i][r] = (gr < M && gk < K) ? A[(size_t)gr * K + gk] : 0.f;
            }
        }
        {
            int kr = tid >> 4;
            int c  = (tid & 15) * 4;
            int gk = k0 + kr;
            #pragma unroll
            for (int i = 0; i < 4; i++) {
                int gc = col0 + c + i;
                Bs[kr][c + i] = (gk < K && gc < Ncol) ? Bm[(size_t)gk * Ncol + gc] : 0.f;
            }
        }
        __syncthreads();
        #pragma unroll
        for (int kk = 0; kk < 16; kk++) {
            float a[4], bv[4];
            #pragma unroll
            for (int i = 0; i < 4; i++) a[i]  = As[kk][ty * 4 + i];
            #pragma unroll
            for (int j = 0; j < 4; j++) bv[j] = Bs[kk][tx * 4 + j];
            #pragma unroll
            for (int i = 0; i < 4; i++)
                #pragma unroll
                for (int j = 0; j < 4; j++)
                    acc[i][j] += a[i] * bv[j];
        }
        __syncthreads();
    }
    size_t zoff = (size_t)bz * M * Ncol;
    #pragma unroll
    for (int i = 0; i < 4; i++) {
        int r = row0 + ty * 4 + i;
        if (r >= M) continue;
        #pragma unroll
        for (int j = 0; j < 4; j++) {
            int c = col0 + tx * 4 + j;
            if (c >= Ncol) continue;
            P[zoff + (size_t)r * Ncol + c] = acc[i][j];
        }
    }
}

__global__ __launch_bounds__(256) void gram_reduce(const float* __restrict__ P,
                                                   float* __restrict__ G,
                                                   int total, int nz) {
    int e = blockIdx.x * 256 + threadIdx.x;
    if (e >= total) return;
    float s = 0.f;
    for (int z = 0; z < nz; z++) s += P[(size_t)z * total + e];
    G[e] = s;
}

// ---------------- obs_prop (wave-parallel, pre-validated) ----------------

__global__ __launch_bounds__(256) void sasr_kernel(const float* __restrict__ z,
                                                   const float* __restrict__ al,
                                                   const float* __restrict__ ar,
                                                   float* __restrict__ sa,
                                                   float* __restrict__ sr) {
    int row  = blockIdx.x * 4 + (threadIdx.x >> 6);
    int lane = threadIdx.x & 63;
    const float* zr = z + (size_t)row * cF;
    float a = 0.f, r = 0.f;
    for (int k = lane; k < cF; k += 64) {
        float v = zr[k];
        a += v * al[k];
        r += v * ar[k];
    }
    for (int off = 32; off; off >>= 1) {
        a += __shfl_xor(a, off);
        r += __shfl_xor(r, off);
    }
    if (lane == 0) { sa[row] = a; sr[row] = r; }
}

template<int WITH_EW>
__global__ __launch_bounds__(256) void alpha_kernel(const float* __restrict__ sa,
                                                    const float* __restrict__ sr,
                                                    const float* __restrict__ ew,
                                                    float* __restrict__ alpha) {
    int idx = blockIdx.x * 4 + (threadIdx.x >> 6);   // local b*64 + d
    int b = idx >> 6, d = idx & 63;
    int s = threadIdx.x & 63;
    float sc = sa[b * 64 + s] + sr[b * 64 + d];
    sc = sc >= 0.f ? sc : 0.2f * sc;
    size_t eidx = (size_t)b * cE + s * 64 + d;
    if (WITH_EW) sc *= ew[eidx];
    float m = sc;
    for (int off = 32; off; off >>= 1) m = fmaxf(m, __shfl_xor(m, off));
    float e = expf(sc - m);
    float zz = e;
    for (int off = 32; off; off >>= 1) zz += __shfl_xor(zz, off);
    alpha[eidx] = e / zz;
}

// dst[b,d,:] = sum_s alpha[b, s*64+d] * z[b,s,:]  (dst separate; OBF: bf16 out)
template<int OBF>
__global__ __launch_bounds__(256) void obs_out_k(const float* __restrict__ alpha,
                                                 const float* __restrict__ z,
                                                 void* __restrict__ dstv) {
    __shared__ float As[64][65];
    int b  = blockIdx.x, fc = blockIdx.y;
    int tid = threadIdx.x;
    for (int i = tid; i < cE; i += 256) As[i >> 6][i & 63] = alpha[(size_t)b * cE + i];
    __syncthreads();
    int f = fc * 256 + tid;
    float acc[64];
    #pragma unroll
    for (int d = 0; d < 64; d++) acc[d] = 0.f;
    for (int s = 0; s < 64; s++) {
        float zv = z[((size_t)b * 64 + s) * cF + f];
        #pragma unroll
        for (int d = 0; d < 64; d++) acc[d] += As[s][d] * zv;
    }
    float* df = (float*)dstv;
    u16*   db = (u16*)dstv;
    #pragma unroll
    for (int d = 0; d < 64; d++) {
        size_t o = ((size_t)b * 64 + d) * cF + f;
        if (OBF) db[o] = f2bf(acc[d]);
        else     df[o] = acc[d];
    }
}

// scatter out2 chunk + pe chunk -> trx chunk f32 AND bf16 (padded 288)
__global__ __launch_bounds__(256) void scatter_trx(const float* __restrict__ out2,
                                                   const float* __restrict__ pe_c,
                                                   float* __restrict__ trx_c,
                                                   u16* __restrict__ trxbf) {
    int r = blockIdx.x;                 // local row = b_local*256 + l
    int bl = r >> 8, l = r & 255;
    size_t obase = (size_t)r * cDTR;
    size_t bbase = (size_t)r * 288;
    for (int c = threadIdx.x; c < cDTR; c += 256) {
        float v;
        if (c < cDM) v = out2[((size_t)bl * 64 + (c >> 2)) * cF + l * 4 + (c & 3)];
        else         v = pe_c[(size_t)r * 16 + (c - cDM)];
        trx_c[obase + c] = v;
        trxbf[bbase + c] = f2bf(v);
    }
}

// ---------------- attention v3: K^T/V^T bf16 in LDS, Ps in LDS ----------------
constexpr int KT_S = 264;   // k-stride (u16): 528B rows, 16B-aligned, conflict-free
__global__ __launch_bounds__(256) void attn_kernel(const float* __restrict__ qkv,
                                                   const int* __restrict__ lengths,
                                                   u16* __restrict__ att) {
    __shared__ __align__(16) u16 Ks[cHD * KT_S];   // 35,904 B  K^T [d][k]
    __shared__ __align__(16) u16 Vs[cHD * KT_S];   // 35,904 B  V^T [d][k]
    __shared__ float Ps[4][cL];                    //  4,096 B
    int blk = blockIdx.x;
    int seg = blk & 3;
    int h   = (blk >> 2) & 3;
    int bl  = blk >> 4;
    int tid = threadIdx.x;
    int len = lengths[bl];

    {
        int k = tid;
        const float* krow = qkv + ((size_t)bl * cL + k) * 816 + cDTR + h * cHD;
        const float* vrow = krow + cDTR;
        for (int d = 0; d < cHD; d += 4) {
            float4 kv = *(const float4*)(krow + d);
            float4 vv = *(const float4*)(vrow + d);
            Ks[(d + 0) * KT_S + k] = f2bf(kv.x);
            Ks[(d + 1) * KT_S + k] = f2bf(kv.y);
            Ks[(d + 2) * KT_S + k] = f2bf(kv.z);
            Ks[(d + 3) * KT_S + k] = f2bf(kv.w);
            Vs[(d + 0) * KT_S + k] = f2bf(vv.x);
            Vs[(d + 1) * KT_S + k] = f2bf(vv.y);
            Vs[(d + 2) * KT_S + k] = f2bf(vv.z);
            Vs[(d + 3) * KT_S + k] = f2bf(vv.w);
        }
    }
    __syncthreads();

    int wave = tid >> 6, lane = tid & 63;
    const float scale = 0.12126781f;   // 1/sqrt(68)
    int d1 = 64 + (lane & 3);
    const u16* v0row = &Vs[lane * KT_S];
    const u16* v1row = &Vs[d1 * KT_S];

    for (int lq = seg * 64 + wave; lq < seg * 64 + 64; lq += 4) {
        size_t qbase = ((size_t)bl * cL + lq) * 816 + h * cHD;
        float acc[4] = {0.f, 0.f, 0.f, 0.f};
        for (int d = 0; d < cHD; d++) {
            float qd = qkv[qbase + d];           // wave-uniform scalar load
            const u16* kr = &Ks[d * KT_S + lane];
            acc[0] += qd * bf2f(kr[0]);
            acc[1] += qd * bf2f(kr[64]);
            acc[2] += qd * bf2f(kr[128]);
            acc[3] += qd * bf2f(kr[192]);
        }
        float sc[4];
        #pragma unroll
        for (int i = 0; i < 4; i++) {
            int lk = lane + i * 64;
            sc[i] = (lk >= len) ? -1e9f : acc[i] * scale;
        }
        float m = fmaxf(fmaxf(sc[0], sc[1]), fmaxf(sc[2], sc[3]));
        for (int off = 32; off; off >>= 1) m = fmaxf(m, __shfl_xor(m, off));
        float e[4], sum = 0.f;
        #pragma unroll
        for (int i = 0; i < 4; i++) { e[i] = expf(sc[i] - m); sum += e[i]; }
        for (int off = 32; off; off >>= 1) sum += __shfl_xor(sum, off);
        float inv = 1.0f / sum;
        #pragma unroll
        for (int i = 0; i < 4; i++) Ps[wave][lane + i * 64] = e[i] * inv;
        __syncthreads();

        float o0 = 0.f, o1 = 0.f;
        #pragma unroll 2
        for (int t8 = 0; t8 < 32; t8++) {
            int t = t8 * 8;
            f32x4 p0 = *(const f32x4*)&Ps[wave][t];
            f32x4 p1 = *(const f32x4*)&Ps[wave][t + 4];
            bf16x8 v0 = *(const bf16x8*)(v0row + t);
            bf16x8 v1 = *(const bf16x8*)(v1row + t);
            o0 += p0[0] * bf2f((u16)v0[0]) + p0[1] * bf2f((u16)v0[1])
                + p0[2] * bf2f((u16)v0[2]) + p0[3] * bf2f((u16)v0[3])
                + p1[0] * bf2f((u16)v0[4]) + p1[1] * bf2f((u16)v0[5])
                + p1[2] * bf2f((u16)v0[6]) + p1[3] * bf2f((u16)v0[7]);
            o1 += p0[0] * bf2f((u16)v1[0]) + p0[1] * bf2f((u16)v1[1])
                + p0[2] * bf2f((u16)v1[2]) + p0[3] * bf2f((u16)v1[3])
                + p1[0] * bf2f((u16)v1[4]) + p1[1] * bf2f((u16)v1[5])
                + p1[2] * bf2f((u16)v1[6]) + p1[3] * bf2f((u16)v1[7]);
        }
        size_t obase = ((size_t)bl * cL + lq) * 288 + h * cHD;
        att[obase + lane] = f2bf(o0);
        if (lane < 4) att[obase + 64 + lane] = f2bf(o1);
        __syncthreads();
    }
}

// ---------------- residual + layernorm (wave per row), fused bf16 out ----------------
__global__ __launch_bounds__(256) void resid_ln_kernel(float* __restrict__ x,
                                                       const float* __restrict__ res,
                                                       const float* __restrict__ g,
                                                       const float* __restrict__ bt,
                                                       u16* __restrict__ xbf) {
    int row  = blockIdx.x * 4 + (threadIdx.x >> 6);
    int lane = threadIdx.x & 63;
    size_t base = (size_t)row * cDTR;
    size_t bbase = (size_t)row * 288;
    float v[5];
    float sum = 0.f, sumsq = 0.f;
    #pragma unroll
    for (int k = 0; k < 5; k++) {
        int c = lane + k * 64;
        float t = 0.f;
        if (c < cDTR) t = x[base + c] + res[base + c];
        v[k] = t;
        sum += t;
        sumsq += t * t;
    }
    for (int off = 32; off; off >>= 1) {
        sum   += __shfl_xor(sum, off);
        sumsq += __shfl_xor(sumsq, off);
    }
    float mean = sum * (1.0f / cDTR);
    float var  = fmaxf(sumsq * (1.0f / cDTR) - mean * mean, 0.f);
    float rstd = 1.0f / sqrtf(var + 1e-5f);
    #pragma unroll
    for (int k = 0; k < 5; k++) {
        int c = lane + k * 64;
        if (c < cDTR) {
            float o = (v[k] - mean) * rstd * g[c] + bt[c];
            x[base + c] = o;
            xbf[bbase + c] = f2bf(o);
        }
    }
}

// ---------------- head ----------------

__global__ __launch_bounds__(256) void agg_kernel(const float* __restrict__ trxc,
                                                  const int* __restrict__ lengths,
                                                  const float* __restrict__ emb,
                                                  float* __restrict__ agg) {
    int b = blockIdx.x;   // local
    int len = lengths[b];
    float inv = 1.0f / ((float)len + 1.0f);
    for (int c = threadIdx.x; c < cDTR; c += 256) {
        float s = 0.f;
        for (int l = 0; l < len; l++) s += trxc[((size_t)b * cL + l) * cDTR + c];
        agg[(size_t)b * cDFIN + c] = s * inv;
    }
    for (int c = threadIdx.x; c < cN; c += 256)
        agg[(size_t)b * cDFIN + cDTR + c] = emb[b * cN + c];
}

__global__ __launch_bounds__(256) void mlp2_naive(const float* __restrict__ hm,
                                                  const float* __restrict__ w2,
                                                  const float* __restrict__ b2,
                                                  float* __restrict__ out) {
    int gid = blockIdx.x * 256 + threadIdx.x;
    if (gid >= cB * 2) return;
    int b = gid >> 1, c = gid & 1;
    float a = b2[c];
    for (int j = 0; j < cDFIN; j++) a += hm[(size_t)b * cDFIN + j] * w2[j * 2 + c];
    out[gid] = a;
}

// ---------------- distance ----------------

__global__ __launch_bounds__(256) void transpose_kernel(const float* __restrict__ a,
                                                        float* __restrict__ at) {
    int t = blockIdx.x * 256 + threadIdx.x;   // b*4096 + e
    int b = t >> 12, e = t & 4095;
    at[(size_t)e * cB + b] = a[t];
}

__global__ __launch_bounds__(256) void dist_rows(const float* __restrict__ G,
                                                 float* __restrict__ part) {
    __shared__ float red[256];
    int i = blockIdx.x, j = threadIdx.x;
    float d2 = fmaxf(G[i * cB + i] + G[j * cB + j] - 2.0f * G[i * cB + j], 0.0f);
    red[j] = sqrtf(d2);
    __syncthreads();
    for (int s = 128; s; s >>= 1) {
        if (j < s) red[j] += red[j + s];
        __syncthreads();
    }
    if (j == 0) part[i] = red[0];
}

__global__ void dist_final_naive(const float* __restrict__ part,
                                 float* __restrict__ out) {
    if (threadIdx.x == 0 && blockIdx.x == 0) {
        float s = 0.f;
        for (int i = 0; i < cB; i++) s += part[i];
        out[512] = s * (1.0f / 65536.0f);
    }
}

// ---------------- launch ----------------

extern "C" void kernel_launch(void* const* d_in, const int* in_sizes, int n_in,
                              void* d_out, int out_size, void* d_ws, size_t ws_size,
                              hipStream_t stream) {
    const float* src     = (const float*)d_in[0];
    const float* statin  = (const float*)d_in[1];
    const float* times   = (const float*)d_in[2];
    const int*   lengths = (const int*)  d_in[3];
    const float* R_u     = (const float*)d_in[4];
    const float* emb_w   = (const float*)d_in[5];
    const float* emb_b   = (const float*)d_in[6];
    const float* op1_W   = (const float*)d_in[7];
    const float* op1_al  = (const float*)d_in[8];
    const float* op1_ar  = (const float*)d_in[9];
    const float* op1_wp  = (const float*)d_in[10];
    const float* op2_W   = (const float*)d_in[11];
    const float* op2_al  = (const float*)d_in[12];
    const float* op2_ar  = (const float*)d_in[13];
    const float* op2_wp  = (const float*)d_in[14];
    const float* tr_wqkv = (const float*)d_in[15];
    const float* tr_bqkv = (const float*)d_in[16];
    const float* tr_wo   = (const float*)d_in[17];
    const float* tr_bo   = (const float*)d_in[18];
    const float* tr_ln1g = (const float*)d_in[19];
    const float* tr_ln1b = (const float*)d_in[20];
    const float* tr_w1   = (const float*)d_in[21];
    const float* tr_b1   = (const float*)d_in[22];
    const float* tr_w2   = (const float*)d_in[23];
    const float* tr_b2   = (const float*)d_in[24];
    const float* tr_ln2g = (const float*)d_in[25];
    const float* tr_ln2b = (const float*)d_in[26];
    const float* mlp_w1  = (const float*)d_in[27];
    const float* mlp_b1  = (const float*)d_in[28];
    const float* mlp_w2  = (const float*)d_in[29];
    const float* mlp_b2  = (const float*)d_in[30];

    float* ws = (float*)d_ws;
    float* out = (float*)d_out;

    float* PE    = ws + O_PE;
    float* TRXC  = ws + O_TRXC;
    float* CH0   = ws + O_CH0;
    float* CH1   = ws + O_CH1;
    int*   LEN   = (int*)(ws + O_LEN);
    u16*   W1o   = (u16*)(ws + O_W1o);
    u16*   W2o   = (u16*)(ws + O_W2o);
    u16*   WQKV  = (u16*)(ws + O_WQKV);
    u16*   WO    = (u16*)(ws + O_WO);
    u16*   W1t   = (u16*)(ws + O_W1t);
    u16*   W2t   = (u16*)(ws + O_W2t);
    u16*   XBBF  = (u16*)(ws + O_XBBF);
    u16*   O1BF  = (u16*)(ws + O_O1BF);
    u16*   TRXBF = (u16*)(ws + O_TRXBF);
    u16*   ATTBF = (u16*)(ws + O_ATTBF);
    u16*   HIDBF = (u16*)(ws + O_HIDBF);

    // ---- setup ----
    fix_lengths<<<1, 256, 0, stream>>>(lengths, LEN);
    pe_kernel<<<cLB / 256, 256, 0, stream>>>(times, PE);
    pemean_naive<<<(cB * 16 + 255) / 256, 256, 0, stream>>>(PE, ws + O_PEM);
    emb_kernel<<<cB, 64, 0, stream>>>(statin, emb_w, emb_b, ws + O_EMB);
    bias_kernel<<<cB * cF / 256, 256, 0, stream>>>(ws + O_PEM, op1_wp, ws + O_BIAS1);
    bias_kernel<<<cB * cF / 256, 256, 0, stream>>>(ws + O_PEM, op2_wp, ws + O_BIAS2);

    // ---- weight conversions (bf16, padded) ----
    cvt_pad<<<(1024 * 1024 + 255) / 256, 256, 0, stream>>>(op1_W, W1o, 1024, 1024, 1024, 1024 * 1024);
    cvt_pad<<<(1024 * 1024 + 255) / 256, 256, 0, stream>>>(op2_W, W2o, 1024, 1024, 1024, 1024 * 1024);
    for (int l = 0; l < 2; l++) {
        cvt_pad<<<(288 * 896 + 255) / 256, 256, 0, stream>>>(
            tr_wqkv + (size_t)l * 272 * 816, WQKV + (size_t)l * 288 * 896, 272, 816, 896, 288 * 896);
        cvt_pad<<<(288 * 384 + 255) / 256, 256, 0, stream>>>(
            tr_wo + (size_t)l * 272 * 272, WO + (size_t)l * 288 * 384, 272, 272, 384, 288 * 384);
        cvt_pad<<<(288 * 1024 + 255) / 256, 256, 0, stream>>>(
            tr_w1 + (size_t)l * 272 * 1024, W1t + (size_t)l * 288 * 1024, 272, 1024, 1024, 288 * 1024);
        cvt_pad<<<(1024 * 384 + 255) / 256, 256, 0, stream>>>(
            tr_w2 + (size_t)l * 1024 * 272, W2t + (size_t)l * 1024 * 384, 1024, 272, 384, 1024 * 384);
    }

    // ---- per-chunk pipeline ----
    for (int c = 0; c < NCHUNK; c++) {
        int b0 = c * BC;

        // obs_prop layer 1 (z in CH0, Ncol=1024)
        build_xb_bf<<<RC_OBS, 256, 0, stream>>>(src, R_u, b0, XBBF);
        gemm_bf<2, 0, 0><<<dim3(8, RC_OBS / 128), 256, 0, stream>>>(
            XBBF, W1o, ws + O_BIAS1 + (size_t)b0 * cF, CH0, RC_OBS, 1024, 1024, 1024);
        sasr_kernel<<<RC_OBS / 4, 256, 0, stream>>>(CH0, op1_al, op1_ar,
            ws + O_SA + b0 * 64, ws + O_SR + b0 * 64);
        alpha_kernel<0><<<RC_OBS / 4, 256, 0, stream>>>(
            ws + O_SA + b0 * 64, ws + O_SR + b0 * 64, nullptr,
            ws + O_AL1 + (size_t)b0 * cE);
        obs_out_k<1><<<dim3(BC, 4), 256, 0, stream>>>(
            ws + O_AL1 + (size_t)b0 * cE, CH0, O1BF);

        // obs_prop layer 2 (out2 f32 -> CH1)
        gemm_bf<2, 0, 0><<<dim3(8, RC_OBS / 128), 256, 0, stream>>>(
            O1BF, W2o, ws + O_BIAS2 + (size_t)b0 * cF, CH0, RC_OBS, 1024, 1024, 1024);
        sasr_kernel<<<RC_OBS / 4, 256, 0, stream>>>(CH0, op2_al, op2_ar,
            ws + O_SA + b0 * 64, ws + O_SR + b0 * 64);
        alpha_kernel<1><<<RC_OBS / 4, 256, 0, stream>>>(
            ws + O_SA + b0 * 64, ws + O_SR + b0 * 64,
            ws + O_AL1 + (size_t)b0 * cE, ws + O_AL2 + (size_t)b0 * cE);
        obs_out_k<0><<<dim3(BC, 4), 256, 0, stream>>>(
            ws + O_AL2 + (size_t)b0 * cE, CH0, CH1);

        // transformer input (f32 + bf16 fused)
        scatter_trx<<<RC_TR, 256, 0, stream>>>(
            CH1, PE + (size_t)b0 * cL * 16, TRXC, TRXBF);

        for (int l = 0; l < 2; l++) {
            const float* bqkv = tr_bqkv + (size_t)l * 816;
            const float* bo   = tr_bo   + (size_t)l * 272;
            const float* bb1  = tr_b1   + (size_t)l * cNH;
            const float* bb2  = tr_b2   + (size_t)l * 272;

            gemm_bf<1, 0, 0><<<dim3(7, RC_TR / 128), 256, 0, stream>>>(
                TRXBF, WQKV + (size_t)l * 288 * 896, bqkv, CH0, RC_TR, 816, 288, 896);
            attn_kernel<<<BC * 16, 256, 0, stream>>>(CH0, LEN + b0, ATTBF);
            gemm_bf<1, 0, 0><<<dim3(3, RC_TR / 128), 256, 0, stream>>>(
                ATTBF, WO + (size_t)l * 288 * 384, bo, CH1, RC_TR, 272, 288, 384);
            resid_ln_kernel<<<RC_TR / 4, 256, 0, stream>>>(
                TRXC, CH1, tr_ln1g + (size_t)l * cDTR, tr_ln1b + (size_t)l * cDTR, TRXBF);
            gemm_bf<1, 1, 1><<<dim3(8, RC_TR / 128), 256, 0, stream>>>(
                TRXBF, W1t + (size_t)l * 288 * 1024, bb1, HIDBF, RC_TR, 1024, 288, 1024);
            gemm_bf<1, 0, 0><<<dim3(3, RC_TR / 128), 256, 0, stream>>>(
                HIDBF, W2t + (size_t)l * 1024 * 384, bb2, CH1, RC_TR, 272, 1024, 384);
            resid_ln_kernel<<<RC_TR / 4, 256, 0, stream>>>(
                TRXC, CH1, tr_ln2g + (size_t)l * cDTR, tr_ln2b + (size_t)l * cDTR, TRXBF);
        }

        agg_kernel<<<BC, 256, 0, stream>>>(
            TRXC, LEN + b0, ws + O_EMB + (size_t)b0 * cN,
            ws + O_AGG + (size_t)b0 * cDFIN);
    }

    // ---- head ----
    gemm_f32<1, 1><<<dim3(6, 4), 256, 0, stream>>>(
        ws + O_AGG, mlp_w1, mlp_b1, ws + O_HMLP, cB, cDFIN, cDFIN);
    mlp2_naive<<<(cB * 2 + 255) / 256, 256, 0, stream>>>(
        ws + O_HMLP, mlp_w2, mlp_b2, out);

    // ---- distance from alpha2: split-K Gram (partials in dead CH0) ----
    transpose_kernel<<<cB * cE / 256, 256, 0, stream>>>(ws + O_AL2, ws + O_AL1);
    gemm_f32_splitk<<<dim3(4, 4, 32), 256, 0, stream>>>(
        ws + O_AL2, ws + O_AL1, CH0, cB, cB, cE, 128);
    gram_reduce<<<(cB * cB + 255) / 256, 256, 0, stream>>>(
        CH0, ws + O_GRAM, cB * cB, 32);
    dist_rows<<<cB, 256, 0, stream>>>(ws + O_GRAM, ws + O_DPART);
    dist_final_naive<<<1, 64, 0, stream>>>(ws + O_DPART, out);

    (void)in_sizes; (void)n_in; (void)out_size; (void)ws_size;
}

// Round 15
// 4220.543 us; speedup vs baseline: 1.2606x; 1.1585x over previous
//
#include <hip/hip_runtime.h>
#include <hip/hip_bf16.h>

// ---------------- problem constants ----------------
constexpr int cL   = 256;
constexpr int cB   = 256;
constexpr int cN   = 64;
constexpr int cF   = 1024;   // L*D_OB
constexpr int cDM  = 256;    // N*D_OB
constexpr int cDTR = 272;    // D_MODEL + D_PE
constexpr int cHD  = 68;     // D_TR / H
constexpr int cNH  = 1024;   // NHID
constexpr int cDST = 9;
constexpr int cDFIN= 336;    // D_TR + N
constexpr int cE   = 4096;   // N*N
constexpr int cLB  = cL * cB;   // 65536
constexpr int cBN  = cB * cN;   // 16384
constexpr int BC   = 64;        // batch chunk
constexpr int NCHUNK = cB / BC; // 4
constexpr int RC_OBS = BC * cN;   // 4096 rows per obs chunk
constexpr int RC_TR  = BC * cL;   // 16384 rows per transformer chunk

using u16 = unsigned short;
using u32 = unsigned int;
typedef short bf16x8 __attribute__((ext_vector_type(8)));
typedef float f32x4  __attribute__((ext_vector_type(4)));
typedef u16   u16x4  __attribute__((ext_vector_type(4)));

__device__ inline u16 f2bf(float x) {            // RNE f32->bf16
    unsigned int u = __float_as_uint(x);
    unsigned int r = (u + 0x7FFFu + ((u >> 16) & 1u)) >> 16;
    return (u16)r;
}
__device__ inline float bf2f(u16 x) {
    return __uint_as_float(((u32)x) << 16);
}

// ---------------- workspace layout (float words), ~183MB ----------------
constexpr size_t O_PE    = 0;                               // LB*16 (b,l,16)
constexpr size_t O_PEM   = O_PE    + (size_t)cLB*16;
constexpr size_t O_EMB   = O_PEM   + (size_t)cB*16;
constexpr size_t O_BIAS1 = O_EMB   + (size_t)cB*64;
constexpr size_t O_BIAS2 = O_BIAS1 + (size_t)cB*cF;
constexpr size_t O_SA    = O_BIAS2 + (size_t)cB*cF;
constexpr size_t O_SR    = O_SA    + (size_t)cBN;
constexpr size_t O_AL1   = O_SR    + (size_t)cBN;           // B*E
constexpr size_t O_AL2   = O_AL1   + (size_t)cB*cE;         // B*E
constexpr size_t O_GRAM  = O_AL2   + (size_t)cB*cE;         // B*B
constexpr size_t O_DPART = O_GRAM  + (size_t)cB*cB;         // B
constexpr size_t O_AGG   = O_DPART + (size_t)cB;            // B*336
constexpr size_t O_HMLP  = O_AGG   + (size_t)cB*cDFIN;      // B*336
constexpr size_t O_LEN   = O_HMLP  + (size_t)cB*cDFIN;      // B ints
// bf16 buffers (word counts = elems/2)
constexpr size_t O_W1o   = O_LEN   + (size_t)cB;            // 1024x1024
constexpr size_t O_W2o   = O_W1o   + 524288;                // 1024x1024
constexpr size_t O_WQKV  = O_W2o   + 524288;                // 2 x 288x896
constexpr size_t O_WO    = O_WQKV  + 258048;                // 2 x 288x384
constexpr size_t O_W1t   = O_WO    + 110592;                // 2 x 288x1024
constexpr size_t O_W2t   = O_W1t   + 294912;                // 2 x 1024x384
constexpr size_t O_XBBF  = O_W2t   + 393216;                // 4096x1024 bf16
constexpr size_t O_O1BF  = O_XBBF  + 2097152;               // 4096x1024 bf16
constexpr size_t O_TRXBF = O_O1BF  + 2097152;               // 16384x288 bf16
constexpr size_t O_ATTBF = O_TRXBF + 2359296;               // 16384x288 bf16
constexpr size_t O_HIDBF = O_ATTBF + 2359296;               // 16384x1024 bf16
constexpr size_t O_TRXC  = O_HIDBF + 8388608;               // 16384x272 f32
constexpr size_t O_CH0   = O_TRXC  + (size_t)RC_TR*cDTR;    // 16384x816 f32 (qkv / obs z / gram partials)
constexpr size_t O_CH1   = O_CH0   + (size_t)RC_TR*816;     // max(4096x1024, 16384x272) f32
constexpr size_t WS_END  = O_CH1   + (size_t)RC_TR*cDTR;    // ~45.7M words

// ---------------- lengths canonicalization ----------------
__global__ void fix_lengths(const int* __restrict__ raw, int* __restrict__ canon) {
    __shared__ int odd_nonzero;
    if (threadIdx.x == 0) odd_nonzero = 0;
    __syncthreads();
    int t = threadIdx.x;
    int w = raw[t];
    if ((t & 1) && w != 0) odd_nonzero = 1;
    __syncthreads();
    if (odd_nonzero) canon[t] = raw[t];
    else             canon[t] = raw[2 * t];
}

// ---------------- setup kernels ----------------

__global__ __launch_bounds__(256) void pe_kernel(const float* __restrict__ times,
                                                 float* __restrict__ pe) {
    int t = blockIdx.x * 256 + threadIdx.x;   // t = b*256 + l
    int b = t >> 8, l = t & 255;
    float tv = times[l * cB + b];
    #pragma unroll
    for (int i = 0; i < 8; i++) {
        float ts = exp2f((8.0f * i) / 7.0f);  // 256^(i/7)
        float sc = tv / ts;
        pe[(size_t)t * 16 + i]     = sinf(sc);
        pe[(size_t)t * 16 + 8 + i] = cosf(sc);
    }
}

__global__ __launch_bounds__(256) void pemean_naive(const float* __restrict__ pe,
                                                    float* __restrict__ pm) {
    int gid = blockIdx.x * 256 + threadIdx.x;
    if (gid >= cB * 16) return;
    int b = gid >> 4, i = gid & 15;
    float s = 0.f;
    for (int l = 0; l < cL; l++) s += pe[((size_t)b * cL + l) * 16 + i];
    pm[gid] = s * (1.0f / 256.0f);
}

__global__ __launch_bounds__(64) void emb_kernel(const float* __restrict__ st,
                                                 const float* __restrict__ w,
                                                 const float* __restrict__ bb,
                                                 float* __restrict__ emb) {
    int b = blockIdx.x, n = threadIdx.x;
    float s = bb[n];
    #pragma unroll
    for (int k = 0; k < cDST; k++) s += st[b * cDST + k] * w[k * cN + n];
    emb[b * cN + n] = s;
}

__global__ __launch_bounds__(256) void bias_kernel(const float* __restrict__ pm,
                                                   const float* __restrict__ wp,
                                                   float* __restrict__ bias) {
    int t = blockIdx.x * 256 + threadIdx.x;   // b*1024 + f
    int b = t >> 10, f = t & 1023;
    float s = 0.f;
    #pragma unroll
    for (int i = 0; i < 16; i++) s += pm[b * 16 + i] * wp[i * cF + f];
    bias[t] = s;
}

// f32 [K][N] -> bf16 [KP][NP], zero padded (weights only)
__global__ __launch_bounds__(256) void cvt_pad(const float* __restrict__ in,
                                               u16* __restrict__ out,
                                               int K, int N, int NP, int total) {
    int gid = blockIdx.x * 256 + threadIdx.x;
    if (gid >= total) return;
    int r = gid / NP, c = gid - r * NP;
    float v = (r < K && c < N) ? in[(size_t)r * N + c] : 0.f;
    out[gid] = f2bf(v);
}

// xb_bf[r,1024] bf16 for local rows r = b_local*64 + n of chunk b0
__global__ __launch_bounds__(256) void build_xb_bf(const float* __restrict__ src,
                                                   const float* __restrict__ R_u,
                                                   int b0,
                                                   u16* __restrict__ xb) {
    int r = blockIdx.x;
    int l = threadIdx.x;
    int b = b0 + (r >> 6), n = r & 63;
    float s = src[((size_t)l * cB + b) * 128 + n];
    float4 rr = *(const float4*)(R_u + n * 4);
    u16x4 o;
    o[0] = f2bf(fmaxf(s * rr.x, 0.f));
    o[1] = f2bf(fmaxf(s * rr.y, 0.f));
    o[2] = f2bf(fmaxf(s * rr.z, 0.f));
    o[3] = f2bf(fmaxf(s * rr.w, 0.f));
    *(u16x4*)(xb + (size_t)r * cF + l * 4) = o;
}

// ---------------- bf16 MFMA GEMM: C(MxNcol) = A(M x KP) * B(KP x NP) ----------------
template<int BIASMODE, int ACT, int OBF>
__global__ __launch_bounds__(256) void gemm_bf(const u16* __restrict__ A,
                                               const u16* __restrict__ B,
                                               const float* __restrict__ bias,
                                               void* __restrict__ Cv,
                                               int M, int Ncol, int KP, int NP) {
    constexpr int LPA = 40;                 // u16 stride for A rows (80B)
    constexpr int LPB = 20;                 // u32 stride for B n-rows (80B)
    __shared__ u16 As[128 * LPA];           // 10 KB
    __shared__ u32 Bs[128 * LPB];           // 10 KB
    int tid = threadIdx.x;
    int m0 = blockIdx.y * 128;
    int n0 = blockIdx.x * 128;
    int w = tid >> 6, lane = tid & 63;
    int wr = w >> 1, wc = w & 1;
    int fr = lane & 15, kg = lane >> 4;

    f32x4 acc[4][4];
    #pragma unroll
    for (int mi = 0; mi < 4; mi++)
        #pragma unroll
        for (int ni = 0; ni < 4; ni++)
            acc[mi][ni] = (f32x4){0.f, 0.f, 0.f, 0.f};

    int arow = tid >> 1, ah = (tid & 1) * 16;
    int bkp = tid >> 4;              // k-pair slot 0..15
    int bnb = (tid & 15) * 8;        // n offset 0..120

    for (int k0 = 0; k0 < KP; k0 += 32) {
        const uint4* ga = (const uint4*)(A + (size_t)(m0 + arow) * KP + k0 + ah);
        *(uint4*)&As[arow * LPA + ah]     = ga[0];
        *(uint4*)&As[arow * LPA + ah + 8] = ga[1];
        const u16* bp0 = B + (size_t)(k0 + 2 * bkp) * NP + n0 + bnb;
        uint4 r0 = *(const uint4*)bp0;
        uint4 r1 = *(const uint4*)(bp0 + NP);
        const u16* e0 = (const u16*)&r0;
        const u16* e1 = (const u16*)&r1;
        #pragma unroll
        for (int j = 0; j < 8; j++) {
            int n = bnb + j;
            int slot = bkp ^ (((n >> 3) & 3) << 2);
            Bs[n * LPB + slot] = (u32)e0[j] | ((u32)e1[j] << 16);
        }
        __syncthreads();

        bf16x8 a[4], bfr[4];
        #pragma unroll
        for (int mi = 0; mi < 4; mi++)
            a[mi] = *(const bf16x8*)&As[(wr * 64 + mi * 16 + fr) * LPA + kg * 8];
        #pragma unroll
        for (int ni = 0; ni < 4; ni++) {
            int n = wc * 64 + ni * 16 + fr;
            int slot4 = 4 * (kg ^ ((n >> 3) & 3));
            bfr[ni] = *(const bf16x8*)&Bs[n * LPB + slot4];
        }
        #pragma unroll
        for (int mi = 0; mi < 4; mi++)
            #pragma unroll
            for (int ni = 0; ni < 4; ni++)
                acc[mi][ni] = __builtin_amdgcn_mfma_f32_16x16x32_bf16(
                    a[mi], bfr[ni], acc[mi][ni], 0, 0, 0);
        __syncthreads();
    }

    float* Cf = (float*)Cv;
    u16*   Cb = (u16*)Cv;
    #pragma unroll
    for (int mi = 0; mi < 4; mi++) {
        #pragma unroll
        for (int ni = 0; ni < 4; ni++) {
            int col = n0 + wc * 64 + ni * 16 + fr;
            if (col >= Ncol) continue;
            #pragma unroll
            for (int r = 0; r < 4; r++) {
                int row = m0 + wr * 64 + mi * 16 + kg * 4 + r;
                float x = acc[mi][ni][r];
                if (BIASMODE == 1) x += bias[col];
                else if (BIASMODE == 2) x += bias[(size_t)(row >> 6) * cF + col];
                if (ACT) x = fmaxf(x, 0.f);
                if (OBF) Cb[(size_t)row * Ncol + col] = f2bf(x);
                else     Cf[(size_t)row * Ncol + col] = x;
            }
        }
    }
}

// ---------------- f32 tiled GEMM (head) ----------------
template<int BIASMODE, int ACT>
__global__ __launch_bounds__(256) void gemm_f32(const float* __restrict__ A,
                                                const float* __restrict__ Bm,
                                                const float* __restrict__ bias,
                                                float* __restrict__ C,
                                                int M, int Ncol, int K) {
    __shared__ float As[16][65];
    __shared__ float Bs[16][65];
    int bx = blockIdx.x, by = blockIdx.y;
    int tid = threadIdx.x;
    int tx = tid & 15, ty = tid >> 4;
    int row0 = by * 64, col0 = bx * 64;
    float acc[4][4] = {};
    for (int k0 = 0; k0 < K; k0 += 16) {
        {
            int r  = tid >> 2;
            int kk = (tid & 3) * 4;
            int gr = row0 + r;
            #pragma unroll
            for (int i = 0; i < 4; i++) {
                int gk = k0 + kk + i;
                As[kk + i][r] = (gr < M && gk < K) ? A[(size_t)gr * K + gk] : 0.f;
            }
        }
        {
            int kr = tid >> 4;
            int c  = (tid & 15) * 4;
            int gk = k0 + kr;
            #pragma unroll
            for (int i = 0; i < 4; i++) {
                int gc = col0 + c + i;
                Bs[kr][c + i] = (gk < K && gc < Ncol) ? Bm[(size_t)gk * Ncol + gc] : 0.f;
            }
        }
        __syncthreads();
        #pragma unroll
        for (int kk = 0; kk < 16; kk++) {
            float a[4], bv[4];
            #pragma unroll
            for (int i = 0; i < 4; i++) a[i]  = As[kk][ty * 4 + i];
            #pragma unroll
            for (int j = 0; j < 4; j++) bv[j] = Bs[kk][tx * 4 + j];
            #pragma unroll
            for (int i = 0; i < 4; i++)
                #pragma unroll
                for (int j = 0; j < 4; j++)
                    acc[i][j] += a[i] * bv[j];
        }
        __syncthreads();
    }
    #pragma unroll
    for (int i = 0; i < 4; i++) {
        int r = row0 + ty * 4 + i;
        if (r >= M) continue;
        #pragma unroll
        for (int j = 0; j < 4; j++) {
            int c = col0 + tx * 4 + j;
            if (c >= Ncol) continue;
            float v = acc[i][j];
            if (BIASMODE == 1) v += bias[c];
            if (ACT == 1) v = fmaxf(v, 0.f);
            C[(size_t)r * Ncol + c] = v;
        }
    }
}

// ---------------- split-K f32 GEMM for the Gram matrix ----------------
__global__ __launch_bounds__(256) void gemm_f32_splitk(const float* __restrict__ A,
                                                       const float* __restrict__ Bm,
                                                       float* __restrict__ P,
                                                       int M, int Ncol, int K, int KS) {
    __shared__ float As[16][65];
    __shared__ float Bs[16][65];
    int bx = blockIdx.x, by = blockIdx.y, bz = blockIdx.z;
    int tid = threadIdx.x;
    int tx = tid & 15, ty = tid >> 4;
    int row0 = by * 64, col0 = bx * 64;
    int kbeg = bz * KS;
    float acc[4][4] = {};
    for (int k0 = kbeg; k0 < kbeg + KS; k0 += 16) {
        {
            int r  = tid >> 2;
            int kk = (tid & 3) * 4;
            int gr = row0 + r;
            #pragma unroll
            for (int i = 0; i < 4; i++) {
                int gk = k0 + kk + i;
                As[kk + i][r] = (gr < M && gk < K) ? A[(size_t)gr * K + gk] : 0.f;
            }
        }
        {
            int kr = tid >> 4;
            int c  = (tid & 15) * 4;
            int gk = k0 + kr;
            #pragma unroll
            for (int i = 0; i < 4; i++) {
                int gc = col0 + c + i;
                Bs[kr][c + i] = (gk < K && gc < Ncol) ? Bm[(size_t)gk * Ncol + gc] : 0.f;
            }
        }
        __syncthreads();
        #pragma unroll
        for (int kk = 0; kk < 16; kk++) {
            float a[4], bv[4];
            #pragma unroll
            for (int i = 0; i < 4; i++) a[i]  = As[kk][ty * 4 + i];
            #pragma unroll
            for (int j = 0; j < 4; j++) bv[j] = Bs[kk][tx * 4 + j];
            #pragma unroll
            for (int i = 0; i < 4; i++)
                #pragma unroll
                for (int j = 0; j < 4; j++)
                    acc[i][j] += a[i] * bv[j];
        }
        __syncthreads();
    }
    size_t zoff = (size_t)bz * M * Ncol;
    #pragma unroll
    for (int i = 0; i < 4; i++) {
        int r = row0 + ty * 4 + i;
        if (r >= M) continue;
        #pragma unroll
        for (int j = 0; j < 4; j++) {
            int c = col0 + tx * 4 + j;
            if (c >= Ncol) continue;
            P[zoff + (size_t)r * Ncol + c] = acc[i][j];
        }
    }
}

__global__ __launch_bounds__(256) void gram_reduce(const float* __restrict__ P,
                                                   float* __restrict__ G,
                                                   int total, int nz) {
    int e = blockIdx.x * 256 + threadIdx.x;
    if (e >= total) return;
    float s = 0.f;
    for (int z = 0; z < nz; z++) s += P[(size_t)z * total + e];
    G[e] = s;
}

// ---------------- obs_prop (wave-parallel, pre-validated) ----------------

__global__ __launch_bounds__(256) void sasr_kernel(const float* __restrict__ z,
                                                   const float* __restrict__ al,
                                                   const float* __restrict__ ar,
                                                   float* __restrict__ sa,
                                                   float* __restrict__ sr) {
    int row  = blockIdx.x * 4 + (threadIdx.x >> 6);
    int lane = threadIdx.x & 63;
    const float* zr = z + (size_t)row * cF;
    float a = 0.f, r = 0.f;
    for (int k = lane; k < cF; k += 64) {
        float v = zr[k];
        a += v * al[k];
        r += v * ar[k];
    }
    for (int off = 32; off; off >>= 1) {
        a += __shfl_xor(a, off);
        r += __shfl_xor(r, off);
    }
    if (lane == 0) { sa[row] = a; sr[row] = r; }
}

template<int WITH_EW>
__global__ __launch_bounds__(256) void alpha_kernel(const float* __restrict__ sa,
                                                    const float* __restrict__ sr,
                                                    const float* __restrict__ ew,
                                                    float* __restrict__ alpha) {
    int idx = blockIdx.x * 4 + (threadIdx.x >> 6);   // local b*64 + d
    int b = idx >> 6, d = idx & 63;
    int s = threadIdx.x & 63;
    float sc = sa[b * 64 + s] + sr[b * 64 + d];
    sc = sc >= 0.f ? sc : 0.2f * sc;
    size_t eidx = (size_t)b * cE + s * 64 + d;
    if (WITH_EW) sc *= ew[eidx];
    float m = sc;
    for (int off = 32; off; off >>= 1) m = fmaxf(m, __shfl_xor(m, off));
    float e = expf(sc - m);
    float zz = e;
    for (int off = 32; off; off >>= 1) zz += __shfl_xor(zz, off);
    alpha[eidx] = e / zz;
}

// dst[b,d,:] = sum_s alpha[b, s*64+d] * z[b,s,:]  (dst separate; OBF: bf16 out)
template<int OBF>
__global__ __launch_bounds__(256) void obs_out_k(const float* __restrict__ alpha,
                                                 const float* __restrict__ z,
                                                 void* __restrict__ dstv) {
    __shared__ float As[64][65];
    int b  = blockIdx.x, fc = blockIdx.y;
    int tid = threadIdx.x;
    for (int i = tid; i < cE; i += 256) As[i >> 6][i & 63] = alpha[(size_t)b * cE + i];
    __syncthreads();
    int f = fc * 256 + tid;
    float acc[64];
    #pragma unroll
    for (int d = 0; d < 64; d++) acc[d] = 0.f;
    for (int s = 0; s < 64; s++) {
        float zv = z[((size_t)b * 64 + s) * cF + f];
        #pragma unroll
        for (int d = 0; d < 64; d++) acc[d] += As[s][d] * zv;
    }
    float* df = (float*)dstv;
    u16*   db = (u16*)dstv;
    #pragma unroll
    for (int d = 0; d < 64; d++) {
        size_t o = ((size_t)b * 64 + d) * cF + f;
        if (OBF) db[o] = f2bf(acc[d]);
        else     df[o] = acc[d];
    }
}

// scatter out2 chunk + pe chunk -> trx chunk f32 AND bf16 (padded 288)
__global__ __launch_bounds__(256) void scatter_trx(const float* __restrict__ out2,
                                                   const float* __restrict__ pe_c,
                                                   float* __restrict__ trx_c,
                                                   u16* __restrict__ trxbf) {
    int r = blockIdx.x;                 // local row = b_local*256 + l
    int bl = r >> 8, l = r & 255;
    size_t obase = (size_t)r * cDTR;
    size_t bbase = (size_t)r * 288;
    for (int c = threadIdx.x; c < cDTR; c += 256) {
        float v;
        if (c < cDM) v = out2[((size_t)bl * 64 + (c >> 2)) * cF + l * 4 + (c & 3)];
        else         v = pe_c[(size_t)r * 16 + (c - cDM)];
        trx_c[obase + c] = v;
        trxbf[bbase + c] = f2bf(v);
    }
}

// ---------------- attention v4: 8 waves share K^T/V^T; per-wave Ps, no inner barriers ----
constexpr int KT_S = 264;   // k-stride (u16): 528B rows, 16B-aligned, conflict-free
__global__ __launch_bounds__(512) void attn_kernel(const float* __restrict__ qkv,
                                                   const int* __restrict__ lengths,
                                                   u16* __restrict__ att) {
    __shared__ __align__(16) u16 Ks[cHD * KT_S];   // 35,904 B  K^T [d][k]
    __shared__ __align__(16) u16 Vs[cHD * KT_S];   // 35,904 B  V^T [d][k]
    __shared__ float Ps[8][cL];                    //  8,192 B  -> total 80,000 B (2 blocks/CU)
    int blk = blockIdx.x;
    int seg = blk & 1;
    int h   = (blk >> 1) & 3;
    int bl  = blk >> 3;
    int tid = threadIdx.x;
    int len = lengths[bl];

    // stage: thread t -> k = t&255, d-half = t>>8 (0: d 0..35, 1: d 36..67)
    {
        int k = tid & 255;
        int half = tid >> 8;
        int dbeg = half ? 36 : 0;
        int dend = half ? 68 : 36;
        const float* krow = qkv + ((size_t)bl * cL + k) * 816 + cDTR + h * cHD;
        const float* vrow = krow + cDTR;
        for (int d = dbeg; d < dend; d += 4) {
            float4 kv = *(const float4*)(krow + d);
            float4 vv = *(const float4*)(vrow + d);
            Ks[(d + 0) * KT_S + k] = f2bf(kv.x);
            Ks[(d + 1) * KT_S + k] = f2bf(kv.y);
            Ks[(d + 2) * KT_S + k] = f2bf(kv.z);
            Ks[(d + 3) * KT_S + k] = f2bf(kv.w);
            Vs[(d + 0) * KT_S + k] = f2bf(vv.x);
            Vs[(d + 1) * KT_S + k] = f2bf(vv.y);
            Vs[(d + 2) * KT_S + k] = f2bf(vv.z);
            Vs[(d + 3) * KT_S + k] = f2bf(vv.w);
        }
    }
    __syncthreads();

    int wave = tid >> 6, lane = tid & 63;
    const float scale = 0.12126781f;   // 1/sqrt(68)
    int d1 = 64 + (lane & 3);
    const u16* v0row = &Vs[lane * KT_S];
    const u16* v1row = &Vs[d1 * KT_S];

    // 8 waves x 16 q-rows each = 128 q-rows per block (seg selects half)
    for (int lq = seg * 128 + wave; lq < seg * 128 + 128; lq += 8) {
        size_t qbase = ((size_t)bl * cL + lq) * 816 + h * cHD;
        float acc[4] = {0.f, 0.f, 0.f, 0.f};
        for (int d = 0; d < cHD; d++) {
            float qd = qkv[qbase + d];           // wave-uniform scalar load
            const u16* kr = &Ks[d * KT_S + lane];
            acc[0] += qd * bf2f(kr[0]);
            acc[1] += qd * bf2f(kr[64]);
            acc[2] += qd * bf2f(kr[128]);
            acc[3] += qd * bf2f(kr[192]);
        }
        float sc[4];
        #pragma unroll
        for (int i = 0; i < 4; i++) {
            int lk = lane + i * 64;
            sc[i] = (lk >= len) ? -1e9f : acc[i] * scale;
        }
        float m = fmaxf(fmaxf(sc[0], sc[1]), fmaxf(sc[2], sc[3]));
        for (int off = 32; off; off >>= 1) m = fmaxf(m, __shfl_xor(m, off));
        float e[4], sum = 0.f;
        #pragma unroll
        for (int i = 0; i < 4; i++) { e[i] = expf(sc[i] - m); sum += e[i]; }
        for (int off = 32; off; off >>= 1) sum += __shfl_xor(sum, off);
        float inv = 1.0f / sum;
        #pragma unroll
        for (int i = 0; i < 4; i++) Ps[wave][lane + i * 64] = e[i] * inv;
        // Ps[wave] is private to this wave: within-wave LDS RAW needs no barrier
        // (single instruction stream; compiler inserts lgkmcnt for the aliasing access)

        float o0 = 0.f, o1 = 0.f;
        #pragma unroll 2
        for (int t8 = 0; t8 < 32; t8++) {
            int t = t8 * 8;
            f32x4 p0 = *(const f32x4*)&Ps[wave][t];
            f32x4 p1 = *(const f32x4*)&Ps[wave][t + 4];
            bf16x8 v0 = *(const bf16x8*)(v0row + t);
            bf16x8 v1 = *(const bf16x8*)(v1row + t);
            o0 += p0[0] * bf2f((u16)v0[0]) + p0[1] * bf2f((u16)v0[1])
                + p0[2] * bf2f((u16)v0[2]) + p0[3] * bf2f((u16)v0[3])
                + p1[0] * bf2f((u16)v0[4]) + p1[1] * bf2f((u16)v0[5])
                + p1[2] * bf2f((u16)v0[6]) + p1[3] * bf2f((u16)v0[7]);
            o1 += p0[0] * bf2f((u16)v1[0]) + p0[1] * bf2f((u16)v1[1])
                + p0[2] * bf2f((u16)v1[2]) + p0[3] * bf2f((u16)v1[3])
                + p1[0] * bf2f((u16)v1[4]) + p1[1] * bf2f((u16)v1[5])
                + p1[2] * bf2f((u16)v1[6]) + p1[3] * bf2f((u16)v1[7]);
        }
        size_t obase = ((size_t)bl * cL + lq) * 288 + h * cHD;
        att[obase + lane] = f2bf(o0);
        if (lane < 4) att[obase + 64 + lane] = f2bf(o1);
    }
}

// ---------------- residual + layernorm (wave per row), fused bf16 out ----------------
__global__ __launch_bounds__(256) void resid_ln_kernel(float* __restrict__ x,
                                                       const float* __restrict__ res,
                                                       const float* __restrict__ g,
                                                       const float* __restrict__ bt,
                                                       u16* __restrict__ xbf) {
    int row  = blockIdx.x * 4 + (threadIdx.x >> 6);
    int lane = threadIdx.x & 63;
    size_t base = (size_t)row * cDTR;
    size_t bbase = (size_t)row * 288;
    float v[5];
    float sum = 0.f, sumsq = 0.f;
    #pragma unroll
    for (int k = 0; k < 5; k++) {
        int c = lane + k * 64;
        float t = 0.f;
        if (c < cDTR) t = x[base + c] + res[base + c];
        v[k] = t;
        sum += t;
        sumsq += t * t;
    }
    for (int off = 32; off; off >>= 1) {
        sum   += __shfl_xor(sum, off);
        sumsq += __shfl_xor(sumsq, off);
    }
    float mean = sum * (1.0f / cDTR);
    float var  = fmaxf(sumsq * (1.0f / cDTR) - mean * mean, 0.f);
    float rstd = 1.0f / sqrtf(var + 1e-5f);
    #pragma unroll
    for (int k = 0; k < 5; k++) {
        int c = lane + k * 64;
        if (c < cDTR) {
            float o = (v[k] - mean) * rstd * g[c] + bt[c];
            x[base + c] = o;
            xbf[bbase + c] = f2bf(o);
        }
    }
}

// ---------------- head ----------------

__global__ __launch_bounds__(256) void agg_kernel(const float* __restrict__ trxc,
                                                  const int* __restrict__ lengths,
                                                  const float* __restrict__ emb,
                                                  float* __restrict__ agg) {
    int b = blockIdx.x;   // local
    int len = lengths[b];
    float inv = 1.0f / ((float)len + 1.0f);
    for (int c = threadIdx.x; c < cDTR; c += 256) {
        float s = 0.f;
        for (int l = 0; l < len; l++) s += trxc[((size_t)b * cL + l) * cDTR + c];
        agg[(size_t)b * cDFIN + c] = s * inv;
    }
    for (int c = threadIdx.x; c < cN; c += 256)
        agg[(size_t)b * cDFIN + cDTR + c] = emb[b * cN + c];
}

__global__ __launch_bounds__(256) void mlp2_naive(const float* __restrict__ hm,
                                                  const float* __restrict__ w2,
                                                  const float* __restrict__ b2,
                                                  float* __restrict__ out) {
    int gid = blockIdx.x * 256 + threadIdx.x;
    if (gid >= cB * 2) return;
    int b = gid >> 1, c = gid & 1;
    float a = b2[c];
    for (int j = 0; j < cDFIN; j++) a += hm[(size_t)b * cDFIN + j] * w2[j * 2 + c];
    out[gid] = a;
}

// ---------------- distance ----------------

__global__ __launch_bounds__(256) void transpose_kernel(const float* __restrict__ a,
                                                        float* __restrict__ at) {
    int t = blockIdx.x * 256 + threadIdx.x;   // b*4096 + e
    int b = t >> 12, e = t & 4095;
    at[(size_t)e * cB + b] = a[t];
}

__global__ __launch_bounds__(256) void dist_rows(const float* __restrict__ G,
                                                 float* __restrict__ part) {
    __shared__ float red[256];
    int i = blockIdx.x, j = threadIdx.x;
    float d2 = fmaxf(G[i * cB + i] + G[j * cB + j] - 2.0f * G[i * cB + j], 0.0f);
    red[j] = sqrtf(d2);
    __syncthreads();
    for (int s = 128; s; s >>= 1) {
        if (j < s) red[j] += red[j + s];
        __syncthreads();
    }
    if (j == 0) part[i] = red[0];
}

__global__ void dist_final_naive(const float* __restrict__ part,
                                 float* __restrict__ out) {
    if (threadIdx.x == 0 && blockIdx.x == 0) {
        float s = 0.f;
        for (int i = 0; i < cB; i++) s += part[i];
        out[512] = s * (1.0f / 65536.0f);
    }
}

// ---------------- launch ----------------

extern "C" void kernel_launch(void* const* d_in, const int* in_sizes, int n_in,
                              void* d_out, int out_size, void* d_ws, size_t ws_size,
                              hipStream_t stream) {
    const float* src     = (const float*)d_in[0];
    const float* statin  = (const float*)d_in[1];
    const float* times   = (const float*)d_in[2];
    const int*   lengths = (const int*)  d_in[3];
    const float* R_u     = (const float*)d_in[4];
    const float* emb_w   = (const float*)d_in[5];
    const float* emb_b   = (const float*)d_in[6];
    const float* op1_W   = (const float*)d_in[7];
    const float* op1_al  = (const float*)d_in[8];
    const float* op1_ar  = (const float*)d_in[9];
    const float* op1_wp  = (const float*)d_in[10];
    const float* op2_W   = (const float*)d_in[11];
    const float* op2_al  = (const float*)d_in[12];
    const float* op2_ar  = (const float*)d_in[13];
    const float* op2_wp  = (const float*)d_in[14];
    const float* tr_wqkv = (const float*)d_in[15];
    const float* tr_bqkv = (const float*)d_in[16];
    const float* tr_wo   = (const float*)d_in[17];
    const float* tr_bo   = (const float*)d_in[18];
    const float* tr_ln1g = (const float*)d_in[19];
    const float* tr_ln1b = (const float*)d_in[20];
    const float* tr_w1   = (const float*)d_in[21];
    const float* tr_b1   = (const float*)d_in[22];
    const float* tr_w2   = (const float*)d_in[23];
    const float* tr_b2   = (const float*)d_in[24];
    const float* tr_ln2g = (const float*)d_in[25];
    const float* tr_ln2b = (const float*)d_in[26];
    const float* mlp_w1  = (const float*)d_in[27];
    const float* mlp_b1  = (const float*)d_in[28];
    const float* mlp_w2  = (const float*)d_in[29];
    const float* mlp_b2  = (const float*)d_in[30];

    float* ws = (float*)d_ws;
    float* out = (float*)d_out;

    float* PE    = ws + O_PE;
    float* TRXC  = ws + O_TRXC;
    float* CH0   = ws + O_CH0;
    float* CH1   = ws + O_CH1;
    int*   LEN   = (int*)(ws + O_LEN);
    u16*   W1o   = (u16*)(ws + O_W1o);
    u16*   W2o   = (u16*)(ws + O_W2o);
    u16*   WQKV  = (u16*)(ws + O_WQKV);
    u16*   WO    = (u16*)(ws + O_WO);
    u16*   W1t   = (u16*)(ws + O_W1t);
    u16*   W2t   = (u16*)(ws + O_W2t);
    u16*   XBBF  = (u16*)(ws + O_XBBF);
    u16*   O1BF  = (u16*)(ws + O_O1BF);
    u16*   TRXBF = (u16*)(ws + O_TRXBF);
    u16*   ATTBF = (u16*)(ws + O_ATTBF);
    u16*   HIDBF = (u16*)(ws + O_HIDBF);

    // ---- setup ----
    fix_lengths<<<1, 256, 0, stream>>>(lengths, LEN);
    pe_kernel<<<cLB / 256, 256, 0, stream>>>(times, PE);
    pemean_naive<<<(cB * 16 + 255) / 256, 256, 0, stream>>>(PE, ws + O_PEM);
    emb_kernel<<<cB, 64, 0, stream>>>(statin, emb_w, emb_b, ws + O_EMB);
    bias_kernel<<<cB * cF / 256, 256, 0, stream>>>(ws + O_PEM, op1_wp, ws + O_BIAS1);
    bias_kernel<<<cB * cF / 256, 256, 0, stream>>>(ws + O_PEM, op2_wp, ws + O_BIAS2);

    // ---- weight conversions (bf16, padded) ----
    cvt_pad<<<(1024 * 1024 + 255) / 256, 256, 0, stream>>>(op1_W, W1o, 1024, 1024, 1024, 1024 * 1024);
    cvt_pad<<<(1024 * 1024 + 255) / 256, 256, 0, stream>>>(op2_W, W2o, 1024, 1024, 1024, 1024 * 1024);
    for (int l = 0; l < 2; l++) {
        cvt_pad<<<(288 * 896 + 255) / 256, 256, 0, stream>>>(
            tr_wqkv + (size_t)l * 272 * 816, WQKV + (size_t)l * 288 * 896, 272, 816, 896, 288 * 896);
        cvt_pad<<<(288 * 384 + 255) / 256, 256, 0, stream>>>(
            tr_wo + (size_t)l * 272 * 272, WO + (size_t)l * 288 * 384, 272, 272, 384, 288 * 384);
        cvt_pad<<<(288 * 1024 + 255) / 256, 256, 0, stream>>>(
            tr_w1 + (size_t)l * 272 * 1024, W1t + (size_t)l * 288 * 1024, 272, 1024, 1024, 288 * 1024);
        cvt_pad<<<(1024 * 384 + 255) / 256, 256, 0, stream>>>(
            tr_w2 + (size_t)l * 1024 * 272, W2t + (size_t)l * 1024 * 384, 1024, 272, 384, 1024 * 384);
    }

    // ---- per-chunk pipeline ----
    for (int c = 0; c < NCHUNK; c++) {
        int b0 = c * BC;

        // obs_prop layer 1 (z in CH0, Ncol=1024)
        build_xb_bf<<<RC_OBS, 256, 0, stream>>>(src, R_u, b0, XBBF);
        gemm_bf<2, 0, 0><<<dim3(8, RC_OBS / 128), 256, 0, stream>>>(
            XBBF, W1o, ws + O_BIAS1 + (size_t)b0 * cF, CH0, RC_OBS, 1024, 1024, 1024);
        sasr_kernel<<<RC_OBS / 4, 256, 0, stream>>>(CH0, op1_al, op1_ar,
            ws + O_SA + b0 * 64, ws + O_SR + b0 * 64);
        alpha_kernel<0><<<RC_OBS / 4, 256, 0, stream>>>(
            ws + O_SA + b0 * 64, ws + O_SR + b0 * 64, nullptr,
            ws + O_AL1 + (size_t)b0 * cE);
        obs_out_k<1><<<dim3(BC, 4), 256, 0, stream>>>(
            ws + O_AL1 + (size_t)b0 * cE, CH0, O1BF);

        // obs_prop layer 2 (out2 f32 -> CH1)
        gemm_bf<2, 0, 0><<<dim3(8, RC_OBS / 128), 256, 0, stream>>>(
            O1BF, W2o, ws + O_BIAS2 + (size_t)b0 * cF, CH0, RC_OBS, 1024, 1024, 1024);
        sasr_kernel<<<RC_OBS / 4, 256, 0, stream>>>(CH0, op2_al, op2_ar,
            ws + O_SA + b0 * 64, ws + O_SR + b0 * 64);
        alpha_kernel<1><<<RC_OBS / 4, 256, 0, stream>>>(
            ws + O_SA + b0 * 64, ws + O_SR + b0 * 64,
            ws + O_AL1 + (size_t)b0 * cE, ws + O_AL2 + (size_t)b0 * cE);
        obs_out_k<0><<<dim3(BC, 4), 256, 0, stream>>>(
            ws + O_AL2 + (size_t)b0 * cE, CH0, CH1);

        // transformer input (f32 + bf16 fused)
        scatter_trx<<<RC_TR, 256, 0, stream>>>(
            CH1, PE + (size_t)b0 * cL * 16, TRXC, TRXBF);

        for (int l = 0; l < 2; l++) {
            const float* bqkv = tr_bqkv + (size_t)l * 816;
            const float* bo   = tr_bo   + (size_t)l * 272;
            const float* bb1  = tr_b1   + (size_t)l * cNH;
            const float* bb2  = tr_b2   + (size_t)l * 272;

            gemm_bf<1, 0, 0><<<dim3(7, RC_TR / 128), 256, 0, stream>>>(
                TRXBF, WQKV + (size_t)l * 288 * 896, bqkv, CH0, RC_TR, 816, 288, 896);
            attn_kernel<<<BC * 8, 512, 0, stream>>>(CH0, LEN + b0, ATTBF);
            gemm_bf<1, 0, 0><<<dim3(3, RC_TR / 128), 256, 0, stream>>>(
                ATTBF, WO + (size_t)l * 288 * 384, bo, CH1, RC_TR, 272, 288, 384);
            resid_ln_kernel<<<RC_TR / 4, 256, 0, stream>>>(
                TRXC, CH1, tr_ln1g + (size_t)l * cDTR, tr_ln1b + (size_t)l * cDTR, TRXBF);
            gemm_bf<1, 1, 1><<<dim3(8, RC_TR / 128), 256, 0, stream>>>(
                TRXBF, W1t + (size_t)l * 288 * 1024, bb1, HIDBF, RC_TR, 1024, 288, 1024);
            gemm_bf<1, 0, 0><<<dim3(3, RC_TR / 128), 256, 0, stream>>>(
                HIDBF, W2t + (size_t)l * 1024 * 384, bb2, CH1, RC_TR, 272, 1024, 384);
            resid_ln_kernel<<<RC_TR / 4, 256, 0, stream>>>(
                TRXC, CH1, tr_ln2g + (size_t)l * cDTR, tr_ln2b + (size_t)l * cDTR, TRXBF);
        }

        agg_kernel<<<BC, 256, 0, stream>>>(
            TRXC, LEN + b0, ws + O_EMB + (size_t)b0 * cN,
            ws + O_AGG + (size_t)b0 * cDFIN);
    }

    // ---- head ----
    gemm_f32<1, 1><<<dim3(6, 4), 256, 0, stream>>>(
        ws + O_AGG, mlp_w1, mlp_b1, ws + O_HMLP, cB, cDFIN, cDFIN);
    mlp2_naive<<<(cB * 2 + 255) / 256, 256, 0, stream>>>(
        ws + O_HMLP, mlp_w2, mlp_b2, out);

    // ---- distance from alpha2: split-K Gram (partials in dead CH0) ----
    transpose_kernel<<<cB * cE / 256, 256, 0, stream>>>(ws + O_AL2, ws + O_AL1);
    gemm_f32_splitk<<<dim3(4, 4, 32), 256, 0, stream>>>(
        ws + O_AL2, ws + O_AL1, CH0, cB, cB, cE, 128);
    gram_reduce<<<(cB * cB + 255) / 256, 256, 0, stream>>>(
        CH0, ws + O_GRAM, cB * cB, 32);
    dist_rows<<<cB, 256, 0, stream>>>(ws + O_GRAM, ws + O_DPART);
    dist_final_naive<<<1, 64, 0, stream>>>(ws + O_DPART, out);

    (void)in_sizes; (void)n_in; (void)out_size; (void)ws_size;
}

// Round 16
// 4219.390 us; speedup vs baseline: 1.2609x; 1.0003x over previous
//
#include <hip/hip_runtime.h>
#include <hip/hip_bf16.h>

// ---------------- problem constants ----------------
constexpr int cL   = 256;
constexpr int cB   = 256;
constexpr int cN   = 64;
constexpr int cF   = 1024;   // L*D_OB
constexpr int cDM  = 256;    // N*D_OB
constexpr int cDTR = 272;    // D_MODEL + D_PE
constexpr int cHD  = 68;     // D_TR / H
constexpr int cNH  = 1024;   // NHID
constexpr int cDST = 9;
constexpr int cDFIN= 336;    // D_TR + N
constexpr int cE   = 4096;   // N*N
constexpr int cLB  = cL * cB;   // 65536
constexpr int cBN  = cB * cN;   // 16384
constexpr int BC   = 64;        // batch chunk
constexpr int NCHUNK = cB / BC; // 4
constexpr int RC_OBS = BC * cN;   // 4096 rows per obs chunk
constexpr int RC_TR  = BC * cL;   // 16384 rows per transformer chunk

using u16 = unsigned short;
using u32 = unsigned int;
typedef short bf16x8 __attribute__((ext_vector_type(8)));
typedef float f32x4  __attribute__((ext_vector_type(4)));
typedef u16   u16x4  __attribute__((ext_vector_type(4)));

__device__ inline u16 f2bf(float x) {            // RNE f32->bf16
    unsigned int u = __float_as_uint(x);
    unsigned int r = (u + 0x7FFFu + ((u >> 16) & 1u)) >> 16;
    return (u16)r;
}
__device__ inline float bf2f(u16 x) {
    return __uint_as_float(((u32)x) << 16);
}

// ---------------- workspace layout (float words), ~183MB ----------------
constexpr size_t O_PE    = 0;                               // LB*16 (b,l,16)
constexpr size_t O_PEM   = O_PE    + (size_t)cLB*16;
constexpr size_t O_EMB   = O_PEM   + (size_t)cB*16;
constexpr size_t O_BIAS1 = O_EMB   + (size_t)cB*64;
constexpr size_t O_BIAS2 = O_BIAS1 + (size_t)cB*cF;
constexpr size_t O_SA    = O_BIAS2 + (size_t)cB*cF;
constexpr size_t O_SR    = O_SA    + (size_t)cBN;
constexpr size_t O_AL1   = O_SR    + (size_t)cBN;           // B*E
constexpr size_t O_AL2   = O_AL1   + (size_t)cB*cE;         // B*E
constexpr size_t O_GRAM  = O_AL2   + (size_t)cB*cE;         // B*B
constexpr size_t O_DPART = O_GRAM  + (size_t)cB*cB;         // B
constexpr size_t O_AGG   = O_DPART + (size_t)cB;            // B*336
constexpr size_t O_HMLP  = O_AGG   + (size_t)cB*cDFIN;      // B*336
constexpr size_t O_LEN   = O_HMLP  + (size_t)cB*cDFIN;      // B ints
// bf16 buffers (word counts = elems/2)
constexpr size_t O_W1o   = O_LEN   + (size_t)cB;            // 1024x1024
constexpr size_t O_W2o   = O_W1o   + 524288;                // 1024x1024
constexpr size_t O_WQKV  = O_W2o   + 524288;                // 2 x 288x896
constexpr size_t O_WO    = O_WQKV  + 258048;                // 2 x 288x384
constexpr size_t O_W1t   = O_WO    + 110592;                // 2 x 288x1024
constexpr size_t O_W2t   = O_W1t   + 294912;                // 2 x 1024x384
constexpr size_t O_XBBF  = O_W2t   + 393216;                // 4096x1024 bf16
constexpr size_t O_O1BF  = O_XBBF  + 2097152;               // 4096x1024 bf16
constexpr size_t O_TRXBF = O_O1BF  + 2097152;               // 16384x288 bf16
constexpr size_t O_ATTBF = O_TRXBF + 2359296;               // 16384x288 bf16
constexpr size_t O_HIDBF = O_ATTBF + 2359296;               // 16384x1024 bf16
constexpr size_t O_TRXC  = O_HIDBF + 8388608;               // 16384x272 f32
constexpr size_t O_CH0   = O_TRXC  + (size_t)RC_TR*cDTR;    // 16384x816 f32 (qkv / obs z / gram partials)
constexpr size_t O_CH1   = O_CH0   + (size_t)RC_TR*816;     // max(4096x1024, 16384x272) f32
constexpr size_t WS_END  = O_CH1   + (size_t)RC_TR*cDTR;    // ~45.7M words

// ---------------- lengths canonicalization ----------------
__global__ void fix_lengths(const int* __restrict__ raw, int* __restrict__ canon) {
    __shared__ int odd_nonzero;
    if (threadIdx.x == 0) odd_nonzero = 0;
    __syncthreads();
    int t = threadIdx.x;
    int w = raw[t];
    if ((t & 1) && w != 0) odd_nonzero = 1;
    __syncthreads();
    if (odd_nonzero) canon[t] = raw[t];
    else             canon[t] = raw[2 * t];
}

// ---------------- setup kernels ----------------

__global__ __launch_bounds__(256) void pe_kernel(const float* __restrict__ times,
                                                 float* __restrict__ pe) {
    int t = blockIdx.x * 256 + threadIdx.x;   // t = b*256 + l
    int b = t >> 8, l = t & 255;
    float tv = times[l * cB + b];
    #pragma unroll
    for (int i = 0; i < 8; i++) {
        float ts = exp2f((8.0f * i) / 7.0f);  // 256^(i/7)
        float sc = tv / ts;
        pe[(size_t)t * 16 + i]     = sinf(sc);
        pe[(size_t)t * 16 + 8 + i] = cosf(sc);
    }
}

__global__ __launch_bounds__(256) void pemean_naive(const float* __restrict__ pe,
                                                    float* __restrict__ pm) {
    int gid = blockIdx.x * 256 + threadIdx.x;
    if (gid >= cB * 16) return;
    int b = gid >> 4, i = gid & 15;
    float s = 0.f;
    for (int l = 0; l < cL; l++) s += pe[((size_t)b * cL + l) * 16 + i];
    pm[gid] = s * (1.0f / 256.0f);
}

__global__ __launch_bounds__(64) void emb_kernel(const float* __restrict__ st,
                                                 const float* __restrict__ w,
                                                 const float* __restrict__ bb,
                                                 float* __restrict__ emb) {
    int b = blockIdx.x, n = threadIdx.x;
    float s = bb[n];
    #pragma unroll
    for (int k = 0; k < cDST; k++) s += st[b * cDST + k] * w[k * cN + n];
    emb[b * cN + n] = s;
}

__global__ __launch_bounds__(256) void bias_kernel(const float* __restrict__ pm,
                                                   const float* __restrict__ wp,
                                                   float* __restrict__ bias) {
    int t = blockIdx.x * 256 + threadIdx.x;   // b*1024 + f
    int b = t >> 10, f = t & 1023;
    float s = 0.f;
    #pragma unroll
    for (int i = 0; i < 16; i++) s += pm[b * 16 + i] * wp[i * cF + f];
    bias[t] = s;
}

// f32 [K][N] -> bf16 [KP][NP], zero padded (weights only)
__global__ __launch_bounds__(256) void cvt_pad(const float* __restrict__ in,
                                               u16* __restrict__ out,
                                               int K, int N, int NP, int total) {
    int gid = blockIdx.x * 256 + threadIdx.x;
    if (gid >= total) return;
    int r = gid / NP, c = gid - r * NP;
    float v = (r < K && c < N) ? in[(size_t)r * N + c] : 0.f;
    out[gid] = f2bf(v);
}

// xb_bf[r,1024] bf16 for local rows r = b_local*64 + n of chunk b0
__global__ __launch_bounds__(256) void build_xb_bf(const float* __restrict__ src,
                                                   const float* __restrict__ R_u,
                                                   int b0,
                                                   u16* __restrict__ xb) {
    int r = blockIdx.x;
    int l = threadIdx.x;
    int b = b0 + (r >> 6), n = r & 63;
    float s = src[((size_t)l * cB + b) * 128 + n];
    float4 rr = *(const float4*)(R_u + n * 4);
    u16x4 o;
    o[0] = f2bf(fmaxf(s * rr.x, 0.f));
    o[1] = f2bf(fmaxf(s * rr.y, 0.f));
    o[2] = f2bf(fmaxf(s * rr.z, 0.f));
    o[3] = f2bf(fmaxf(s * rr.w, 0.f));
    *(u16x4*)(xb + (size_t)r * cF + l * 4) = o;
}

// ---------------- bf16 MFMA GEMM: C(MxNcol) = A(M x KP) * B(KP x NP) ----------------
template<int BIASMODE, int ACT, int OBF>
__global__ __launch_bounds__(256) void gemm_bf(const u16* __restrict__ A,
                                               const u16* __restrict__ B,
                                               const float* __restrict__ bias,
                                               void* __restrict__ Cv,
                                               int M, int Ncol, int KP, int NP) {
    constexpr int LPA = 40;                 // u16 stride for A rows (80B)
    constexpr int LPB = 20;                 // u32 stride for B n-rows (80B)
    __shared__ u16 As[128 * LPA];           // 10 KB
    __shared__ u32 Bs[128 * LPB];           // 10 KB
    int tid = threadIdx.x;
    int m0 = blockIdx.y * 128;
    int n0 = blockIdx.x * 128;
    int w = tid >> 6, lane = tid & 63;
    int wr = w >> 1, wc = w & 1;
    int fr = lane & 15, kg = lane >> 4;

    f32x4 acc[4][4];
    #pragma unroll
    for (int mi = 0; mi < 4; mi++)
        #pragma unroll
        for (int ni = 0; ni < 4; ni++)
            acc[mi][ni] = (f32x4){0.f, 0.f, 0.f, 0.f};

    int arow = tid >> 1, ah = (tid & 1) * 16;
    int bkp = tid >> 4;              // k-pair slot 0..15
    int bnb = (tid & 15) * 8;        // n offset 0..120

    for (int k0 = 0; k0 < KP; k0 += 32) {
        const uint4* ga = (const uint4*)(A + (size_t)(m0 + arow) * KP + k0 + ah);
        *(uint4*)&As[arow * LPA + ah]     = ga[0];
        *(uint4*)&As[arow * LPA + ah + 8] = ga[1];
        const u16* bp0 = B + (size_t)(k0 + 2 * bkp) * NP + n0 + bnb;
        uint4 r0 = *(const uint4*)bp0;
        uint4 r1 = *(const uint4*)(bp0 + NP);
        const u16* e0 = (const u16*)&r0;
        const u16* e1 = (const u16*)&r1;
        #pragma unroll
        for (int j = 0; j < 8; j++) {
            int n = bnb + j;
            int slot = bkp ^ (((n >> 3) & 3) << 2);
            Bs[n * LPB + slot] = (u32)e0[j] | ((u32)e1[j] << 16);
        }
        __syncthreads();

        bf16x8 a[4], bfr[4];
        #pragma unroll
        for (int mi = 0; mi < 4; mi++)
            a[mi] = *(const bf16x8*)&As[(wr * 64 + mi * 16 + fr) * LPA + kg * 8];
        #pragma unroll
        for (int ni = 0; ni < 4; ni++) {
            int n = wc * 64 + ni * 16 + fr;
            int slot4 = 4 * (kg ^ ((n >> 3) & 3));
            bfr[ni] = *(const bf16x8*)&Bs[n * LPB + slot4];
        }
        #pragma unroll
        for (int mi = 0; mi < 4; mi++)
            #pragma unroll
            for (int ni = 0; ni < 4; ni++)
                acc[mi][ni] = __builtin_amdgcn_mfma_f32_16x16x32_bf16(
                    a[mi], bfr[ni], acc[mi][ni], 0, 0, 0);
        __syncthreads();
    }

    float* Cf = (float*)Cv;
    u16*   Cb = (u16*)Cv;
    #pragma unroll
    for (int mi = 0; mi < 4; mi++) {
        #pragma unroll
        for (int ni = 0; ni < 4; ni++) {
            int col = n0 + wc * 64 + ni * 16 + fr;
            if (col >= Ncol) continue;
            #pragma unroll
            for (int r = 0; r < 4; r++) {
                int row = m0 + wr * 64 + mi * 16 + kg * 4 + r;
                float x = acc[mi][ni][r];
                if (BIASMODE == 1) x += bias[col];
                else if (BIASMODE == 2) x += bias[(size_t)(row >> 6) * cF + col];
                if (ACT) x = fmaxf(x, 0.f);
                if (OBF) Cb[(size_t)row * Ncol + col] = f2bf(x);
                else     Cf[(size_t)row * Ncol + col] = x;
            }
        }
    }
}

// ---------------- f32 tiled GEMM (head) ----------------
template<int BIASMODE, int ACT>
__global__ __launch_bounds__(256) void gemm_f32(const float* __restrict__ A,
                                                const float* __restrict__ Bm,
                                                const float* __restrict__ bias,
                                                float* __restrict__ C,
                                                int M, int Ncol, int K) {
    __shared__ float As[16][65];
    __shared__ float Bs[16][65];
    int bx = blockIdx.x, by = blockIdx.y;
    int tid = threadIdx.x;
    int tx = tid & 15, ty = tid >> 4;
    int row0 = by * 64, col0 = bx * 64;
    float acc[4][4] = {};
    for (int k0 = 0; k0 < K; k0 += 16) {
        {
            int r  = tid >> 2;
            int kk = (tid & 3) * 4;
            int gr = row0 + r;
            #pragma unroll
            for (int i = 0; i < 4; i++) {
                int gk = k0 + kk + i;
                As[kk + i][r] = (gr < M && gk < K) ? A[(size_t)gr * K + gk] : 0.f;
            }
        }
        {
            int kr = tid >> 4;
            int c  = (tid & 15) * 4;
            int gk = k0 + kr;
            #pragma unroll
            for (int i = 0; i < 4; i++) {
                int gc = col0 + c + i;
                Bs[kr][c + i] = (gk < K && gc < Ncol) ? Bm[(size_t)gk * Ncol + gc] : 0.f;
            }
        }
        __syncthreads();
        #pragma unroll
        for (int kk = 0; kk < 16; kk++) {
            float a[4], bv[4];
            #pragma unroll
            for (int i = 0; i < 4; i++) a[i]  = As[kk][ty * 4 + i];
            #pragma unroll
            for (int j = 0; j < 4; j++) bv[j] = Bs[kk][tx * 4 + j];
            #pragma unroll
            for (int i = 0; i < 4; i++)
                #pragma unroll
                for (int j = 0; j < 4; j++)
                    acc[i][j] += a[i] * bv[j];
        }
        __syncthreads();
    }
    #pragma unroll
    for (int i = 0; i < 4; i++) {
        int r = row0 + ty * 4 + i;
        if (r >= M) continue;
        #pragma unroll
        for (int j = 0; j < 4; j++) {
            int c = col0 + tx * 4 + j;
            if (c >= Ncol) continue;
            float v = acc[i][j];
            if (BIASMODE == 1) v += bias[c];
            if (ACT == 1) v = fmaxf(v, 0.f);
            C[(size_t)r * Ncol + c] = v;
        }
    }
}

// ---------------- split-K f32 GEMM for the Gram matrix ----------------
__global__ __launch_bounds__(256) void gemm_f32_splitk(const float* __restrict__ A,
                                                       const float* __restrict__ Bm,
                                                       float* __restrict__ P,
                                                       int M, int Ncol, int K, int KS) {
    __shared__ float As[16][65];
    __shared__ float Bs[16][65];
    int bx = blockIdx.x, by = blockIdx.y, bz = blockIdx.z;
    int tid = threadIdx.x;
    int tx = tid & 15, ty = tid >> 4;
    int row0 = by * 64, col0 = bx * 64;
    int kbeg = bz * KS;
    float acc[4][4] = {};
    for (int k0 = kbeg; k0 < kbeg + KS; k0 += 16) {
        {
            int r  = tid >> 2;
            int kk = (tid & 3) * 4;
            int gr = row0 + r;
            #pragma unroll
            for (int i = 0; i < 4; i++) {
                int gk = k0 + kk + i;
                As[kk + i][r] = (gr < M && gk < K) ? A[(size_t)gr * K + gk] : 0.f;
            }
        }
        {
            int kr = tid >> 4;
            int c  = (tid & 15) * 4;
            int gk = k0 + kr;
            #pragma unroll
            for (int i = 0; i < 4; i++) {
                int gc = col0 + c + i;
                Bs[kr][c + i] = (gk < K && gc < Ncol) ? Bm[(size_t)gk * Ncol + gc] : 0.f;
            }
        }
        __syncthreads();
        #pragma unroll
        for (int kk = 0; kk < 16; kk++) {
            float a[4], bv[4];
            #pragma unroll
            for (int i = 0; i < 4; i++) a[i]  = As[kk][ty * 4 + i];
            #pragma unroll
            for (int j = 0; j < 4; j++) bv[j] = Bs[kk][tx * 4 + j];
            #pragma unroll
            for (int i = 0; i < 4; i++)
                #pragma unroll
                for (int j = 0; j < 4; j++)
                    acc[i][j] += a[i] * bv[j];
        }
        __syncthreads();
    }
    size_t zoff = (size_t)bz * M * Ncol;
    #pragma unroll
    for (int i = 0; i < 4; i++) {
        int r = row0 + ty * 4 + i;
        if (r >= M) continue;
        #pragma unroll
        for (int j = 0; j < 4; j++) {
            int c = col0 + tx * 4 + j;
            if (c >= Ncol) continue;
            P[zoff + (size_t)r * Ncol + c] = acc[i][j];
        }
    }
}

__global__ __launch_bounds__(256) void gram_reduce(const float* __restrict__ P,
                                                   float* __restrict__ G,
                                                   int total, int nz) {
    int e = blockIdx.x * 256 + threadIdx.x;
    if (e >= total) return;
    float s = 0.f;
    for (int z = 0; z < nz; z++) s += P[(size_t)z * total + e];
    G[e] = s;
}

// ---------------- obs_prop (wave-parallel, pre-validated) ----------------

__global__ __launch_bounds__(256) void sasr_kernel(const float* __restrict__ z,
                                                   const float* __restrict__ al,
                                                   const float* __restrict__ ar,
                                                   float* __restrict__ sa,
                                                   float* __restrict__ sr) {
    int row  = blockIdx.x * 4 + (threadIdx.x >> 6);
    int lane = threadIdx.x & 63;
    const float* zr = z + (size_t)row * cF;
    float a = 0.f, r = 0.f;
    for (int k = lane; k < cF; k += 64) {
        float v = zr[k];
        a += v * al[k];
        r += v * ar[k];
    }
    for (int off = 32; off; off >>= 1) {
        a += __shfl_xor(a, off);
        r += __shfl_xor(r, off);
    }
    if (lane == 0) { sa[row] = a; sr[row] = r; }
}

template<int WITH_EW>
__global__ __launch_bounds__(256) void alpha_kernel(const float* __restrict__ sa,
                                                    const float* __restrict__ sr,
                                                    const float* __restrict__ ew,
                                                    float* __restrict__ alpha) {
    int idx = blockIdx.x * 4 + (threadIdx.x >> 6);   // local b*64 + d
    int b = idx >> 6, d = idx & 63;
    int s = threadIdx.x & 63;
    float sc = sa[b * 64 + s] + sr[b * 64 + d];
    sc = sc >= 0.f ? sc : 0.2f * sc;
    size_t eidx = (size_t)b * cE + s * 64 + d;
    if (WITH_EW) sc *= ew[eidx];
    float m = sc;
    for (int off = 32; off; off >>= 1) m = fmaxf(m, __shfl_xor(m, off));
    float e = expf(sc - m);
    float zz = e;
    for (int off = 32; off; off >>= 1) zz += __shfl_xor(zz, off);
    alpha[eidx] = e / zz;
}

// dst[b,d,:] = sum_s alpha[b, s*64+d] * z[b,s,:]  (dst separate; OBF: bf16 out)
template<int OBF>
__global__ __launch_bounds__(256) void obs_out_k(const float* __restrict__ alpha,
                                                 const float* __restrict__ z,
                                                 void* __restrict__ dstv) {
    __shared__ float As[64][65];
    int b  = blockIdx.x, fc = blockIdx.y;
    int tid = threadIdx.x;
    for (int i = tid; i < cE; i += 256) As[i >> 6][i & 63] = alpha[(size_t)b * cE + i];
    __syncthreads();
    int f = fc * 256 + tid;
    float acc[64];
    #pragma unroll
    for (int d = 0; d < 64; d++) acc[d] = 0.f;
    for (int s = 0; s < 64; s++) {
        float zv = z[((size_t)b * 64 + s) * cF + f];
        #pragma unroll
        for (int d = 0; d < 64; d++) acc[d] += As[s][d] * zv;
    }
    float* df = (float*)dstv;
    u16*   db = (u16*)dstv;
    #pragma unroll
    for (int d = 0; d < 64; d++) {
        size_t o = ((size_t)b * 64 + d) * cF + f;
        if (OBF) db[o] = f2bf(acc[d]);
        else     df[o] = acc[d];
    }
}

// scatter out2 chunk + pe chunk -> trx chunk f32 AND bf16 (padded 288)
__global__ __launch_bounds__(256) void scatter_trx(const float* __restrict__ out2,
                                                   const float* __restrict__ pe_c,
                                                   float* __restrict__ trx_c,
                                                   u16* __restrict__ trxbf) {
    int r = blockIdx.x;                 // local row = b_local*256 + l
    int bl = r >> 8, l = r & 255;
    size_t obase = (size_t)r * cDTR;
    size_t bbase = (size_t)r * 288;
    for (int c = threadIdx.x; c < cDTR; c += 256) {
        float v;
        if (c < cDM) v = out2[((size_t)bl * 64 + (c >> 2)) * cF + l * 4 + (c & 3)];
        else         v = pe_c[(size_t)r * 16 + (c - cDM)];
        trx_c[obase + c] = v;
        trxbf[bbase + c] = f2bf(v);
    }
}

// ---------------- attention v4: 8 waves share K^T/V^T; per-wave Ps, no inner barriers ----
constexpr int KT_S = 264;   // k-stride (u16): 528B rows, 16B-aligned, conflict-free
__global__ __launch_bounds__(512) void attn_kernel(const float* __restrict__ qkv,
                                                   const int* __restrict__ lengths,
                                                   u16* __restrict__ att) {
    __shared__ __align__(16) u16 Ks[cHD * KT_S];   // 35,904 B  K^T [d][k]
    __shared__ __align__(16) u16 Vs[cHD * KT_S];   // 35,904 B  V^T [d][k]
    __shared__ float Ps[8][cL];                    //  8,192 B  -> total 80,000 B (2 blocks/CU)
    int blk = blockIdx.x;
    int seg = blk & 1;
    int h   = (blk >> 1) & 3;
    int bl  = blk >> 3;
    int tid = threadIdx.x;
    int len = lengths[bl];

    // stage: thread t -> k = t&255, d-half = t>>8 (0: d 0..35, 1: d 36..67)
    {
        int k = tid & 255;
        int half = tid >> 8;
        int dbeg = half ? 36 : 0;
        int dend = half ? 68 : 36;
        const float* krow = qkv + ((size_t)bl * cL + k) * 816 + cDTR + h * cHD;
        const float* vrow = krow + cDTR;
        for (int d = dbeg; d < dend; d += 4) {
            float4 kv = *(const float4*)(krow + d);
            float4 vv = *(const float4*)(vrow + d);
            Ks[(d + 0) * KT_S + k] = f2bf(kv.x);
            Ks[(d + 1) * KT_S + k] = f2bf(kv.y);
            Ks[(d + 2) * KT_S + k] = f2bf(kv.z);
            Ks[(d + 3) * KT_S + k] = f2bf(kv.w);
            Vs[(d + 0) * KT_S + k] = f2bf(vv.x);
            Vs[(d + 1) * KT_S + k] = f2bf(vv.y);
            Vs[(d + 2) * KT_S + k] = f2bf(vv.z);
            Vs[(d + 3) * KT_S + k] = f2bf(vv.w);
        }
    }
    __syncthreads();

    int wave = tid >> 6, lane = tid & 63;
    const float scale = 0.12126781f;   // 1/sqrt(68)
    int d1 = 64 + (lane & 3);
    const u16* v0row = &Vs[lane * KT_S];
    const u16* v1row = &Vs[d1 * KT_S];

    // 8 waves x 16 q-rows each = 128 q-rows per block (seg selects half)
    for (int lq = seg * 128 + wave; lq < seg * 128 + 128; lq += 8) {
        size_t qbase = ((size_t)bl * cL + lq) * 816 + h * cHD;
        float acc[4] = {0.f, 0.f, 0.f, 0.f};
        for (int d = 0; d < cHD; d++) {
            float qd = qkv[qbase + d];           // wave-uniform scalar load
            const u16* kr = &Ks[d * KT_S + lane];
            acc[0] += qd * bf2f(kr[0]);
            acc[1] += qd * bf2f(kr[64]);
            acc[2] += qd * bf2f(kr[128]);
            acc[3] += qd * bf2f(kr[192]);
        }
        float sc[4];
        #pragma unroll
        for (int i = 0; i < 4; i++) {
            int lk = lane + i * 64;
            sc[i] = (lk >= len) ? -1e9f : acc[i] * scale;
        }
        float m = fmaxf(fmaxf(sc[0], sc[1]), fmaxf(sc[2], sc[3]));
        for (int off = 32; off; off >>= 1) m = fmaxf(m, __shfl_xor(m, off));
        float e[4], sum = 0.f;
        #pragma unroll
        for (int i = 0; i < 4; i++) { e[i] = expf(sc[i] - m); sum += e[i]; }
        for (int off = 32; off; off >>= 1) sum += __shfl_xor(sum, off);
        float inv = 1.0f / sum;
        #pragma unroll
        for (int i = 0; i < 4; i++) Ps[wave][lane + i * 64] = e[i] * inv;
        // Ps[wave] is private to this wave: within-wave LDS RAW needs no barrier
        // (single instruction stream; compiler inserts lgkmcnt for the aliasing access)

        float o0 = 0.f, o1 = 0.f;
        #pragma unroll 2
        for (int t8 = 0; t8 < 32; t8++) {
            int t = t8 * 8;
            f32x4 p0 = *(const f32x4*)&Ps[wave][t];
            f32x4 p1 = *(const f32x4*)&Ps[wave][t + 4];
            bf16x8 v0 = *(const bf16x8*)(v0row + t);
            bf16x8 v1 = *(const bf16x8*)(v1row + t);
            o0 += p0[0] * bf2f((u16)v0[0]) + p0[1] * bf2f((u16)v0[1])
                + p0[2] * bf2f((u16)v0[2]) + p0[3] * bf2f((u16)v0[3])
                + p1[0] * bf2f((u16)v0[4]) + p1[1] * bf2f((u16)v0[5])
                + p1[2] * bf2f((u16)v0[6]) + p1[3] * bf2f((u16)v0[7]);
            o1 += p0[0] * bf2f((u16)v1[0]) + p0[1] * bf2f((u16)v1[1])
                + p0[2] * bf2f((u16)v1[2]) + p0[3] * bf2f((u16)v1[3])
                + p1[0] * bf2f((u16)v1[4]) + p1[1] * bf2f((u16)v1[5])
                + p1[2] * bf2f((u16)v1[6]) + p1[3] * bf2f((u16)v1[7]);
        }
        size_t obase = ((size_t)bl * cL + lq) * 288 + h * cHD;
        att[obase + lane] = f2bf(o0);
        if (lane < 4) att[obase + 64 + lane] = f2bf(o1);
    }
}

// ---------------- residual + layernorm (wave per row), fused bf16 out ----------------
__global__ __launch_bounds__(256) void resid_ln_kernel(float* __restrict__ x,
                                                       const float* __restrict__ res,
                                                       const float* __restrict__ g,
                                                       const float* __restrict__ bt,
                                                       u16* __restrict__ xbf) {
    int row  = blockIdx.x * 4 + (threadIdx.x >> 6);
    int lane = threadIdx.x & 63;
    size_t base = (size_t)row * cDTR;
    size_t bbase = (size_t)row * 288;
    float v[5];
    float sum = 0.f, sumsq = 0.f;
    #pragma unroll
    for (int k = 0; k < 5; k++) {
        int c = lane + k * 64;
        float t = 0.f;
        if (c < cDTR) t = x[base + c] + res[base + c];
        v[k] = t;
        sum += t;
        sumsq += t * t;
    }
    for (int off = 32; off; off >>= 1) {
        sum   += __shfl_xor(sum, off);
        sumsq += __shfl_xor(sumsq, off);
    }
    float mean = sum * (1.0f / cDTR);
    float var  = fmaxf(sumsq * (1.0f / cDTR) - mean * mean, 0.f);
    float rstd = 1.0f / sqrtf(var + 1e-5f);
    #pragma unroll
    for (int k = 0; k < 5; k++) {
        int c = lane + k * 64;
        if (c < cDTR) {
            float o = (v[k] - mean) * rstd * g[c] + bt[c];
            x[base + c] = o;
            xbf[bbase + c] = f2bf(o);
        }
    }
}

// ---------------- head ----------------

__global__ __launch_bounds__(256) void agg_kernel(const float* __restrict__ trxc,
                                                  const int* __restrict__ lengths,
                                                  const float* __restrict__ emb,
                                                  float* __restrict__ agg) {
    int b = blockIdx.x;   // local
    int len = lengths[b];
    float inv = 1.0f / ((float)len + 1.0f);
    for (int c = threadIdx.x; c < cDTR; c += 256) {
        float s = 0.f;
        for (int l = 0; l < len; l++) s += trxc[((size_t)b * cL + l) * cDTR + c];
        agg[(size_t)b * cDFIN + c] = s * inv;
    }
    for (int c = threadIdx.x; c < cN; c += 256)
        agg[(size_t)b * cDFIN + cDTR + c] = emb[b * cN + c];
}

__global__ __launch_bounds__(256) void mlp2_naive(const float* __restrict__ hm,
                                                  const float* __restrict__ w2,
                                                  const float* __restrict__ b2,
                                                  float* __restrict__ out) {
    int gid = blockIdx.x * 256 + threadIdx.x;
    if (gid >= cB * 2) return;
    int b = gid >> 1, c = gid & 1;
    float a = b2[c];
    for (int j = 0; j < cDFIN; j++) a += hm[(size_t)b * cDFIN + j] * w2[j * 2 + c];
    out[gid] = a;
}

// ---------------- distance ----------------

__global__ __launch_bounds__(256) void transpose_kernel(const float* __restrict__ a,
                                                        float* __restrict__ at) {
    int t = blockIdx.x * 256 + threadIdx.x;   // b*4096 + e
    int b = t >> 12, e = t & 4095;
    at[(size_t)e * cB + b] = a[t];
}

__global__ __launch_bounds__(256) void dist_rows(const float* __restrict__ G,
                                                 float* __restrict__ part) {
    __shared__ float red[256];
    int i = blockIdx.x, j = threadIdx.x;
    float d2 = fmaxf(G[i * cB + i] + G[j * cB + j] - 2.0f * G[i * cB + j], 0.0f);
    red[j] = sqrtf(d2);
    __syncthreads();
    for (int s = 128; s; s >>= 1) {
        if (j < s) red[j] += red[j + s];
        __syncthreads();
    }
    if (j == 0) part[i] = red[0];
}

__global__ void dist_final_naive(const float* __restrict__ part,
                                 float* __restrict__ out) {
    if (threadIdx.x == 0 && blockIdx.x == 0) {
        float s = 0.f;
        for (int i = 0; i < cB; i++) s += part[i];
        out[512] = s * (1.0f / 65536.0f);
    }
}

// ---------------- launch ----------------

extern "C" void kernel_launch(void* const* d_in, const int* in_sizes, int n_in,
                              void* d_out, int out_size, void* d_ws, size_t ws_size,
                              hipStream_t stream) {
    const float* src     = (const float*)d_in[0];
    const float* statin  = (const float*)d_in[1];
    const float* times   = (const float*)d_in[2];
    const int*   lengths = (const int*)  d_in[3];
    const float* R_u     = (const float*)d_in[4];
    const float* emb_w   = (const float*)d_in[5];
    const float* emb_b   = (const float*)d_in[6];
    const float* op1_W   = (const float*)d_in[7];
    const float* op1_al  = (const float*)d_in[8];
    const float* op1_ar  = (const float*)d_in[9];
    const float* op1_wp  = (const float*)d_in[10];
    const float* op2_W   = (const float*)d_in[11];
    const float* op2_al  = (const float*)d_in[12];
    const float* op2_ar  = (const float*)d_in[13];
    const float* op2_wp  = (const float*)d_in[14];
    const float* tr_wqkv = (const float*)d_in[15];
    const float* tr_bqkv = (const float*)d_in[16];
    const float* tr_wo   = (const float*)d_in[17];
    const float* tr_bo   = (const float*)d_in[18];
    const float* tr_ln1g = (const float*)d_in[19];
    const float* tr_ln1b = (const float*)d_in[20];
    const float* tr_w1   = (const float*)d_in[21];
    const float* tr_b1   = (const float*)d_in[22];
    const float* tr_w2   = (const float*)d_in[23];
    const float* tr_b2   = (const float*)d_in[24];
    const float* tr_ln2g = (const float*)d_in[25];
    const float* tr_ln2b = (const float*)d_in[26];
    const float* mlp_w1  = (const float*)d_in[27];
    const float* mlp_b1  = (const float*)d_in[28];
    const float* mlp_w2  = (const float*)d_in[29];
    const float* mlp_b2  = (const float*)d_in[30];

    float* ws = (float*)d_ws;
    float* out = (float*)d_out;

    float* PE    = ws + O_PE;
    float* TRXC  = ws + O_TRXC;
    float* CH0   = ws + O_CH0;
    float* CH1   = ws + O_CH1;
    int*   LEN   = (int*)(ws + O_LEN);
    u16*   W1o   = (u16*)(ws + O_W1o);
    u16*   W2o   = (u16*)(ws + O_W2o);
    u16*   WQKV  = (u16*)(ws + O_WQKV);
    u16*   WO    = (u16*)(ws + O_WO);
    u16*   W1t   = (u16*)(ws + O_W1t);
    u16*   W2t   = (u16*)(ws + O_W2t);
    u16*   XBBF  = (u16*)(ws + O_XBBF);
    u16*   O1BF  = (u16*)(ws + O_O1BF);
    u16*   TRXBF = (u16*)(ws + O_TRXBF);
    u16*   ATTBF = (u16*)(ws + O_ATTBF);
    u16*   HIDBF = (u16*)(ws + O_HIDBF);

    // ---- setup ----
    fix_lengths<<<1, 256, 0, stream>>>(lengths, LEN);
    pe_kernel<<<cLB / 256, 256, 0, stream>>>(times, PE);
    pemean_naive<<<(cB * 16 + 255) / 256, 256, 0, stream>>>(PE, ws + O_PEM);
    emb_kernel<<<cB, 64, 0, stream>>>(statin, emb_w, emb_b, ws + O_EMB);
    bias_kernel<<<cB * cF / 256, 256, 0, stream>>>(ws + O_PEM, op1_wp, ws + O_BIAS1);
    bias_kernel<<<cB * cF / 256, 256, 0, stream>>>(ws + O_PEM, op2_wp, ws + O_BIAS2);

    // ---- weight conversions (bf16, padded) ----
    cvt_pad<<<(1024 * 1024 + 255) / 256, 256, 0, stream>>>(op1_W, W1o, 1024, 1024, 1024, 1024 * 1024);
    cvt_pad<<<(1024 * 1024 + 255) / 256, 256, 0, stream>>>(op2_W, W2o, 1024, 1024, 1024, 1024 * 1024);
    for (int l = 0; l < 2; l++) {
        cvt_pad<<<(288 * 896 + 255) / 256, 256, 0, stream>>>(
            tr_wqkv + (size_t)l * 272 * 816, WQKV + (size_t)l * 288 * 896, 272, 816, 896, 288 * 896);
        cvt_pad<<<(288 * 384 + 255) / 256, 256, 0, stream>>>(
            tr_wo + (size_t)l * 272 * 272, WO + (size_t)l * 288 * 384, 272, 272, 384, 288 * 384);
        cvt_pad<<<(288 * 1024 + 255) / 256, 256, 0, stream>>>(
            tr_w1 + (size_t)l * 272 * 1024, W1t + (size_t)l * 288 * 1024, 272, 1024, 1024, 288 * 1024);
        cvt_pad<<<(1024 * 384 + 255) / 256, 256, 0, stream>>>(
            tr_w2 + (size_t)l * 1024 * 272, W2t + (size_t)l * 1024 * 384, 1024, 272, 384, 1024 * 384);
    }

    // ---- per-chunk pipeline ----
    for (int c = 0; c < NCHUNK; c++) {
        int b0 = c * BC;

        // obs_prop layer 1 (z in CH0, Ncol=1024)
        build_xb_bf<<<RC_OBS, 256, 0, stream>>>(src, R_u, b0, XBBF);
        gemm_bf<2, 0, 0><<<dim3(8, RC_OBS / 128), 256, 0, stream>>>(
            XBBF, W1o, ws + O_BIAS1 + (size_t)b0 * cF, CH0, RC_OBS, 1024, 1024, 1024);
        sasr_kernel<<<RC_OBS / 4, 256, 0, stream>>>(CH0, op1_al, op1_ar,
            ws + O_SA + b0 * 64, ws + O_SR + b0 * 64);
        alpha_kernel<0><<<RC_OBS / 4, 256, 0, stream>>>(
            ws + O_SA + b0 * 64, ws + O_SR + b0 * 64, nullptr,
            ws + O_AL1 + (size_t)b0 * cE);
        obs_out_k<1><<<dim3(BC, 4), 256, 0, stream>>>(
            ws + O_AL1 + (size_t)b0 * cE, CH0, O1BF);

        // obs_prop layer 2 (out2 f32 -> CH1)
        gemm_bf<2, 0, 0><<<dim3(8, RC_OBS / 128), 256, 0, stream>>>(
            O1BF, W2o, ws + O_BIAS2 + (size_t)b0 * cF, CH0, RC_OBS, 1024, 1024, 1024);
        sasr_kernel<<<RC_OBS / 4, 256, 0, stream>>>(CH0, op2_al, op2_ar,
            ws + O_SA + b0 * 64, ws + O_SR + b0 * 64);
        alpha_kernel<1><<<RC_OBS / 4, 256, 0, stream>>>(
            ws + O_SA + b0 * 64, ws + O_SR + b0 * 64,
            ws + O_AL1 + (size_t)b0 * cE, ws + O_AL2 + (size_t)b0 * cE);
        obs_out_k<0><<<dim3(BC, 4), 256, 0, stream>>>(
            ws + O_AL2 + (size_t)b0 * cE, CH0, CH1);

        // transformer input (f32 + bf16 fused)
        scatter_trx<<<RC_TR, 256, 0, stream>>>(
            CH1, PE + (size_t)b0 * cL * 16, TRXC, TRXBF);

        for (int l = 0; l < 2; l++) {
            const float* bqkv = tr_bqkv + (size_t)l * 816;
            const float* bo   = tr_bo   + (size_t)l * 272;
            const float* bb1  = tr_b1   + (size_t)l * cNH;
            const float* bb2  = tr_b2   + (size_t)l * 272;

            gemm_bf<1, 0, 0><<<dim3(7, RC_TR / 128), 256, 0, stream>>>(
                TRXBF, WQKV + (size_t)l * 288 * 896, bqkv, CH0, RC_TR, 816, 288, 896);
            attn_kernel<<<BC * 8, 512, 0, stream>>>(CH0, LEN + b0, ATTBF);
            gemm_bf<1, 0, 0><<<dim3(3, RC_TR / 128), 256, 0, stream>>>(
                ATTBF, WO + (size_t)l * 288 * 384, bo, CH1, RC_TR, 272, 288, 384);
            resid_ln_kernel<<<RC_TR / 4, 256, 0, stream>>>(
                TRXC, CH1, tr_ln1g + (size_t)l * cDTR, tr_ln1b + (size_t)l * cDTR, TRXBF);
            gemm_bf<1, 1, 1><<<dim3(8, RC_TR / 128), 256, 0, stream>>>(
                TRXBF, W1t + (size_t)l * 288 * 1024, bb1, HIDBF, RC_TR, 1024, 288, 1024);
            gemm_bf<1, 0, 0><<<dim3(3, RC_TR / 128), 256, 0, stream>>>(
                HIDBF, W2t + (size_t)l * 1024 * 384, bb2, CH1, RC_TR, 272, 1024, 384);
            resid_ln_kernel<<<RC_TR / 4, 256, 0, stream>>>(
                TRXC, CH1, tr_ln2g + (size_t)l * cDTR, tr_ln2b + (size_t)l * cDTR, TRXBF);
        }

        agg_kernel<<<BC, 256, 0, stream>>>(
            TRXC, LEN + b0, ws + O_EMB + (size_t)b0 * cN,
            ws + O_AGG + (size_t)b0 * cDFIN);
    }

    // ---- head ----
    gemm_f32<1, 1><<<dim3(6, 4), 256, 0, stream>>>(
        ws + O_AGG, mlp_w1, mlp_b1, ws + O_HMLP, cB, cDFIN, cDFIN);
    mlp2_naive<<<(cB * 2 + 255) / 256, 256, 0, stream>>>(
        ws + O_HMLP, mlp_w2, mlp_b2, out);

    // ---- distance from alpha2: split-K Gram (partials in dead CH0) ----
    transpose_kernel<<<cB * cE / 256, 256, 0, stream>>>(ws + O_AL2, ws + O_AL1);
    gemm_f32_splitk<<<dim3(4, 4, 32), 256, 0, stream>>>(
        ws + O_AL2, ws + O_AL1, CH0, cB, cB, cE, 128);
    gram_reduce<<<(cB * cB + 255) / 256, 256, 0, stream>>>(
        CH0, ws + O_GRAM, cB * cB, 32);
    dist_rows<<<cB, 256, 0, stream>>>(ws + O_GRAM, ws + O_DPART);
    dist_final_naive<<<1, 64, 0, stream>>>(ws + O_DPART, out);

    (void)in_sizes; (void)n_in; (void)out_size; (void)ws_size;
}

// Round 17
// 2928.740 us; speedup vs baseline: 1.8166x; 1.4407x over previous
//
#include <hip/hip_runtime.h>
#include <hip/hip_bf16.h>

// ---------------- problem constants ----------------
constexpr int cL   = 256;
constexpr int cB   = 256;
constexpr int cN   = 64;
constexpr int cF   = 1024;   // L*D_OB
constexpr int cDM  = 256;    // N*D_OB
constexpr int cDTR = 272;    // D_MODEL + D_PE
constexpr int cHD  = 68;     // D_TR / H
constexpr int cNH  = 1024;   // NHID
constexpr int cDST = 9;
constexpr int cDFIN= 336;    // D_TR + N
constexpr int cE   = 4096;   // N*N
constexpr int cLB  = cL * cB;   // 65536
constexpr int cBN  = cB * cN;   // 16384
constexpr int BC   = 64;        // batch chunk
constexpr int NCHUNK = cB / BC; // 4
constexpr int RC_OBS = BC * cN;   // 4096 rows per obs chunk
constexpr int RC_TR  = BC * cL;   // 16384 rows per transformer chunk

using u16 = unsigned short;
using u32 = unsigned int;
typedef short bf16x8 __attribute__((ext_vector_type(8)));
typedef float f32x4  __attribute__((ext_vector_type(4)));
typedef u16   u16x4  __attribute__((ext_vector_type(4)));

__device__ inline u16 f2bf(float x) {            // RNE f32->bf16
    unsigned int u = __float_as_uint(x);
    unsigned int r = (u + 0x7FFFu + ((u >> 16) & 1u)) >> 16;
    return (u16)r;
}
__device__ inline float bf2f(u16 x) {
    return __uint_as_float(((u32)x) << 16);
}

// ---------------- workspace layout (float words), ~183MB ----------------
constexpr size_t O_PE    = 0;                               // LB*16 (b,l,16)
constexpr size_t O_PEM   = O_PE    + (size_t)cLB*16;
constexpr size_t O_EMB   = O_PEM   + (size_t)cB*16;
constexpr size_t O_BIAS1 = O_EMB   + (size_t)cB*64;
constexpr size_t O_BIAS2 = O_BIAS1 + (size_t)cB*cF;
constexpr size_t O_SA    = O_BIAS2 + (size_t)cB*cF;
constexpr size_t O_SR    = O_SA    + (size_t)cBN;
constexpr size_t O_AL1   = O_SR    + (size_t)cBN;           // B*E
constexpr size_t O_AL2   = O_AL1   + (size_t)cB*cE;         // B*E
constexpr size_t O_GRAM  = O_AL2   + (size_t)cB*cE;         // B*B
constexpr size_t O_DPART = O_GRAM  + (size_t)cB*cB;         // B
constexpr size_t O_AGG   = O_DPART + (size_t)cB;            // B*336
constexpr size_t O_HMLP  = O_AGG   + (size_t)cB*cDFIN;      // B*336
constexpr size_t O_LEN   = O_HMLP  + (size_t)cB*cDFIN;      // B ints
// bf16 buffers (word counts = elems/2)
constexpr size_t O_W1o   = O_LEN   + (size_t)cB;            // 1024x1024
constexpr size_t O_W2o   = O_W1o   + 524288;                // 1024x1024
constexpr size_t O_WQKV  = O_W2o   + 524288;                // 2 x 288x896
constexpr size_t O_WO    = O_WQKV  + 258048;                // 2 x 288x384
constexpr size_t O_W1t   = O_WO    + 110592;                // 2 x 288x1024
constexpr size_t O_W2t   = O_W1t   + 294912;                // 2 x 1024x384
constexpr size_t O_XBBF  = O_W2t   + 393216;                // 4096x1024 bf16
constexpr size_t O_O1BF  = O_XBBF  + 2097152;               // 4096x1024 bf16
constexpr size_t O_TRXBF = O_O1BF  + 2097152;               // 16384x288 bf16
constexpr size_t O_ATTBF = O_TRXBF + 2359296;               // 16384x288 bf16
constexpr size_t O_HIDBF = O_ATTBF + 2359296;               // 16384x1024 bf16 (FFN hidden / attn S+P)
constexpr size_t O_TRXC  = O_HIDBF + 8388608;               // 16384x272 f32
constexpr size_t O_CH0   = O_TRXC  + (size_t)RC_TR*cDTR;    // 16384x816 f32 (qkv / obs z / gram partials)
constexpr size_t O_CH1   = O_CH0   + (size_t)RC_TR*816;     // max(4096x1024, 16384x272) f32
constexpr size_t WS_END  = O_CH1   + (size_t)RC_TR*cDTR;    // ~45.7M words

// ---------------- lengths canonicalization ----------------
__global__ void fix_lengths(const int* __restrict__ raw, int* __restrict__ canon) {
    __shared__ int odd_nonzero;
    if (threadIdx.x == 0) odd_nonzero = 0;
    __syncthreads();
    int t = threadIdx.x;
    int w = raw[t];
    if ((t & 1) && w != 0) odd_nonzero = 1;
    __syncthreads();
    if (odd_nonzero) canon[t] = raw[t];
    else             canon[t] = raw[2 * t];
}

// ---------------- setup kernels ----------------

__global__ __launch_bounds__(256) void pe_kernel(const float* __restrict__ times,
                                                 float* __restrict__ pe) {
    int t = blockIdx.x * 256 + threadIdx.x;   // t = b*256 + l
    int b = t >> 8, l = t & 255;
    float tv = times[l * cB + b];
    #pragma unroll
    for (int i = 0; i < 8; i++) {
        float ts = exp2f((8.0f * i) / 7.0f);  // 256^(i/7)
        float sc = tv / ts;
        pe[(size_t)t * 16 + i]     = sinf(sc);
        pe[(size_t)t * 16 + 8 + i] = cosf(sc);
    }
}

__global__ __launch_bounds__(256) void pemean_naive(const float* __restrict__ pe,
                                                    float* __restrict__ pm) {
    int gid = blockIdx.x * 256 + threadIdx.x;
    if (gid >= cB * 16) return;
    int b = gid >> 4, i = gid & 15;
    float s = 0.f;
    for (int l = 0; l < cL; l++) s += pe[((size_t)b * cL + l) * 16 + i];
    pm[gid] = s * (1.0f / 256.0f);
}

__global__ __launch_bounds__(64) void emb_kernel(const float* __restrict__ st,
                                                 const float* __restrict__ w,
                                                 const float* __restrict__ bb,
                                                 float* __restrict__ emb) {
    int b = blockIdx.x, n = threadIdx.x;
    float s = bb[n];
    #pragma unroll
    for (int k = 0; k < cDST; k++) s += st[b * cDST + k] * w[k * cN + n];
    emb[b * cN + n] = s;
}

__global__ __launch_bounds__(256) void bias_kernel(const float* __restrict__ pm,
                                                   const float* __restrict__ wp,
                                                   float* __restrict__ bias) {
    int t = blockIdx.x * 256 + threadIdx.x;   // b*1024 + f
    int b = t >> 10, f = t & 1023;
    float s = 0.f;
    #pragma unroll
    for (int i = 0; i < 16; i++) s += pm[b * 16 + i] * wp[i * cF + f];
    bias[t] = s;
}

// f32 [K][N] -> bf16 [KP][NP], zero padded (weights only)
__global__ __launch_bounds__(256) void cvt_pad(const float* __restrict__ in,
                                               u16* __restrict__ out,
                                               int K, int N, int NP, int total) {
    int gid = blockIdx.x * 256 + threadIdx.x;
    if (gid >= total) return;
    int r = gid / NP, c = gid - r * NP;
    float v = (r < K && c < N) ? in[(size_t)r * N + c] : 0.f;
    out[gid] = f2bf(v);
}

// xb_bf[r,1024] bf16 for local rows r = b_local*64 + n of chunk b0
__global__ __launch_bounds__(256) void build_xb_bf(const float* __restrict__ src,
                                                   const float* __restrict__ R_u,
                                                   int b0,
                                                   u16* __restrict__ xb) {
    int r = blockIdx.x;
    int l = threadIdx.x;
    int b = b0 + (r >> 6), n = r & 63;
    float s = src[((size_t)l * cB + b) * 128 + n];
    float4 rr = *(const float4*)(R_u + n * 4);
    u16x4 o;
    o[0] = f2bf(fmaxf(s * rr.x, 0.f));
    o[1] = f2bf(fmaxf(s * rr.y, 0.f));
    o[2] = f2bf(fmaxf(s * rr.z, 0.f));
    o[3] = f2bf(fmaxf(s * rr.w, 0.f));
    *(u16x4*)(xb + (size_t)r * cF + l * 4) = o;
}

// ---------------- bf16 MFMA GEMM: C(MxNcol) = A(M x KP) * B(KP x NP) ----------------
template<int BIASMODE, int ACT, int OBF>
__global__ __launch_bounds__(256) void gemm_bf(const u16* __restrict__ A,
                                               const u16* __restrict__ B,
                                               const float* __restrict__ bias,
                                               void* __restrict__ Cv,
                                               int M, int Ncol, int KP, int NP) {
    constexpr int LPA = 40;                 // u16 stride for A rows (80B)
    constexpr int LPB = 20;                 // u32 stride for B n-rows (80B)
    __shared__ u16 As[128 * LPA];           // 10 KB
    __shared__ u32 Bs[128 * LPB];           // 10 KB
    int tid = threadIdx.x;
    int m0 = blockIdx.y * 128;
    int n0 = blockIdx.x * 128;
    int w = tid >> 6, lane = tid & 63;
    int wr = w >> 1, wc = w & 1;
    int fr = lane & 15, kg = lane >> 4;

    f32x4 acc[4][4];
    #pragma unroll
    for (int mi = 0; mi < 4; mi++)
        #pragma unroll
        for (int ni = 0; ni < 4; ni++)
            acc[mi][ni] = (f32x4){0.f, 0.f, 0.f, 0.f};

    int arow = tid >> 1, ah = (tid & 1) * 16;
    int bkp = tid >> 4;              // k-pair slot 0..15
    int bnb = (tid & 15) * 8;        // n offset 0..120

    for (int k0 = 0; k0 < KP; k0 += 32) {
        const uint4* ga = (const uint4*)(A + (size_t)(m0 + arow) * KP + k0 + ah);
        *(uint4*)&As[arow * LPA + ah]     = ga[0];
        *(uint4*)&As[arow * LPA + ah + 8] = ga[1];
        const u16* bp0 = B + (size_t)(k0 + 2 * bkp) * NP + n0 + bnb;
        uint4 r0 = *(const uint4*)bp0;
        uint4 r1 = *(const uint4*)(bp0 + NP);
        const u16* e0 = (const u16*)&r0;
        const u16* e1 = (const u16*)&r1;
        #pragma unroll
        for (int j = 0; j < 8; j++) {
            int n = bnb + j;
            int slot = bkp ^ (((n >> 3) & 3) << 2);
            Bs[n * LPB + slot] = (u32)e0[j] | ((u32)e1[j] << 16);
        }
        __syncthreads();

        bf16x8 a[4], bfr[4];
        #pragma unroll
        for (int mi = 0; mi < 4; mi++)
            a[mi] = *(const bf16x8*)&As[(wr * 64 + mi * 16 + fr) * LPA + kg * 8];
        #pragma unroll
        for (int ni = 0; ni < 4; ni++) {
            int n = wc * 64 + ni * 16 + fr;
            int slot4 = 4 * (kg ^ ((n >> 3) & 3));
            bfr[ni] = *(const bf16x8*)&Bs[n * LPB + slot4];
        }
        #pragma unroll
        for (int mi = 0; mi < 4; mi++)
            #pragma unroll
            for (int ni = 0; ni < 4; ni++)
                acc[mi][ni] = __builtin_amdgcn_mfma_f32_16x16x32_bf16(
                    a[mi], bfr[ni], acc[mi][ni], 0, 0, 0);
        __syncthreads();
    }

    float* Cf = (float*)Cv;
    u16*   Cb = (u16*)Cv;
    #pragma unroll
    for (int mi = 0; mi < 4; mi++) {
        #pragma unroll
        for (int ni = 0; ni < 4; ni++) {
            int col = n0 + wc * 64 + ni * 16 + fr;
            if (col >= Ncol) continue;
            #pragma unroll
            for (int r = 0; r < 4; r++) {
                int row = m0 + wr * 64 + mi * 16 + kg * 4 + r;
                float x = acc[mi][ni][r];
                if (BIASMODE == 1) x += bias[col];
                else if (BIASMODE == 2) x += bias[(size_t)(row >> 6) * cF + col];
                if (ACT) x = fmaxf(x, 0.f);
                if (OBF) Cb[(size_t)row * Ncol + col] = f2bf(x);
                else     Cf[(size_t)row * Ncol + col] = x;
            }
        }
    }
}

// ---------------- MFMA attention: S = Q.K^T (per b,h) ----------------
// grid(2 keytile, 2 qtile, BC*4); S bf16 [bh][256 q][256 key], masked & scaled.
__global__ __launch_bounds__(256) void attn_qk(const float* __restrict__ qkv,
                                               const int* __restrict__ lengths,
                                               u16* __restrict__ S) {
    constexpr int LP = 40;                  // u16 row stride (holds 32-k step)
    __shared__ u16 As[128 * LP];            // Q tile [q][d]
    __shared__ u16 Bs[128 * LP];            // K tile [key][d]
    int tid = threadIdx.x;
    int n0 = blockIdx.x * 128;              // key
    int m0 = blockIdx.y * 128;              // q
    int bh = blockIdx.z;
    int bl = bh >> 2, h = bh & 3;
    int len = lengths[bl];
    int w = tid >> 6, lane = tid & 63;
    int wr = w >> 1, wc = w & 1;
    int fr = lane & 15, kg = lane >> 4;

    f32x4 acc[4][4];
    #pragma unroll
    for (int mi = 0; mi < 4; mi++)
        #pragma unroll
        for (int ni = 0; ni < 4; ni++)
            acc[mi][ni] = (f32x4){0.f, 0.f, 0.f, 0.f};

    int arow = tid >> 1, ah = (tid & 1) * 16;
    const float* qp = qkv + ((size_t)(bl * 256 + m0 + arow)) * 816 + h * cHD;
    const float* kp = qkv + ((size_t)(bl * 256 + n0 + arow)) * 816 + cDTR + h * cHD;

    for (int k0 = 0; k0 < 96; k0 += 32) {   // d padded 68 -> 96
        u16 ta[16], tb[16];
        #pragma unroll
        for (int j = 0; j < 16; j++) {
            int dd = k0 + ah + j;
            ta[j] = (dd < cHD) ? f2bf(qp[dd]) : 0;
            tb[j] = (dd < cHD) ? f2bf(kp[dd]) : 0;
        }
        *(uint4*)&As[arow * LP + ah]     = *(uint4*)&ta[0];
        *(uint4*)&As[arow * LP + ah + 8] = *(uint4*)&ta[8];
        *(uint4*)&Bs[arow * LP + ah]     = *(uint4*)&tb[0];
        *(uint4*)&Bs[arow * LP + ah + 8] = *(uint4*)&tb[8];
        __syncthreads();

        bf16x8 a[4], b[4];
        #pragma unroll
        for (int mi = 0; mi < 4; mi++)
            a[mi] = *(const bf16x8*)&As[(wr * 64 + mi * 16 + fr) * LP + kg * 8];
        #pragma unroll
        for (int ni = 0; ni < 4; ni++)
            b[ni] = *(const bf16x8*)&Bs[(wc * 64 + ni * 16 + fr) * LP + kg * 8];
        #pragma unroll
        for (int mi = 0; mi < 4; mi++)
            #pragma unroll
            for (int ni = 0; ni < 4; ni++)
                acc[mi][ni] = __builtin_amdgcn_mfma_f32_16x16x32_bf16(
                    a[mi], b[ni], acc[mi][ni], 0, 0, 0);
        __syncthreads();
    }

    const float scale = 0.12126781f;        // 1/sqrt(68)
    u16* Srow = S + (size_t)bh * 65536;
    #pragma unroll
    for (int mi = 0; mi < 4; mi++) {
        #pragma unroll
        for (int ni = 0; ni < 4; ni++) {
            int col = n0 + wc * 64 + ni * 16 + fr;   // key
            #pragma unroll
            for (int r = 0; r < 4; r++) {
                int row = m0 + wr * 64 + mi * 16 + kg * 4 + r;   // q
                float x = (col >= len) ? -300.f : acc[mi][ni][r] * scale;
                Srow[(size_t)row * 256 + col] = f2bf(x);
            }
        }
    }
}

// ---------------- softmax in place on S (bf16), wave per row ----------------
__global__ __launch_bounds__(256) void attn_softmax(u16* __restrict__ S) {
    int row  = blockIdx.x * 4 + (threadIdx.x >> 6);
    int lane = threadIdx.x & 63;
    u16* sr = S + (size_t)row * 256 + lane * 4;
    u16x4 v = *(const u16x4*)sr;
    float s0 = bf2f(v[0]), s1 = bf2f(v[1]), s2 = bf2f(v[2]), s3 = bf2f(v[3]);
    float m = fmaxf(fmaxf(s0, s1), fmaxf(s2, s3));
    for (int off = 32; off; off >>= 1) m = fmaxf(m, __shfl_xor(m, off));
    float e0 = expf(s0 - m), e1 = expf(s1 - m), e2 = expf(s2 - m), e3 = expf(s3 - m);
    float sum = e0 + e1 + e2 + e3;
    for (int off = 32; off; off >>= 1) sum += __shfl_xor(sum, off);
    float inv = 1.0f / sum;
    u16x4 o;
    o[0] = f2bf(e0 * inv); o[1] = f2bf(e1 * inv);
    o[2] = f2bf(e2 * inv); o[3] = f2bf(e3 * inv);
    *(u16x4*)sr = o;
}

// ---------------- MFMA attention: O = P.V (per b,h) ----------------
// grid(1, 2 qtile, BC*4). P bf16 from S; V from qkv f32; out ATTBF [row][288].
__global__ __launch_bounds__(256) void attn_pv(const float* __restrict__ qkv,
                                               const u16* __restrict__ S,
                                               u16* __restrict__ att) {
    constexpr int LPA = 40;
    constexpr int LPB = 20;
    __shared__ u16 As[128 * LPA];
    __shared__ u32 Bs[128 * LPB];
    int tid = threadIdx.x;
    int m0 = blockIdx.y * 128;              // q
    int bh = blockIdx.z;
    int bl = bh >> 2, h = bh & 3;
    int w = tid >> 6, lane = tid & 63;
    int wr = w >> 1, wc = w & 1;
    int fr = lane & 15, kg = lane >> 4;

    f32x4 acc[4][4];
    #pragma unroll
    for (int mi = 0; mi < 4; mi++)
        #pragma unroll
        for (int ni = 0; ni < 4; ni++)
            acc[mi][ni] = (f32x4){0.f, 0.f, 0.f, 0.f};

    int arow = tid >> 1, ah = (tid & 1) * 16;
    int bkp = tid >> 4;
    int bnb = (tid & 15) * 8;
    const u16* Pbase = S + (size_t)bh * 65536;

    for (int k0 = 0; k0 < 256; k0 += 32) {  // keys
        const uint4* ga = (const uint4*)(Pbase + (size_t)(m0 + arow) * 256 + k0 + ah);
        *(uint4*)&As[arow * LPA + ah]     = ga[0];
        *(uint4*)&As[arow * LPA + ah + 8] = ga[1];
        const float* vp0 = qkv + ((size_t)(bl * 256 + k0 + 2 * bkp)) * 816 + 2 * cDTR + h * cHD;
        const float* vp1 = vp0 + 816;
        #pragma unroll
        for (int j = 0; j < 8; j++) {
            int n = bnb + j;
            float a = (n < cHD) ? vp0[n] : 0.f;
            float b = (n < cHD) ? vp1[n] : 0.f;
            int slot = bkp ^ (((n >> 3) & 3) << 2);
            Bs[n * LPB + slot] = (u32)f2bf(a) | ((u32)f2bf(b) << 16);
        }
        __syncthreads();

        bf16x8 a[4], bfr[4];
        #pragma unroll
        for (int mi = 0; mi < 4; mi++)
            a[mi] = *(const bf16x8*)&As[(wr * 64 + mi * 16 + fr) * LPA + kg * 8];
        #pragma unroll
        for (int ni = 0; ni < 4; ni++) {
            int n = wc * 64 + ni * 16 + fr;
            int slot4 = 4 * (kg ^ ((n >> 3) & 3));
            bfr[ni] = *(const bf16x8*)&Bs[n * LPB + slot4];
        }
        #pragma unroll
        for (int mi = 0; mi < 4; mi++)
            #pragma unroll
            for (int ni = 0; ni < 4; ni++)
                acc[mi][ni] = __builtin_amdgcn_mfma_f32_16x16x32_bf16(
                    a[mi], bfr[ni], acc[mi][ni], 0, 0, 0);
        __syncthreads();
    }

    #pragma unroll
    for (int mi = 0; mi < 4; mi++) {
        #pragma unroll
        for (int ni = 0; ni < 4; ni++) {
            int ncol = wc * 64 + ni * 16 + fr;   // d
            if (ncol >= cHD) continue;
            #pragma unroll
            for (int r = 0; r < 4; r++) {
                int q = m0 + wr * 64 + mi * 16 + kg * 4 + r;
                att[((size_t)(bl * 256 + q)) * 288 + h * cHD + ncol] = f2bf(acc[mi][ni][r]);
            }
        }
    }
}

// ---------------- f32 tiled GEMM (head) ----------------
template<int BIASMODE, int ACT>
__global__ __launch_bounds__(256) void gemm_f32(const float* __restrict__ A,
                                                const float* __restrict__ Bm,
                                                const float* __restrict__ bias,
                                                float* __restrict__ C,
                                                int M, int Ncol, int K) {
    __shared__ float As[16][65];
    __shared__ float Bs[16][65];
    int bx = blockIdx.x, by = blockIdx.y;
    int tid = threadIdx.x;
    int tx = tid & 15, ty = tid >> 4;
    int row0 = by * 64, col0 = bx * 64;
    float acc[4][4] = {};
    for (int k0 = 0; k0 < K; k0 += 16) {
        {
            int r  = tid >> 2;
            int kk = (tid & 3) * 4;
            int gr = row0 + r;
            #pragma unroll
            for (int i = 0; i < 4; i++) {
                int gk = k0 + kk + i;
                As[kk + i][r] = (gr < M && gk < K) ? A[(size_t)gr * K + gk] : 0.f;
            }
        }
        {
            int kr = tid >> 4;
            int c  = (tid & 15) * 4;
            int gk = k0 + kr;
            #pragma unroll
            for (int i = 0; i < 4; i++) {
                int gc = col0 + c + i;
                Bs[kr][c + i] = (gk < K && gc < Ncol) ? Bm[(size_t)gk * Ncol + gc] : 0.f;
            }
        }
        __syncthreads();
        #pragma unroll
        for (int kk = 0; kk < 16; kk++) {
            float a[4], bv[4];
            #pragma unroll
            for (int i = 0; i < 4; i++) a[i]  = As[kk][ty * 4 + i];
            #pragma unroll
            for (int j = 0; j < 4; j++) bv[j] = Bs[kk][tx * 4 + j];
            #pragma unroll
            for (int i = 0; i < 4; i++)
                #pragma unroll
                for (int j = 0; j < 4; j++)
                    acc[i][j] += a[i] * bv[j];
        }
        __syncthreads();
    }
    #pragma unroll
    for (int i = 0; i < 4; i++) {
        int r = row0 + ty * 4 + i;
        if (r >= M) continue;
        #pragma unroll
        for (int j = 0; j < 4; j++) {
            int c = col0 + tx * 4 + j;
            if (c >= Ncol) continue;
            float v = acc[i][j];
            if (BIASMODE == 1) v += bias[c];
            if (ACT == 1) v = fmaxf(v, 0.f);
            C[(size_t)r * Ncol + c] = v;
        }
    }
}

// ---------------- split-K f32 GEMM for the Gram matrix ----------------
__global__ __launch_bounds__(256) void gemm_f32_splitk(const float* __restrict__ A,
                                                       const float* __restrict__ Bm,
                                                       float* __restrict__ P,
                                                       int M, int Ncol, int K, int KS) {
    __shared__ float As[16][65];
    __shared__ float Bs[16][65];
    int bx = blockIdx.x, by = blockIdx.y, bz = blockIdx.z;
    int tid = threadIdx.x;
    int tx = tid & 15, ty = tid >> 4;
    int row0 = by * 64, col0 = bx * 64;
    int kbeg = bz * KS;
    float acc[4][4] = {};
    for (int k0 = kbeg; k0 < kbeg + KS; k0 += 16) {
        {
            int r  = tid >> 2;
            int kk = (tid & 3) * 4;
            int gr = row0 + r;
            #pragma unroll
            for (int i = 0; i < 4; i++) {
                int gk = k0 + kk + i;
                As[kk + i][r] = (gr < M && gk < K) ? A[(size_t)gr * K + gk] : 0.f;
            }
        }
        {
            int kr = tid >> 4;
            int c  = (tid & 15) * 4;
            int gk = k0 + kr;
            #pragma unroll
            for (int i = 0; i < 4; i++) {
                int gc = col0 + c + i;
                Bs[kr][c + i] = (gk < K && gc < Ncol) ? Bm[(size_t)gk * Ncol + gc] : 0.f;
            }
        }
        __syncthreads();
        #pragma unroll
        for (int kk = 0; kk < 16; kk++) {
            float a[4], bv[4];
            #pragma unroll
            for (int i = 0; i < 4; i++) a[i]  = As[kk][ty * 4 + i];
            #pragma unroll
            for (int j = 0; j < 4; j++) bv[j] = Bs[kk][tx * 4 + j];
            #pragma unroll
            for (int i = 0; i < 4; i++)
                #pragma unroll
                for (int j = 0; j < 4; j++)
                    acc[i][j] += a[i] * bv[j];
        }
        __syncthreads();
    }
    size_t zoff = (size_t)bz * M * Ncol;
    #pragma unroll
    for (int i = 0; i < 4; i++) {
        int r = row0 + ty * 4 + i;
        if (r >= M) continue;
        #pragma unroll
        for (int j = 0; j < 4; j++) {
            int c = col0 + tx * 4 + j;
            if (c >= Ncol) continue;
            P[zoff + (size_t)r * Ncol + c] = acc[i][j];
        }
    }
}

__global__ __launch_bounds__(256) void gram_reduce(const float* __restrict__ P,
                                                   float* __restrict__ G,
                                                   int total, int nz) {
    int e = blockIdx.x * 256 + threadIdx.x;
    if (e >= total) return;
    float s = 0.f;
    for (int z = 0; z < nz; z++) s += P[(size_t)z * total + e];
    G[e] = s;
}

// ---------------- obs_prop (wave-parallel, pre-validated) ----------------

__global__ __launch_bounds__(256) void sasr_kernel(const float* __restrict__ z,
                                                   const float* __restrict__ al,
                                                   const float* __restrict__ ar,
                                                   float* __restrict__ sa,
                                                   float* __restrict__ sr) {
    int row  = blockIdx.x * 4 + (threadIdx.x >> 6);
    int lane = threadIdx.x & 63;
    const float* zr = z + (size_t)row * cF;
    float a = 0.f, r = 0.f;
    for (int k = lane; k < cF; k += 64) {
        float v = zr[k];
        a += v * al[k];
        r += v * ar[k];
    }
    for (int off = 32; off; off >>= 1) {
        a += __shfl_xor(a, off);
        r += __shfl_xor(r, off);
    }
    if (lane == 0) { sa[row] = a; sr[row] = r; }
}

template<int WITH_EW>
__global__ __launch_bounds__(256) void alpha_kernel(const float* __restrict__ sa,
                                                    const float* __restrict__ sr,
                                                    const float* __restrict__ ew,
                                                    float* __restrict__ alpha) {
    int idx = blockIdx.x * 4 + (threadIdx.x >> 6);   // local b*64 + d
    int b = idx >> 6, d = idx & 63;
    int s = threadIdx.x & 63;
    float sc = sa[b * 64 + s] + sr[b * 64 + d];
    sc = sc >= 0.f ? sc : 0.2f * sc;
    size_t eidx = (size_t)b * cE + s * 64 + d;
    if (WITH_EW) sc *= ew[eidx];
    float m = sc;
    for (int off = 32; off; off >>= 1) m = fmaxf(m, __shfl_xor(m, off));
    float e = expf(sc - m);
    float zz = e;
    for (int off = 32; off; off >>= 1) zz += __shfl_xor(zz, off);
    alpha[eidx] = e / zz;
}

// dst[b,d,:] = sum_s alpha[b, s*64+d] * z[b,s,:]  (dst separate; OBF: bf16 out)
template<int OBF>
__global__ __launch_bounds__(256) void obs_out_k(const float* __restrict__ alpha,
                                                 const float* __restrict__ z,
                                                 void* __restrict__ dstv) {
    __shared__ float As[64][65];
    int b  = blockIdx.x, fc = blockIdx.y;
    int tid = threadIdx.x;
    for (int i = tid; i < cE; i += 256) As[i >> 6][i & 63] = alpha[(size_t)b * cE + i];
    __syncthreads();
    int f = fc * 256 + tid;
    float acc[64];
    #pragma unroll
    for (int d = 0; d < 64; d++) acc[d] = 0.f;
    for (int s = 0; s < 64; s++) {
        float zv = z[((size_t)b * 64 + s) * cF + f];
        #pragma unroll
        for (int d = 0; d < 64; d++) acc[d] += As[s][d] * zv;
    }
    float* df = (float*)dstv;
    u16*   db = (u16*)dstv;
    #pragma unroll
    for (int d = 0; d < 64; d++) {
        size_t o = ((size_t)b * 64 + d) * cF + f;
        if (OBF) db[o] = f2bf(acc[d]);
        else     df[o] = acc[d];
    }
}

// scatter out2 chunk + pe chunk -> trx chunk f32 AND bf16 (padded 288)
__global__ __launch_bounds__(256) void scatter_trx(const float* __restrict__ out2,
                                                   const float* __restrict__ pe_c,
                                                   float* __restrict__ trx_c,
                                                   u16* __restrict__ trxbf) {
    int r = blockIdx.x;                 // local row = b_local*256 + l
    int bl = r >> 8, l = r & 255;
    size_t obase = (size_t)r * cDTR;
    size_t bbase = (size_t)r * 288;
    for (int c = threadIdx.x; c < cDTR; c += 256) {
        float v;
        if (c < cDM) v = out2[((size_t)bl * 64 + (c >> 2)) * cF + l * 4 + (c & 3)];
        else         v = pe_c[(size_t)r * 16 + (c - cDM)];
        trx_c[obase + c] = v;
        trxbf[bbase + c] = f2bf(v);
    }
}

// ---------------- residual + layernorm (wave per row), fused bf16 out ----------------
__global__ __launch_bounds__(256) void resid_ln_kernel(float* __restrict__ x,
                                                       const float* __restrict__ res,
                                                       const float* __restrict__ g,
                                                       const float* __restrict__ bt,
                                                       u16* __restrict__ xbf) {
    int row  = blockIdx.x * 4 + (threadIdx.x >> 6);
    int lane = threadIdx.x & 63;
    size_t base = (size_t)row * cDTR;
    size_t bbase = (size_t)row * 288;
    float v[5];
    float sum = 0.f, sumsq = 0.f;
    #pragma unroll
    for (int k = 0; k < 5; k++) {
        int c = lane + k * 64;
        float t = 0.f;
        if (c < cDTR) t = x[base + c] + res[base + c];
        v[k] = t;
        sum += t;
        sumsq += t * t;
    }
    for (int off = 32; off; off >>= 1) {
        sum   += __shfl_xor(sum, off);
        sumsq += __shfl_xor(sumsq, off);
    }
    float mean = sum * (1.0f / cDTR);
    float var  = fmaxf(sumsq * (1.0f / cDTR) - mean * mean, 0.f);
    float rstd = 1.0f / sqrtf(var + 1e-5f);
    #pragma unroll
    for (int k = 0; k < 5; k++) {
        int c = lane + k * 64;
        if (c < cDTR) {
            float o = (v[k] - mean) * rstd * g[c] + bt[c];
            x[base + c] = o;
            xbf[bbase + c] = f2bf(o);
        }
    }
}

// ---------------- head ----------------

__global__ __launch_bounds__(256) void agg_kernel(const float* __restrict__ trxc,
                                                  const int* __restrict__ lengths,
                                                  const float* __restrict__ emb,
                                                  float* __restrict__ agg) {
    int b = blockIdx.x;   // local
    int len = lengths[b];
    float inv = 1.0f / ((float)len + 1.0f);
    for (int c = threadIdx.x; c < cDTR; c += 256) {
        float s = 0.f;
        for (int l = 0; l < len; l++) s += trxc[((size_t)b * cL + l) * cDTR + c];
        agg[(size_t)b * cDFIN + c] = s * inv;
    }
    for (int c = threadIdx.x; c < cN; c += 256)
        agg[(size_t)b * cDFIN + cDTR + c] = emb[b * cN + c];
}

__global__ __launch_bounds__(256) void mlp2_naive(const float* __restrict__ hm,
                                                  const float* __restrict__ w2,
                                                  const float* __restrict__ b2,
                                                  float* __restrict__ out) {
    int gid = blockIdx.x * 256 + threadIdx.x;
    if (gid >= cB * 2) return;
    int b = gid >> 1, c = gid & 1;
    float a = b2[c];
    for (int j = 0; j < cDFIN; j++) a += hm[(size_t)b * cDFIN + j] * w2[j * 2 + c];
    out[gid] = a;
}

// ---------------- distance ----------------

__global__ __launch_bounds__(256) void transpose_kernel(const float* __restrict__ a,
                                                        float* __restrict__ at) {
    int t = blockIdx.x * 256 + threadIdx.x;   // b*4096 + e
    int b = t >> 12, e = t & 4095;
    at[(size_t)e * cB + b] = a[t];
}

__global__ __launch_bounds__(256) void dist_rows(const float* __restrict__ G,
                                                 float* __restrict__ part) {
    __shared__ float red[256];
    int i = blockIdx.x, j = threadIdx.x;
    float d2 = fmaxf(G[i * cB + i] + G[j * cB + j] - 2.0f * G[i * cB + j], 0.0f);
    red[j] = sqrtf(d2);
    __syncthreads();
    for (int s = 128; s; s >>= 1) {
        if (j < s) red[j] += red[j + s];
        __syncthreads();
    }
    if (j == 0) part[i] = red[0];
}

__global__ void dist_final_naive(const float* __restrict__ part,
                                 float* __restrict__ out) {
    if (threadIdx.x == 0 && blockIdx.x == 0) {
        float s = 0.f;
        for (int i = 0; i < cB; i++) s += part[i];
        out[512] = s * (1.0f / 65536.0f);
    }
}

// ---------------- launch ----------------

extern "C" void kernel_launch(void* const* d_in, const int* in_sizes, int n_in,
                              void* d_out, int out_size, void* d_ws, size_t ws_size,
                              hipStream_t stream) {
    const float* src     = (const float*)d_in[0];
    const float* statin  = (const float*)d_in[1];
    const float* times   = (const float*)d_in[2];
    const int*   lengths = (const int*)  d_in[3];
    const float* R_u     = (const float*)d_in[4];
    const float* emb_w   = (const float*)d_in[5];
    const float* emb_b   = (const float*)d_in[6];
    const float* op1_W   = (const float*)d_in[7];
    const float* op1_al  = (const float*)d_in[8];
    const float* op1_ar  = (const float*)d_in[9];
    const float* op1_wp  = (const float*)d_in[10];
    const float* op2_W   = (const float*)d_in[11];
    const float* op2_al  = (const float*)d_in[12];
    const float* op2_ar  = (const float*)d_in[13];
    const float* op2_wp  = (const float*)d_in[14];
    const float* tr_wqkv = (const float*)d_in[15];
    const float* tr_bqkv = (const float*)d_in[16];
    const float* tr_wo   = (const float*)d_in[17];
    const float* tr_bo   = (const float*)d_in[18];
    const float* tr_ln1g = (const float*)d_in[19];
    const float* tr_ln1b = (const float*)d_in[20];
    const float* tr_w1   = (const float*)d_in[21];
    const float* tr_b1   = (const float*)d_in[22];
    const float* tr_w2   = (const float*)d_in[23];
    const float* tr_b2   = (const float*)d_in[24];
    const float* tr_ln2g = (const float*)d_in[25];
    const float* tr_ln2b = (const float*)d_in[26];
    const float* mlp_w1  = (const float*)d_in[27];
    const float* mlp_b1  = (const float*)d_in[28];
    const float* mlp_w2  = (const float*)d_in[29];
    const float* mlp_b2  = (const float*)d_in[30];

    float* ws = (float*)d_ws;
    float* out = (float*)d_out;

    float* PE    = ws + O_PE;
    float* TRXC  = ws + O_TRXC;
    float* CH0   = ws + O_CH0;
    float* CH1   = ws + O_CH1;
    int*   LEN   = (int*)(ws + O_LEN);
    u16*   W1o   = (u16*)(ws + O_W1o);
    u16*   W2o   = (u16*)(ws + O_W2o);
    u16*   WQKV  = (u16*)(ws + O_WQKV);
    u16*   WO    = (u16*)(ws + O_WO);
    u16*   W1t   = (u16*)(ws + O_W1t);
    u16*   W2t   = (u16*)(ws + O_W2t);
    u16*   XBBF  = (u16*)(ws + O_XBBF);
    u16*   O1BF  = (u16*)(ws + O_O1BF);
    u16*   TRXBF = (u16*)(ws + O_TRXBF);
    u16*   ATTBF = (u16*)(ws + O_ATTBF);
    u16*   HIDBF = (u16*)(ws + O_HIDBF);

    // ---- setup ----
    fix_lengths<<<1, 256, 0, stream>>>(lengths, LEN);
    pe_kernel<<<cLB / 256, 256, 0, stream>>>(times, PE);
    pemean_naive<<<(cB * 16 + 255) / 256, 256, 0, stream>>>(PE, ws + O_PEM);
    emb_kernel<<<cB, 64, 0, stream>>>(statin, emb_w, emb_b, ws + O_EMB);
    bias_kernel<<<cB * cF / 256, 256, 0, stream>>>(ws + O_PEM, op1_wp, ws + O_BIAS1);
    bias_kernel<<<cB * cF / 256, 256, 0, stream>>>(ws + O_PEM, op2_wp, ws + O_BIAS2);

    // ---- weight conversions (bf16, padded) ----
    cvt_pad<<<(1024 * 1024 + 255) / 256, 256, 0, stream>>>(op1_W, W1o, 1024, 1024, 1024, 1024 * 1024);
    cvt_pad<<<(1024 * 1024 + 255) / 256, 256, 0, stream>>>(op2_W, W2o, 1024, 1024, 1024, 1024 * 1024);
    for (int l = 0; l < 2; l++) {
        cvt_pad<<<(288 * 896 + 255) / 256, 256, 0, stream>>>(
            tr_wqkv + (size_t)l * 272 * 816, WQKV + (size_t)l * 288 * 896, 272, 816, 896, 288 * 896);
        cvt_pad<<<(288 * 384 + 255) / 256, 256, 0, stream>>>(
            tr_wo + (size_t)l * 272 * 272, WO + (size_t)l * 288 * 384, 272, 272, 384, 288 * 384);
        cvt_pad<<<(288 * 1024 + 255) / 256, 256, 0, stream>>>(
            tr_w1 + (size_t)l * 272 * 1024, W1t + (size_t)l * 288 * 1024, 272, 1024, 1024, 288 * 1024);
        cvt_pad<<<(1024 * 384 + 255) / 256, 256, 0, stream>>>(
            tr_w2 + (size_t)l * 1024 * 272, W2t + (size_t)l * 1024 * 384, 1024, 272, 384, 1024 * 384);
    }

    // ---- per-chunk pipeline ----
    for (int c = 0; c < NCHUNK; c++) {
        int b0 = c * BC;

        // obs_prop layer 1 (z in CH0, Ncol=1024)
        build_xb_bf<<<RC_OBS, 256, 0, stream>>>(src, R_u, b0, XBBF);
        gemm_bf<2, 0, 0><<<dim3(8, RC_OBS / 128), 256, 0, stream>>>(
            XBBF, W1o, ws + O_BIAS1 + (size_t)b0 * cF, CH0, RC_OBS, 1024, 1024, 1024);
        sasr_kernel<<<RC_OBS / 4, 256, 0, stream>>>(CH0, op1_al, op1_ar,
            ws + O_SA + b0 * 64, ws + O_SR + b0 * 64);
        alpha_kernel<0><<<RC_OBS / 4, 256, 0, stream>>>(
            ws + O_SA + b0 * 64, ws + O_SR + b0 * 64, nullptr,
            ws + O_AL1 + (size_t)b0 * cE);
        obs_out_k<1><<<dim3(BC, 4), 256, 0, stream>>>(
            ws + O_AL1 + (size_t)b0 * cE, CH0, O1BF);

        // obs_prop layer 2 (out2 f32 -> CH1)
        gemm_bf<2, 0, 0><<<dim3(8, RC_OBS / 128), 256, 0, stream>>>(
            O1BF, W2o, ws + O_BIAS2 + (size_t)b0 * cF, CH0, RC_OBS, 1024, 1024, 1024);
        sasr_kernel<<<RC_OBS / 4, 256, 0, stream>>>(CH0, op2_al, op2_ar,
            ws + O_SA + b0 * 64, ws + O_SR + b0 * 64);
        alpha_kernel<1><<<RC_OBS / 4, 256, 0, stream>>>(
            ws + O_SA + b0 * 64, ws + O_SR + b0 * 64,
            ws + O_AL1 + (size_t)b0 * cE, ws + O_AL2 + (size_t)b0 * cE);
        obs_out_k<0><<<dim3(BC, 4), 256, 0, stream>>>(
            ws + O_AL2 + (size_t)b0 * cE, CH0, CH1);

        // transformer input (f32 + bf16 fused)
        scatter_trx<<<RC_TR, 256, 0, stream>>>(
            CH1, PE + (size_t)b0 * cL * 16, TRXC, TRXBF);

        for (int l = 0; l < 2; l++) {
            const float* bqkv = tr_bqkv + (size_t)l * 816;
            const float* bo   = tr_bo   + (size_t)l * 272;
            const float* bb1  = tr_b1   + (size_t)l * cNH;
            const float* bb2  = tr_b2   + (size_t)l * 272;

            gemm_bf<1, 0, 0><<<dim3(7, RC_TR / 128), 256, 0, stream>>>(
                TRXBF, WQKV + (size_t)l * 288 * 896, bqkv, CH0, RC_TR, 816, 288, 896);
            // MFMA attention: S -> softmax -> PV (S/P live in HIDBF, dead until FFN1)
            attn_qk<<<dim3(2, 2, BC * 4), 256, 0, stream>>>(CH0, LEN + b0, HIDBF);
            attn_softmax<<<BC * 4 * 256 / 4, 256, 0, stream>>>(HIDBF);
            attn_pv<<<dim3(1, 2, BC * 4), 256, 0, stream>>>(CH0, HIDBF, ATTBF);
            gemm_bf<1, 0, 0><<<dim3(3, RC_TR / 128), 256, 0, stream>>>(
                ATTBF, WO + (size_t)l * 288 * 384, bo, CH1, RC_TR, 272, 288, 384);
            resid_ln_kernel<<<RC_TR / 4, 256, 0, stream>>>(
                TRXC, CH1, tr_ln1g + (size_t)l * cDTR, tr_ln1b + (size_t)l * cDTR, TRXBF);
            gemm_bf<1, 1, 1><<<dim3(8, RC_TR / 128), 256, 0, stream>>>(
                TRXBF, W1t + (size_t)l * 288 * 1024, bb1, HIDBF, RC_TR, 1024, 288, 1024);
            gemm_bf<1, 0, 0><<<dim3(3, RC_TR / 128), 256, 0, stream>>>(
                HIDBF, W2t + (size_t)l * 1024 * 384, bb2, CH1, RC_TR, 272, 1024, 384);
            resid_ln_kernel<<<RC_TR / 4, 256, 0, stream>>>(
                TRXC, CH1, tr_ln2g + (size_t)l * cDTR, tr_ln2b + (size_t)l * cDTR, TRXBF);
        }

        agg_kernel<<<BC, 256, 0, stream>>>(
            TRXC, LEN + b0, ws + O_EMB + (size_t)b0 * cN,
            ws + O_AGG + (size_t)b0 * cDFIN);
    }

    // ---- head ----
    gemm_f32<1, 1><<<dim3(6, 4), 256, 0, stream>>>(
        ws + O_AGG, mlp_w1, mlp_b1, ws + O_HMLP, cB, cDFIN, cDFIN);
    mlp2_naive<<<(cB * 2 + 255) / 256, 256, 0, stream>>>(
        ws + O_HMLP, mlp_w2, mlp_b2, out);

    // ---- distance from alpha2: split-K Gram (partials in dead CH0) ----
    transpose_kernel<<<cB * cE / 256, 256, 0, stream>>>(ws + O_AL2, ws + O_AL1);
    gemm_f32_splitk<<<dim3(4, 4, 32), 256, 0, stream>>>(
        ws + O_AL2, ws + O_AL1, CH0, cB, cB, cE, 128);
    gram_reduce<<<(cB * cB + 255) / 256, 256, 0, stream>>>(
        CH0, ws + O_GRAM, cB * cB, 32);
    dist_rows<<<cB, 256, 0, stream>>>(ws + O_GRAM, ws + O_DPART);
    dist_final_naive<<<1, 64, 0, stream>>>(ws + O_DPART, out);

    (void)in_sizes; (void)n_in; (void)out_size; (void)ws_size;
}